// Round 1
// 442.999 us; speedup vs baseline: 1.0113x; 1.0113x over previous
//
#include <hip/hip_runtime.h>
#include <hip/hip_bf16.h>

// ---------------------------------------------------------------------------
// VectorFieldAttention on MI355X — round 9 (mha occupancy + layout rework)
//
// r8 counters: mha 124us, MfmaUtil 13%, VALUBusy 33%, Occupancy 20% (LDS
// 69,632B -> 2 blocks/CU), SQ_LDS_BANK_CONFLICT 1.2e7 (~16% of cycles, X
// staging scatter is 16-way). This round:
//  * comb becomes PIXEL-MAJOR [b][y][x][e=128] bf16 (conv2 writes 16B/px/wave
//    records; fuse reads uint4v). A window row = 2KB contiguous -> mha stages
//    X with coalesced 1KB-per-wave loads, single stage, no chunk barriers.
//  * mha LDS 69,632 -> 50,176B via 16B-slot XOR swizzles (Q/K [64][32]swz,
//    P [64][64]swz overlays Q+K, V^T [32][64]swz overlays dead X, O/D [64][136]
//    overlays region0) -> 3 blocks/CU.
// Math order unchanged -> absmax must stay 0.03125 exactly.
// ws: flag@0 | wf@1024 | comb@593,920 | hidden@17,371,136 (dead after conv2)
//     overlaid by att@17,371,136 (62,980,096 B) -> total 80,351,232 B.
// ---------------------------------------------------------------------------

#define HW 16384           // 128*128
#define NSEQ 3844          // 961 windows * 4 batch

// f32 weight file offsets (floats)
#define WF_IPW 0
#define WF_IPB 49152
#define WF_OPW 49536
#define WF_OPB 65920
#define WF_FCW 66048
#define WF_FCB 74240
#define WF_MW1 74304
#define WF_MB1 92736
#define WF_AW1 92768
#define WF_AB1 111200
#define WF_MW2 111232
#define WF_MB2 129664
#define WF_AW2 129728
#define WF_AB2 148160
#define WF_TOTAL 148224

typedef __bf16 bf16x8 __attribute__((ext_vector_type(8)));
typedef float f32x4 __attribute__((ext_vector_type(4)));
typedef unsigned int uint2v __attribute__((ext_vector_type(2)));
typedef unsigned int uint4v __attribute__((ext_vector_type(4)));

#define MFMA16(a, b, c) __builtin_amdgcn_mfma_f32_16x16x32_bf16((a), (b), (c), 0, 0, 0)

__device__ __forceinline__ float bfu(unsigned short u) {
    union { unsigned int i; float f; } v; v.i = ((unsigned int)u) << 16; return v.f;
}
__device__ __forceinline__ unsigned short fbf(float f) {
    union { float f; unsigned int i; } v; v.f = f;
    unsigned int x = v.i;
    return (unsigned short)((x + 0x7fffu + ((x >> 16) & 1u)) >> 16);
}
__device__ __forceinline__ float ldin(const void* p, long long i, bool f32) {
    return f32 ? ((const float*)p)[i] : bfu(((const unsigned short*)p)[i]);
}
__device__ __forceinline__ bf16x8 frag_ld(const unsigned short* p) {
    union { uint4v u; bf16x8 b; } v;
    v.u = *(const uint4v*)p;
    return v.b;
}
__device__ __forceinline__ uint2v pack4(float a, float b, float c, float d) {
    uint2v r;
    r.x = (unsigned int)fbf(a) | ((unsigned int)fbf(b) << 16);
    r.y = (unsigned int)fbf(c) | ((unsigned int)fbf(d) << 16);
    return r;
}
__device__ __forceinline__ void unp8(uint4v u, float* x) {
    union { unsigned int i; float f; } a;
    a.i = u.x << 16;         x[0] = a.f;
    a.i = u.x & 0xffff0000u; x[1] = a.f;
    a.i = u.y << 16;         x[2] = a.f;
    a.i = u.y & 0xffff0000u; x[3] = a.f;
    a.i = u.z << 16;         x[4] = a.f;
    a.i = u.z & 0xffff0000u; x[5] = a.f;
    a.i = u.w << 16;         x[6] = a.f;
    a.i = u.w & 0xffff0000u; x[7] = a.f;
}

// ------------------------------------------------------------- K-1: detect
__global__ __launch_bounds__(256) void detect_kernel(const unsigned short* __restrict__ vfu,
                                                     int* __restrict__ flag)
{
    __shared__ int cnt;
    if (threadIdx.x == 0) cnt = 0;
    __syncthreads();
    int bad = 0;
    for (int i = threadIdx.x; i < 8192; i += 256) {
        int e = (vfu[i] >> 7) & 0xff;
        if (e < 0x60 || e > 0xA0) ++bad;
    }
    atomicAdd(&cnt, bad);
    __syncthreads();
    if (threadIdx.x == 0) *flag = (cnt > 400) ? 1 : 0;
}

// ---------------------------------------------------------------- K0: weights
__global__ __launch_bounds__(256) void cvtw_kernel(
    const void* ipw, const void* ipb,
    const void* opw, const void* opb,
    const void* fcw, const void* fcb,
    const void* mw1, const void* mb1,
    const void* aw1, const void* ab1,
    const void* mw2, const void* mb2,
    const void* aw2, const void* ab2,
    const int* __restrict__ flag, float* __restrict__ wf)
{
    int i = blockIdx.x * 256 + threadIdx.x;
    if (i >= WF_TOTAL) return;
    const bool f32 = (*flag != 0);
    const void* src; int off;
    if      (i < WF_IPB) { src = ipw; off = WF_IPW; }
    else if (i < WF_OPW) { src = ipb; off = WF_IPB; }
    else if (i < WF_OPB) { src = opw; off = WF_OPW; }
    else if (i < WF_FCW) { src = opb; off = WF_OPB; }
    else if (i < WF_FCB) { src = fcw; off = WF_FCW; }
    else if (i < WF_MW1) { src = fcb; off = WF_FCB; }
    else if (i < WF_MB1) { src = mw1; off = WF_MW1; }
    else if (i < WF_AW1) { src = mb1; off = WF_MB1; }
    else if (i < WF_AB1) { src = aw1; off = WF_AW1; }
    else if (i < WF_MW2) { src = ab1; off = WF_AB1; }
    else if (i < WF_MB2) { src = mw2; off = WF_MW2; }
    else if (i < WF_AW2) { src = mb2; off = WF_MB2; }
    else if (i < WF_AB2) { src = aw2; off = WF_AW2; }
    else                 { src = ab2; off = WF_AB2; }
    float v = ldin(src, i - off, f32);
    if (i < WF_IPB) {
        ((unsigned short*)(wf + WF_IPW))[i] = fbf(v);           // wqkv_bf [384][128]
    } else if (i >= WF_OPW && i < WF_OPB) {
        ((unsigned short*)(wf + WF_OPW))[i - WF_OPW] = fbf(v);  // wo_bf [128][128]
    } else {
        wf[i] = v;
    }
}

// ------------------------------------------------------------- conv3x3 body
// PIXMAJ=false: out channel-major [oc][HW] (hidden). PIXMAJ=true: out
// pixel-major records [pixel][128], writing 8 oc = 16B at +wv*8 (comb).
template<int IC, bool RELU, bool PIXMAJ>
__device__ void conv3x3_body(const void* __restrict__ in, long long in_off, bool f32,
                             const float* __restrict__ w,    // [32][IC][9]
                             const float* __restrict__ bias, // [32]
                             unsigned short* __restrict__ out)
{
    __shared__ float xs[32][10][38];
    const int t = threadIdx.x;
    const int tx0 = blockIdx.x * 32, ty0 = blockIdx.y * 8;
    const int wv = __builtin_amdgcn_readfirstlane(t >> 6);
    const int lane = t & 63;
    const int pr = lane >> 3, pcq = lane & 7;

    float acc[8][4];
#pragma unroll
    for (int oo = 0; oo < 8; ++oo)
#pragma unroll
        for (int p = 0; p < 4; ++p) acc[oo][p] = 0.f;

    for (int cc = 0; cc < IC; cc += 32) {
        if (cc) __syncthreads();
        for (int i = t; i < 32 * 340; i += 256) {
            int c = i / 340, rem = i - c * 340;
            int rr = rem / 34, cx = rem - rr * 34;
            int gy = ty0 + rr - 1, gx = tx0 + cx - 1;
            float v = 0.f;
            if (gy >= 0 && gy < 128 && gx >= 0 && gx < 128)
                v = ldin(in, in_off + (long long)(cc + c) * HW + gy * 128 + gx, f32);
            xs[c][rr][cx] = v;
        }
        __syncthreads();
        for (int c = 0; c < 32; ++c) {
            float xv[3][6];
#pragma unroll
            for (int dy = 0; dy < 3; ++dy)
#pragma unroll
                for (int dx = 0; dx < 6; ++dx)
                    xv[dy][dx] = xs[c][pr + dy][pcq * 4 + dx];
            const float* wr0 = w + (wv * 8 * IC + (cc + c)) * 9;
#pragma unroll
            for (int oo = 0; oo < 8; ++oo) {
                const float* wr = wr0 + oo * IC * 9;
#pragma unroll
                for (int dy = 0; dy < 3; ++dy)
#pragma unroll
                    for (int dx = 0; dx < 3; ++dx) {
                        float wvv = wr[dy * 3 + dx];
#pragma unroll
                        for (int p = 0; p < 4; ++p)
                            acc[oo][p] = fmaf(wvv, xv[dy][p + dx], acc[oo][p]);
                    }
            }
        }
    }
    const int px = tx0 + pcq * 4, py = ty0 + pr;
    if constexpr (PIXMAJ) {
#pragma unroll
        for (int p = 0; p < 4; ++p) {
            union { unsigned short u[8]; uint4v v; } pk;
#pragma unroll
            for (int oo = 0; oo < 8; ++oo) {
                float vv = acc[oo][p] + bias[wv * 8 + oo];
                if (RELU) vv = fmaxf(vv, 0.f);
                pk.u[oo] = fbf(vv);
            }
            *(uint4v*)(out + (size_t)(py * 128 + px + p) * 128 + wv * 8) = pk.v;
        }
    } else {
#pragma unroll
        for (int oo = 0; oo < 8; ++oo) {
            int oc = wv * 8 + oo;
            float bb = bias[oc];
            float v0 = acc[oo][0] + bb, v1 = acc[oo][1] + bb;
            float v2 = acc[oo][2] + bb, v3 = acc[oo][3] + bb;
            if (RELU) {
                v0 = fmaxf(v0, 0.f); v1 = fmaxf(v1, 0.f);
                v2 = fmaxf(v2, 0.f); v3 = fmaxf(v3, 0.f);
            }
            ushort4 pk;
            pk.x = fbf(v0); pk.y = fbf(v1); pk.z = fbf(v2); pk.w = fbf(v3);
            *(ushort4*)(out + oc * HW + py * 128 + px) = pk;
        }
    }
}

__global__ __launch_bounds__(256) void conv1_kernel(const void* __restrict__ vf,
                                                    const float* __restrict__ wf,
                                                    const int* __restrict__ flag,
                                                    unsigned short* __restrict__ hidden)
{
    int z = blockIdx.z, b = z >> 1, br = z & 1;
    const bool f32 = (*flag != 0);
    conv3x3_body<64, true, false>(vf, (long long)(b * 128 + br * 64) * HW, f32,
                                  wf + (br ? WF_AW1 : WF_MW1), wf + (br ? WF_AB1 : WF_MB1),
                                  hidden + (b * 64 + br * 32) * HW);
}

__global__ __launch_bounds__(256) void conv2_kernel(const unsigned short* __restrict__ hidden,
                                                    const float* __restrict__ wf,
                                                    unsigned short* __restrict__ comb)
{
    int z = blockIdx.z, b = z >> 2, br = (z >> 1) & 1, hf = z & 1;
    // comb pixel-major: image base b*16384*128, channel base br*64+hf*32
    conv3x3_body<32, false, true>(hidden, (long long)(b * 64 + br * 32) * HW, false,
                                  wf + (br ? WF_AW2 : WF_MW2) + hf * 32 * 32 * 9,
                                  wf + (br ? WF_AB2 : WF_MB2) + hf * 32,
                                  comb + (size_t)b * 2097152 + br * 64 + hf * 32);
}

// ---------------------------------------------------------------- K3: MHA (MFMA)
// LDS map (ushort units, 25,088 total = 50,176 B -> 3 blocks/CU):
//   region0 @0 (8,704 ush): X [64][136]  ->  V^T 4x[32][64]swz  ->  O/D [64][136]
//   head hh @8,704+hh*4,096: Q [64][32]swz | K @+2,048 [64][32]swz
//                            P [64][64]swz overlays Q+K after scores
// Swizzle = XOR of the 16B-slot index with low row bits (keeps all
// ds_read_b128 16B-aligned, kills the stride-power-of-2 bank conflicts).
__global__ __launch_bounds__(256, 3) void mha_kernel(
    const unsigned short* __restrict__ comb,   // [b][y][x][e=128] bf16 pixel-major
    const float* __restrict__ wf,
    unsigned short* __restrict__ att)          // [n][tok][e] bf16, raw out-proj
{
    __shared__ unsigned short lds[25088];

    const unsigned short* wqkv = (const unsigned short*)(wf + WF_IPW); // [384][128] bf16
    const unsigned short* wo   = (const unsigned short*)(wf + WF_OPW); // [128][128] bf16

    const int n = blockIdx.x;
    const int ihw = n >> 2, bb = n & 3;
    const int ih = ihw / 31, iw = ihw - ih * 31;
    const int t = threadIdx.x;
    const int lane = t & 63, quad = lane >> 4, l16 = lane & 15;
    const int hh = __builtin_amdgcn_readfirstlane(t >> 6);
    const int hb = hh * 32;
    const int QOFF = 8704 + hh * 4096;
    const int KOFF = QOFF + 2048;
    const int VOFF = hh * 2048;

    // ---- QKV accumulators seeded with bias ----
    int rowb[6];
    f32x4 acc[6][4];
#pragma unroll
    for (int nt = 0; nt < 6; ++nt) {
        int rb = (nt < 2) ? (hb + nt * 16)
               : (nt < 4) ? (128 + hb + (nt - 2) * 16)
                          : (256 + hb + (nt - 4) * 16);
        rowb[nt] = rb;
        f32x4 b4;
        b4[0] = wf[WF_IPB + rb + quad * 4 + 0];
        b4[1] = wf[WF_IPB + rb + quad * 4 + 1];
        b4[2] = wf[WF_IPB + rb + quad * 4 + 2];
        b4[3] = wf[WF_IPB + rb + quad * 4 + 3];
#pragma unroll
        for (int mt = 0; mt < 4; ++mt) acc[nt][mt] = b4;
    }

    // ---- stage X [tok][e] s136: wave hh covers window rows 2hh,2hh+1,
    //      each row = 8 px * 256B = 2KB contiguous -> 1KB coalesced per issue ----
#pragma unroll
    for (int rh = 0; rh < 2; ++rh) {
        const int r = hh * 2 + rh;
        const unsigned short* rp = comb +
            (size_t)(bb * 16384 + (ih * 4 + r) * 128 + iw * 4) * 128;
#pragma unroll
        for (int hv = 0; hv < 2; ++hv) {
            uint4v v = *(const uint4v*)(rp + hv * 512 + lane * 8);
            const int tok = r * 8 + hv * 4 + (lane >> 4);
            *(uint4v*)&lds[tok * 136 + (lane & 15) * 8] = v;
        }
    }
    __syncthreads();

    // ---- QKV: D = Wqkv . X^T (no per-chunk barriers) ----
#pragma unroll
    for (int kc = 0; kc < 4; ++kc) {
        bf16x8 bx[4];
#pragma unroll
        for (int mt = 0; mt < 4; ++mt)
            bx[mt] = frag_ld(&lds[(mt * 16 + l16) * 136 + kc * 32 + quad * 8]);
#pragma unroll
        for (int nt = 0; nt < 6; ++nt) {
            bf16x8 aw = frag_ld(&wqkv[(rowb[nt] + l16) * 128 + kc * 32 + quad * 8]);
#pragma unroll
            for (int mt = 0; mt < 4; ++mt)
                acc[nt][mt] = MFMA16(aw, bx[mt], acc[nt][mt]);
        }
    }

    // ---- write Q,K: [tok][d=32], 16B-slot swizzle (slot ^ (tok&3)) ----
#pragma unroll
    for (int nt = 0; nt < 2; ++nt)
#pragma unroll
        for (int mt = 0; mt < 4; ++mt) {
            const int tok = mt * 16 + l16;
            const int aoff = tok * 32 + (((nt * 2 + (quad >> 1)) ^ (tok & 3)) << 3)
                           + (quad & 1) * 4;
            *(uint2v*)&lds[QOFF + aoff] =
                pack4(acc[nt][mt][0], acc[nt][mt][1], acc[nt][mt][2], acc[nt][mt][3]);
            *(uint2v*)&lds[KOFF + aoff] =
                pack4(acc[nt + 2][mt][0], acc[nt + 2][mt][1],
                      acc[nt + 2][mt][2], acc[nt + 2][mt][3]);
        }
    __syncthreads();   // all waves done reading X -> region0 reusable; Q/K drained

    // ---- V^T [d=32][tok=64] swz (slot ^ (d&7)), overlays dead X ----
#pragma unroll
    for (int nt = 4; nt < 6; ++nt)
#pragma unroll
        for (int mt = 0; mt < 4; ++mt)
#pragma unroll
            for (int r = 0; r < 4; ++r) {
                const int d = (nt - 4) * 16 + quad * 4 + r;
                const int tok = mt * 16 + l16;
                lds[VOFF + d * 64 + (((tok >> 3) ^ (d & 7)) << 3) + (tok & 7)] =
                    fbf(acc[nt][mt][r]);
            }

    // ---- scores: S^T = K . Q^T ----
    bf16x8 ak[4], bq[4];
#pragma unroll
    for (int mtk = 0; mtk < 4; ++mtk) {
        const int tok = mtk * 16 + l16;
        ak[mtk] = frag_ld(&lds[KOFF + tok * 32 + ((quad ^ (tok & 3)) << 3)]);
    }
#pragma unroll
    for (int ntq = 0; ntq < 4; ++ntq) {
        const int tok = ntq * 16 + l16;
        bq[ntq] = frag_ld(&lds[QOFF + tok * 32 + ((quad ^ (tok & 3)) << 3)]);
    }
    f32x4 sc[4][4];
    {
        f32x4 zz = {0.f, 0.f, 0.f, 0.f};
#pragma unroll
        for (int mtk = 0; mtk < 4; ++mtk)
#pragma unroll
            for (int ntq = 0; ntq < 4; ++ntq)
                sc[mtk][ntq] = MFMA16(ak[mtk], bq[ntq], zz);
    }

    // ---- softmax; P [tokq][tokk=64] swz (slot ^ (tokq&7)) overlays Q+K ----
    const float scale = 0.17677669529663687f;  // 32^-0.5
#pragma unroll
    for (int ntq = 0; ntq < 4; ++ntq) {
        float m0 = -1e30f;
#pragma unroll
        for (int mtk = 0; mtk < 4; ++mtk)
#pragma unroll
            for (int r = 0; r < 4; ++r) {
                sc[mtk][ntq][r] *= scale;
                m0 = fmaxf(m0, sc[mtk][ntq][r]);
            }
        m0 = fmaxf(m0, __shfl_xor(m0, 16));
        m0 = fmaxf(m0, __shfl_xor(m0, 32));
        float s0 = 0.f;
#pragma unroll
        for (int mtk = 0; mtk < 4; ++mtk)
#pragma unroll
            for (int r = 0; r < 4; ++r) {
                float p = __expf(sc[mtk][ntq][r] - m0);
                sc[mtk][ntq][r] = p;
                s0 += p;
            }
        s0 += __shfl_xor(s0, 16);
        s0 += __shfl_xor(s0, 32);
        float inv = 1.f / s0;
        const int tokq = ntq * 16 + l16;
#pragma unroll
        for (int mtk = 0; mtk < 4; ++mtk)
            *(uint2v*)&lds[QOFF + tokq * 64 +
                           (((mtk * 2 + (quad >> 1)) ^ (tokq & 7)) << 3) + (quad & 1) * 4] =
                pack4(sc[mtk][ntq][0] * inv, sc[mtk][ntq][1] * inv,
                      sc[mtk][ntq][2] * inv, sc[mtk][ntq][3] * inv);
    }
    __asm__ volatile("s_waitcnt lgkmcnt(0)" ::: "memory");  // within-wave P/V handoff

    // ---- O = P . V ----
    f32x4 ov[4][2];
#pragma unroll
    for (int mt = 0; mt < 4; ++mt)
#pragma unroll
        for (int nv = 0; nv < 2; ++nv) { f32x4 zz = {0.f, 0.f, 0.f, 0.f}; ov[mt][nv] = zz; }
#pragma unroll
    for (int ks = 0; ks < 2; ++ks) {
        bf16x8 ap[4];
#pragma unroll
        for (int mt = 0; mt < 4; ++mt) {
            const int tokq = mt * 16 + l16;
            ap[mt] = frag_ld(&lds[QOFF + tokq * 64 + (((ks * 4 + quad) ^ (tokq & 7)) << 3)]);
        }
#pragma unroll
        for (int nv = 0; nv < 2; ++nv) {
            const int d = nv * 16 + l16;
            bf16x8 bv = frag_ld(&lds[VOFF + d * 64 + (((ks * 4 + quad) ^ (d & 7)) << 3)]);
#pragma unroll
            for (int mt = 0; mt < 4; ++mt)
                ov[mt][nv] = MFMA16(ap[mt], bv, ov[mt][nv]);
        }
    }
    __syncthreads();  // all P/V reads done before O overlays region0

    // ---- O -> LDS [tok][e] s136 @0 ----
#pragma unroll
    for (int mt = 0; mt < 4; ++mt)
#pragma unroll
        for (int nv = 0; nv < 2; ++nv)
#pragma unroll
            for (int r = 0; r < 4; ++r)
                lds[(mt * 16 + quad * 4 + r) * 136 + hb + nv * 16 + l16] =
                    fbf(ov[mt][nv][r]);
    __syncthreads();

    // ---- out-proj: D = O . Wo^T (raw; coef+bias applied in fuse) ----
    f32x4 dp[4][2];
#pragma unroll
    for (int mt = 0; mt < 4; ++mt)
#pragma unroll
        for (int nl = 0; nl < 2; ++nl) { f32x4 zz = {0.f, 0.f, 0.f, 0.f}; dp[mt][nl] = zz; }
#pragma unroll
    for (int ks = 0; ks < 4; ++ks) {
        bf16x8 af[4];
#pragma unroll
        for (int mt = 0; mt < 4; ++mt)
            af[mt] = frag_ld(&lds[(mt * 16 + l16) * 136 + ks * 32 + quad * 8]);
#pragma unroll
        for (int nl = 0; nl < 2; ++nl) {
            const int erow = hb + nl * 16 + l16;
            bf16x8 bw = frag_ld(&wo[erow * 128 + ks * 32 + quad * 8]);
#pragma unroll
            for (int mt = 0; mt < 4; ++mt)
                dp[mt][nl] = MFMA16(af[mt], bw, dp[mt][nl]);
        }
    }
    __syncthreads();  // all O reads done before D overlays the same area

    // ---- D -> LDS [tok][e] s136 @0 ----
#pragma unroll
    for (int mt = 0; mt < 4; ++mt)
#pragma unroll
        for (int nl = 0; nl < 2; ++nl)
#pragma unroll
            for (int r = 0; r < 4; ++r)
                lds[(mt * 16 + quad * 4 + r) * 136 + hb + nl * 16 + l16] =
                    fbf(dp[mt][nl][r]);
    __syncthreads();

    // ---- coalesced att store: thread covers (tok = t>>2, 32 e's) ----
    {
        const int tok2 = t >> 2, eo = (t & 3) * 32;
        unsigned short* op = att + (size_t)n * 8192 + tok2 * 128 + eo;
        const unsigned short* lp = lds + tok2 * 136 + eo;
#pragma unroll
        for (int k4 = 0; k4 < 4; ++k4)
            *(uint4v*)(op + k4 * 8) = *(const uint4v*)(lp + k4 * 8);
    }
}

// ---------------------------------------------------------------- K4: fuse
// gathers <=4 covering windows per pixel with closed-form scan coefs.
__global__ __launch_bounds__(256) void fuse_kernel(
    const unsigned short* __restrict__ comb,  // pixel-major [b][y][x][128]
    const unsigned short* __restrict__ att,   // [n][tok][e] raw out-proj
    const void* __restrict__ vf,
    const float* __restrict__ wf,
    const int* __restrict__ flag,
    void* __restrict__ outp)
{
    __shared__ float enhs[128][65];
    __shared__ float fws[64][65];
    const float* fcw = wf + WF_FCW;
    const float* fcb = wf + WF_FCB;
    const bool f32 = (*flag != 0);
    const int t = threadIdx.x;
    const int wl = t & 63;
    const int eg = __builtin_amdgcn_readfirstlane(t >> 6);
    const int h = blockIdx.y, b = blockIdx.z;
    const int w = blockIdx.x * 64 + wl;

    const int mh = h >> 2, mw = w >> 2;
    const bool vh0 = (mh >= 1), vh1 = (mh <= 30);
    const bool vw0 = (mw >= 1), vw1 = (mw <= 30);
    const int k = ((int)vh0 + (int)vh1) * ((int)vw0 + (int)vw1); // 1,2,4
    const float base7 = (k == 1) ? 0.7f : (k == 2) ? 0.49f : 0.2401f;
    const float bias_c = 1.f - base7;  // sum_j coef_j (out-proj bias weight)

    float cw[4]; int coff[4];
    {
        const bool vs[4] = { vh0 && vw0, vh0 && vw1, vh1 && vw0, vh1 && vw1 };
        const int ihc[4] = { mh - 1, mh - 1, mh, mh };
        const int iwc[4] = { mw - 1, mw, mw - 1, mw };
        int j = 0;
#pragma unroll
        for (int s = 0; s < 4; ++s) {
            if (vs[s]) {
                ++j;
                int e2 = k - j;  // 0..3
                float pw = (e2 == 0) ? 1.f : (e2 == 1) ? 0.7f : (e2 == 2) ? 0.49f : 0.343f;
                cw[s] = 0.3f * pw;
                int nn = (ihc[s] * 31 + iwc[s]) * 4 + b;
                int ll = (h - 4 * ihc[s]) * 8 + (w - 4 * iwc[s]);
                coff[s] = nn * 8192 + ll * 128;
            } else { cw[s] = 0.f; coff[s] = 0; }
        }
    }

    const int cbase = (b * 128) * HW + h * 128 + w;                 // vf/out index
    const size_t cpix = (size_t)(b * 16384 + h * 128 + w) * 128;    // comb record
    const int e0 = eg * 32;
#pragma unroll
    for (int i8 = 0; i8 < 4; ++i8) {
        float av[8];
#pragma unroll
        for (int j = 0; j < 8; ++j)
            av[j] = bias_c * wf[WF_OPB + e0 + i8 * 8 + j];
#pragma unroll
        for (int s = 0; s < 4; ++s) {
            uint4v u = *(const uint4v*)(att + coff[s] + e0 + i8 * 8);
            float x[8];
            unp8(u, x);
#pragma unroll
            for (int j = 0; j < 8; ++j)
                av[j] = fmaf(cw[s], x[j], av[j]);
        }
        uint4v cu = *(const uint4v*)(comb + cpix + e0 + i8 * 8);
        float cx[8];
        unp8(cu, cx);
#pragma unroll
        for (int j = 0; j < 8; ++j)
            enhs[e0 + i8 * 8 + j][wl] = fmaf(base7, cx[j], av[j]);
    }
    __syncthreads();

    float a2[16];
    const int co0 = eg * 16;
#pragma unroll
    for (int i = 0; i < 16; ++i) a2[i] = fcb[co0 + i];
    for (int e = 0; e < 128; ++e) {
        float x = enhs[e][wl];
#pragma unroll
        for (int i = 0; i < 16; ++i)
            a2[i] = fmaf(x, fcw[(co0 + i) * 128 + e], a2[i]);
    }
#pragma unroll
    for (int i = 0; i < 16; ++i)
        fws[co0 + i][wl] = 1.f / (1.f + __expf(-a2[i]));
    __syncthreads();

#pragma unroll
    for (int i = 0; i < 32; ++i) {
        const int e = eg * 32 + i;
        const int idx = cbase + e * HW;
        float val = enhs[e][wl] * fws[e & 63][wl] + ldin(vf, idx, f32);
        if (f32) ((float*)outp)[idx] = val;
        else     ((unsigned short*)outp)[idx] = fbf(val);
    }
}

// ---------------------------------------------------------------------------
extern "C" void kernel_launch(void* const* d_in, const int* in_sizes, int n_in,
                              void* d_out, int out_size, void* d_ws, size_t ws_size,
                              hipStream_t stream)
{
    const void* vf  = d_in[0];
    const void* mw1 = d_in[1];
    const void* mb1 = d_in[2];
    const void* mw2 = d_in[3];
    const void* mb2 = d_in[4];
    const void* aw1 = d_in[5];
    const void* ab1 = d_in[6];
    const void* aw2 = d_in[7];
    const void* ab2 = d_in[8];
    const void* ipw = d_in[9];
    const void* ipb = d_in[10];
    const void* opw = d_in[11];
    const void* opb = d_in[12];
    const void* fcw = d_in[13];
    const void* fcb = d_in[14];

    // ws layout (80,351,232 B total)
    int* flag = (int*)d_ws;                                         // @0
    float* wf = (float*)((char*)d_ws + 1024);                       // 592,896 B
    unsigned short* comb = (unsigned short*)((char*)d_ws + 593920); // 16,777,216 B (pixel-major)
    unsigned short* hidden = (unsigned short*)((char*)d_ws + 17371136); // 8.39 MB
    unsigned short* att = (unsigned short*)((char*)d_ws + 17371136);    // 62,980,096 B (overlays hidden)

    detect_kernel<<<1, 256, 0, stream>>>((const unsigned short*)vf, flag);
    cvtw_kernel<<<(WF_TOTAL + 255) / 256, 256, 0, stream>>>(
        ipw, ipb, opw, opb, fcw, fcb, mw1, mb1, aw1, ab1, mw2, mb2, aw2, ab2, flag, wf);
    conv1_kernel<<<dim3(4, 16, 8), 256, 0, stream>>>(vf, wf, flag, hidden);
    conv2_kernel<<<dim3(4, 16, 16), 256, 0, stream>>>(hidden, wf, comb);
    mha_kernel<<<NSEQ, 256, 0, stream>>>(comb, wf, att);
    fuse_kernel<<<dim3(2, 128, 4), 256, 0, stream>>>(comb, att, vf, wf, flag, d_out);
}

// Round 2
// 418.930 us; speedup vs baseline: 1.0694x; 1.0575x over previous
//
#include <hip/hip_runtime.h>
#include <hip/hip_bf16.h>

// ---------------------------------------------------------------------------
// VectorFieldAttention on MI355X — round 10 (de-spill mha + XCD-chunked map)
//
// r9 post-mortem: __launch_bounds__(256,3) forced <=170 VGPR/wave but the
// kernel needs ~180 (acc[6][4] f32x4 = 96 + ~84 arch) -> scratch spill =
// +106MB WRITE/+38MB FETCH; and blockIdx round-robin over 8 XCDs put
// overlapping windows on different L2s (FETCH 17->54.6MB). dur = traffic/BW.
// r10:
//  * two-pass QKV (Q,K with acc[4][4], then V with accv[2][4], X re-read
//    from LDS) -> peak regs ~130, plain __launch_bounds__(256), 3 blocks/CU
//    via LDS cap with NO spill. Accumulation chains unchanged -> bit-identical.
//  * bijective XCD-chunked batch-major window map: XCD k owns a contiguous
//    raster run (~481 windows, ~2.3MB comb footprint < 4MB L2) -> window
//    overlap reuse restored. att record index unchanged (fuse untouched).
// ws: flag@0 | wf@1024 | comb@593,920 | hidden@17,371,136 (dead after conv2)
//     overlaid by att@17,371,136 (62,980,096 B) -> total 80,351,232 B.
// ---------------------------------------------------------------------------

#define HW 16384           // 128*128
#define NSEQ 3844          // 961 windows * 4 batch

// f32 weight file offsets (floats)
#define WF_IPW 0
#define WF_IPB 49152
#define WF_OPW 49536
#define WF_OPB 65920
#define WF_FCW 66048
#define WF_FCB 74240
#define WF_MW1 74304
#define WF_MB1 92736
#define WF_AW1 92768
#define WF_AB1 111200
#define WF_MW2 111232
#define WF_MB2 129664
#define WF_AW2 129728
#define WF_AB2 148160
#define WF_TOTAL 148224

typedef __bf16 bf16x8 __attribute__((ext_vector_type(8)));
typedef float f32x4 __attribute__((ext_vector_type(4)));
typedef unsigned int uint2v __attribute__((ext_vector_type(2)));
typedef unsigned int uint4v __attribute__((ext_vector_type(4)));

#define MFMA16(a, b, c) __builtin_amdgcn_mfma_f32_16x16x32_bf16((a), (b), (c), 0, 0, 0)

__device__ __forceinline__ float bfu(unsigned short u) {
    union { unsigned int i; float f; } v; v.i = ((unsigned int)u) << 16; return v.f;
}
__device__ __forceinline__ unsigned short fbf(float f) {
    union { float f; unsigned int i; } v; v.f = f;
    unsigned int x = v.i;
    return (unsigned short)((x + 0x7fffu + ((x >> 16) & 1u)) >> 16);
}
__device__ __forceinline__ float ldin(const void* p, long long i, bool f32) {
    return f32 ? ((const float*)p)[i] : bfu(((const unsigned short*)p)[i]);
}
__device__ __forceinline__ bf16x8 frag_ld(const unsigned short* p) {
    union { uint4v u; bf16x8 b; } v;
    v.u = *(const uint4v*)p;
    return v.b;
}
__device__ __forceinline__ uint2v pack4(float a, float b, float c, float d) {
    uint2v r;
    r.x = (unsigned int)fbf(a) | ((unsigned int)fbf(b) << 16);
    r.y = (unsigned int)fbf(c) | ((unsigned int)fbf(d) << 16);
    return r;
}
__device__ __forceinline__ void unp8(uint4v u, float* x) {
    union { unsigned int i; float f; } a;
    a.i = u.x << 16;         x[0] = a.f;
    a.i = u.x & 0xffff0000u; x[1] = a.f;
    a.i = u.y << 16;         x[2] = a.f;
    a.i = u.y & 0xffff0000u; x[3] = a.f;
    a.i = u.z << 16;         x[4] = a.f;
    a.i = u.z & 0xffff0000u; x[5] = a.f;
    a.i = u.w << 16;         x[6] = a.f;
    a.i = u.w & 0xffff0000u; x[7] = a.f;
}

// ------------------------------------------------------------- K-1: detect
__global__ __launch_bounds__(256) void detect_kernel(const unsigned short* __restrict__ vfu,
                                                     int* __restrict__ flag)
{
    __shared__ int cnt;
    if (threadIdx.x == 0) cnt = 0;
    __syncthreads();
    int bad = 0;
    for (int i = threadIdx.x; i < 8192; i += 256) {
        int e = (vfu[i] >> 7) & 0xff;
        if (e < 0x60 || e > 0xA0) ++bad;
    }
    atomicAdd(&cnt, bad);
    __syncthreads();
    if (threadIdx.x == 0) *flag = (cnt > 400) ? 1 : 0;
}

// ---------------------------------------------------------------- K0: weights
__global__ __launch_bounds__(256) void cvtw_kernel(
    const void* ipw, const void* ipb,
    const void* opw, const void* opb,
    const void* fcw, const void* fcb,
    const void* mw1, const void* mb1,
    const void* aw1, const void* ab1,
    const void* mw2, const void* mb2,
    const void* aw2, const void* ab2,
    const int* __restrict__ flag, float* __restrict__ wf)
{
    int i = blockIdx.x * 256 + threadIdx.x;
    if (i >= WF_TOTAL) return;
    const bool f32 = (*flag != 0);
    const void* src; int off;
    if      (i < WF_IPB) { src = ipw; off = WF_IPW; }
    else if (i < WF_OPW) { src = ipb; off = WF_IPB; }
    else if (i < WF_OPB) { src = opw; off = WF_OPW; }
    else if (i < WF_FCW) { src = opb; off = WF_OPB; }
    else if (i < WF_FCB) { src = fcw; off = WF_FCW; }
    else if (i < WF_MW1) { src = fcb; off = WF_FCB; }
    else if (i < WF_MB1) { src = mw1; off = WF_MW1; }
    else if (i < WF_AW1) { src = mb1; off = WF_MB1; }
    else if (i < WF_AB1) { src = aw1; off = WF_AW1; }
    else if (i < WF_MB2) { src = (i < WF_MW2) ? ab1 : mw2; off = (i < WF_MW2) ? WF_AB1 : WF_MW2; }
    else if (i < WF_AW2) { src = mb2; off = WF_MB2; }
    else if (i < WF_AB2) { src = aw2; off = WF_AW2; }
    else                 { src = ab2; off = WF_AB2; }
    float v = ldin(src, i - off, f32);
    if (i < WF_IPB) {
        ((unsigned short*)(wf + WF_IPW))[i] = fbf(v);           // wqkv_bf [384][128]
    } else if (i >= WF_OPW && i < WF_OPB) {
        ((unsigned short*)(wf + WF_OPW))[i - WF_OPW] = fbf(v);  // wo_bf [128][128]
    } else {
        wf[i] = v;
    }
}

// ------------------------------------------------------------- conv3x3 body
// PIXMAJ=false: out channel-major [oc][HW] (hidden). PIXMAJ=true: out
// pixel-major records [pixel][128], writing 8 oc = 16B at +wv*8 (comb).
template<int IC, bool RELU, bool PIXMAJ>
__device__ void conv3x3_body(const void* __restrict__ in, long long in_off, bool f32,
                             const float* __restrict__ w,    // [32][IC][9]
                             const float* __restrict__ bias, // [32]
                             unsigned short* __restrict__ out)
{
    __shared__ float xs[32][10][38];
    const int t = threadIdx.x;
    const int tx0 = blockIdx.x * 32, ty0 = blockIdx.y * 8;
    const int wv = __builtin_amdgcn_readfirstlane(t >> 6);
    const int lane = t & 63;
    const int pr = lane >> 3, pcq = lane & 7;

    float acc[8][4];
#pragma unroll
    for (int oo = 0; oo < 8; ++oo)
#pragma unroll
        for (int p = 0; p < 4; ++p) acc[oo][p] = 0.f;

    for (int cc = 0; cc < IC; cc += 32) {
        if (cc) __syncthreads();
        for (int i = t; i < 32 * 340; i += 256) {
            int c = i / 340, rem = i - c * 340;
            int rr = rem / 34, cx = rem - rr * 34;
            int gy = ty0 + rr - 1, gx = tx0 + cx - 1;
            float v = 0.f;
            if (gy >= 0 && gy < 128 && gx >= 0 && gx < 128)
                v = ldin(in, in_off + (long long)(cc + c) * HW + gy * 128 + gx, f32);
            xs[c][rr][cx] = v;
        }
        __syncthreads();
        for (int c = 0; c < 32; ++c) {
            float xv[3][6];
#pragma unroll
            for (int dy = 0; dy < 3; ++dy)
#pragma unroll
                for (int dx = 0; dx < 6; ++dx)
                    xv[dy][dx] = xs[c][pr + dy][pcq * 4 + dx];
            const float* wr0 = w + (wv * 8 * IC + (cc + c)) * 9;
#pragma unroll
            for (int oo = 0; oo < 8; ++oo) {
                const float* wr = wr0 + oo * IC * 9;
#pragma unroll
                for (int dy = 0; dy < 3; ++dy)
#pragma unroll
                    for (int dx = 0; dx < 3; ++dx) {
                        float wvv = wr[dy * 3 + dx];
#pragma unroll
                        for (int p = 0; p < 4; ++p)
                            acc[oo][p] = fmaf(wvv, xv[dy][p + dx], acc[oo][p]);
                    }
            }
        }
    }
    const int px = tx0 + pcq * 4, py = ty0 + pr;
    if constexpr (PIXMAJ) {
#pragma unroll
        for (int p = 0; p < 4; ++p) {
            union { unsigned short u[8]; uint4v v; } pk;
#pragma unroll
            for (int oo = 0; oo < 8; ++oo) {
                float vv = acc[oo][p] + bias[wv * 8 + oo];
                if (RELU) vv = fmaxf(vv, 0.f);
                pk.u[oo] = fbf(vv);
            }
            *(uint4v*)(out + (size_t)(py * 128 + px + p) * 128 + wv * 8) = pk.v;
        }
    } else {
#pragma unroll
        for (int oo = 0; oo < 8; ++oo) {
            int oc = wv * 8 + oo;
            float bb = bias[oc];
            float v0 = acc[oo][0] + bb, v1 = acc[oo][1] + bb;
            float v2 = acc[oo][2] + bb, v3 = acc[oo][3] + bb;
            if (RELU) {
                v0 = fmaxf(v0, 0.f); v1 = fmaxf(v1, 0.f);
                v2 = fmaxf(v2, 0.f); v3 = fmaxf(v3, 0.f);
            }
            ushort4 pk;
            pk.x = fbf(v0); pk.y = fbf(v1); pk.z = fbf(v2); pk.w = fbf(v3);
            *(ushort4*)(out + oc * HW + py * 128 + px) = pk;
        }
    }
}

__global__ __launch_bounds__(256) void conv1_kernel(const void* __restrict__ vf,
                                                    const float* __restrict__ wf,
                                                    const int* __restrict__ flag,
                                                    unsigned short* __restrict__ hidden)
{
    int z = blockIdx.z, b = z >> 1, br = z & 1;
    const bool f32 = (*flag != 0);
    conv3x3_body<64, true, false>(vf, (long long)(b * 128 + br * 64) * HW, f32,
                                  wf + (br ? WF_AW1 : WF_MW1), wf + (br ? WF_AB1 : WF_MB1),
                                  hidden + (b * 64 + br * 32) * HW);
}

__global__ __launch_bounds__(256) void conv2_kernel(const unsigned short* __restrict__ hidden,
                                                    const float* __restrict__ wf,
                                                    unsigned short* __restrict__ comb)
{
    int z = blockIdx.z, b = z >> 2, br = (z >> 1) & 1, hf = z & 1;
    // comb pixel-major: image base b*16384*128, channel base br*64+hf*32
    conv3x3_body<32, false, true>(hidden, (long long)(b * 64 + br * 32) * HW, false,
                                  wf + (br ? WF_AW2 : WF_MW2) + hf * 32 * 32 * 9,
                                  wf + (br ? WF_AB2 : WF_MB2) + hf * 32,
                                  comb + (size_t)b * 2097152 + br * 64 + hf * 32);
}

// ---------------------------------------------------------------- K3: MHA (MFMA)
// LDS map (ushort units, 25,088 total = 50,176 B -> 3 blocks/CU):
//   region0 @0 (8,704 ush): X [64][136]  ->  V^T 4x[32][64]swz  ->  O/D [64][136]
//   head hh @8,704+hh*4,096: Q [64][32]swz | K @+2,048 [64][32]swz
//                            P [64][64]swz overlays Q+K after scores
// Two-pass QKV keeps peak regs ~130 (no forced min-waves, no spill).
__global__ __launch_bounds__(256) void mha_kernel(
    const unsigned short* __restrict__ comb,   // [b][y][x][e=128] bf16 pixel-major
    const float* __restrict__ wf,
    unsigned short* __restrict__ att)          // [n][tok][e] bf16, raw out-proj
{
    __shared__ unsigned short lds[25088];

    const unsigned short* wqkv = (const unsigned short*)(wf + WF_IPW); // [384][128] bf16
    const unsigned short* wo   = (const unsigned short*)(wf + WF_OPW); // [128][128] bf16

    // Bijective XCD-chunked batch-major map (HW: block i -> XCD i%8).
    // 3844 = 8*480 + 4: XCD 0..3 own 481 windows, XCD 4..7 own 480.
    const int bid = blockIdx.x;
    const int xcd = bid & 7, idx = bid >> 3;
    const int start = (xcd < 4) ? xcd * 481 : 1924 + (xcd - 4) * 480;
    const int nl = start + idx;            // bb*961 + ih*31 + iw (batch-major raster)
    const int bb = nl / 961;
    const int ihw = nl - bb * 961;
    const int ih = ihw / 31, iw = ihw - ih * 31;
    const int n = ihw * 4 + bb;            // att record index (fuse layout unchanged)

    const int t = threadIdx.x;
    const int lane = t & 63, quad = lane >> 4, l16 = lane & 15;
    const int hh = __builtin_amdgcn_readfirstlane(t >> 6);
    const int hb = hh * 32;
    const int QOFF = 8704 + hh * 4096;
    const int KOFF = QOFF + 2048;
    const int VOFF = hh * 2048;

    // ---- stage X [tok][e] s136: wave hh covers window rows 2hh,2hh+1,
    //      each row = 8 px * 256B = 2KB contiguous -> 1KB coalesced per issue ----
#pragma unroll
    for (int rh = 0; rh < 2; ++rh) {
        const int r = hh * 2 + rh;
        const unsigned short* rp = comb +
            (size_t)(bb * 16384 + (ih * 4 + r) * 128 + iw * 4) * 128;
#pragma unroll
        for (int hv = 0; hv < 2; ++hv) {
            uint4v v = *(const uint4v*)(rp + hv * 512 + lane * 8);
            const int tok = r * 8 + hv * 4 + (lane >> 4);
            *(uint4v*)&lds[tok * 136 + (lane & 15) * 8] = v;
        }
    }
    __syncthreads();

    // ---- pass A: Q,K = Wqkv[0:256] . X^T  (acc[4][4] = 64 regs peak) ----
    {
        f32x4 acc[4][4];
#pragma unroll
        for (int nt = 0; nt < 4; ++nt) {
            const int rb = (nt < 2) ? (hb + nt * 16) : (128 + hb + (nt - 2) * 16);
            f32x4 b4;
            b4[0] = wf[WF_IPB + rb + quad * 4 + 0];
            b4[1] = wf[WF_IPB + rb + quad * 4 + 1];
            b4[2] = wf[WF_IPB + rb + quad * 4 + 2];
            b4[3] = wf[WF_IPB + rb + quad * 4 + 3];
#pragma unroll
            for (int mt = 0; mt < 4; ++mt) acc[nt][mt] = b4;
        }
#pragma unroll
        for (int kc = 0; kc < 4; ++kc) {
            bf16x8 bx[4];
#pragma unroll
            for (int mt = 0; mt < 4; ++mt)
                bx[mt] = frag_ld(&lds[(mt * 16 + l16) * 136 + kc * 32 + quad * 8]);
#pragma unroll
            for (int nt = 0; nt < 4; ++nt) {
                const int rb = (nt < 2) ? (hb + nt * 16) : (128 + hb + (nt - 2) * 16);
                bf16x8 aw = frag_ld(&wqkv[(rb + l16) * 128 + kc * 32 + quad * 8]);
#pragma unroll
                for (int mt = 0; mt < 4; ++mt)
                    acc[nt][mt] = MFMA16(aw, bx[mt], acc[nt][mt]);
            }
        }
        // write Q,K: [tok][d=32], 16B-slot swizzle (slot ^ (tok&3))
#pragma unroll
        for (int nt = 0; nt < 2; ++nt)
#pragma unroll
            for (int mt = 0; mt < 4; ++mt) {
                const int tok = mt * 16 + l16;
                const int aoff = tok * 32 + (((nt * 2 + (quad >> 1)) ^ (tok & 3)) << 3)
                               + (quad & 1) * 4;
                *(uint2v*)&lds[QOFF + aoff] =
                    pack4(acc[nt][mt][0], acc[nt][mt][1], acc[nt][mt][2], acc[nt][mt][3]);
                *(uint2v*)&lds[KOFF + aoff] =
                    pack4(acc[nt + 2][mt][0], acc[nt + 2][mt][1],
                          acc[nt + 2][mt][2], acc[nt + 2][mt][3]);
            }
    }

    // ---- pass B: V = Wqkv[256:384] . X^T  (accv[2][4] = 32 regs) ----
    f32x4 accv[2][4];
#pragma unroll
    for (int nv = 0; nv < 2; ++nv) {
        const int rb = 256 + hb + nv * 16;
        f32x4 b4;
        b4[0] = wf[WF_IPB + rb + quad * 4 + 0];
        b4[1] = wf[WF_IPB + rb + quad * 4 + 1];
        b4[2] = wf[WF_IPB + rb + quad * 4 + 2];
        b4[3] = wf[WF_IPB + rb + quad * 4 + 3];
#pragma unroll
        for (int mt = 0; mt < 4; ++mt) accv[nv][mt] = b4;
    }
#pragma unroll
    for (int kc = 0; kc < 4; ++kc) {
        bf16x8 bx[4];
#pragma unroll
        for (int mt = 0; mt < 4; ++mt)
            bx[mt] = frag_ld(&lds[(mt * 16 + l16) * 136 + kc * 32 + quad * 8]);
#pragma unroll
        for (int nv = 0; nv < 2; ++nv) {
            const int rb = 256 + hb + nv * 16;
            bf16x8 aw = frag_ld(&wqkv[(rb + l16) * 128 + kc * 32 + quad * 8]);
#pragma unroll
            for (int mt = 0; mt < 4; ++mt)
                accv[nv][mt] = MFMA16(aw, bx[mt], accv[nv][mt]);
        }
    }
    __syncthreads();   // all waves done reading X -> region0 reusable; Q/K drained

    // ---- V^T [d=32][tok=64] swz (slot ^ (d&7)), overlays dead X ----
#pragma unroll
    for (int nv = 0; nv < 2; ++nv)
#pragma unroll
        for (int mt = 0; mt < 4; ++mt)
#pragma unroll
            for (int r = 0; r < 4; ++r) {
                const int d = nv * 16 + quad * 4 + r;
                const int tok = mt * 16 + l16;
                lds[VOFF + d * 64 + (((tok >> 3) ^ (d & 7)) << 3) + (tok & 7)] =
                    fbf(accv[nv][mt][r]);
            }

    // ---- scores: S^T = K . Q^T ----
    bf16x8 ak[4], bq[4];
#pragma unroll
    for (int mtk = 0; mtk < 4; ++mtk) {
        const int tok = mtk * 16 + l16;
        ak[mtk] = frag_ld(&lds[KOFF + tok * 32 + ((quad ^ (tok & 3)) << 3)]);
    }
#pragma unroll
    for (int ntq = 0; ntq < 4; ++ntq) {
        const int tok = ntq * 16 + l16;
        bq[ntq] = frag_ld(&lds[QOFF + tok * 32 + ((quad ^ (tok & 3)) << 3)]);
    }
    f32x4 sc[4][4];
    {
        f32x4 zz = {0.f, 0.f, 0.f, 0.f};
#pragma unroll
        for (int mtk = 0; mtk < 4; ++mtk)
#pragma unroll
            for (int ntq = 0; ntq < 4; ++ntq)
                sc[mtk][ntq] = MFMA16(ak[mtk], bq[ntq], zz);
    }

    // ---- softmax; P [tokq][tokk=64] swz (slot ^ (tokq&7)) overlays Q+K ----
    const float scale = 0.17677669529663687f;  // 32^-0.5
#pragma unroll
    for (int ntq = 0; ntq < 4; ++ntq) {
        float m0 = -1e30f;
#pragma unroll
        for (int mtk = 0; mtk < 4; ++mtk)
#pragma unroll
            for (int r = 0; r < 4; ++r) {
                sc[mtk][ntq][r] *= scale;
                m0 = fmaxf(m0, sc[mtk][ntq][r]);
            }
        m0 = fmaxf(m0, __shfl_xor(m0, 16));
        m0 = fmaxf(m0, __shfl_xor(m0, 32));
        float s0 = 0.f;
#pragma unroll
        for (int mtk = 0; mtk < 4; ++mtk)
#pragma unroll
            for (int r = 0; r < 4; ++r) {
                float p = __expf(sc[mtk][ntq][r] - m0);
                sc[mtk][ntq][r] = p;
                s0 += p;
            }
        s0 += __shfl_xor(s0, 16);
        s0 += __shfl_xor(s0, 32);
        float inv = 1.f / s0;
        const int tokq = ntq * 16 + l16;
#pragma unroll
        for (int mtk = 0; mtk < 4; ++mtk)
            *(uint2v*)&lds[QOFF + tokq * 64 +
                           (((mtk * 2 + (quad >> 1)) ^ (tokq & 7)) << 3) + (quad & 1) * 4] =
                pack4(sc[mtk][ntq][0] * inv, sc[mtk][ntq][1] * inv,
                      sc[mtk][ntq][2] * inv, sc[mtk][ntq][3] * inv);
    }
    __asm__ volatile("s_waitcnt lgkmcnt(0)" ::: "memory");  // within-wave P/V handoff

    // ---- O = P . V ----
    f32x4 ov[4][2];
#pragma unroll
    for (int mt = 0; mt < 4; ++mt)
#pragma unroll
        for (int nv = 0; nv < 2; ++nv) { f32x4 zz = {0.f, 0.f, 0.f, 0.f}; ov[mt][nv] = zz; }
#pragma unroll
    for (int ks = 0; ks < 2; ++ks) {
        bf16x8 ap[4];
#pragma unroll
        for (int mt = 0; mt < 4; ++mt) {
            const int tokq = mt * 16 + l16;
            ap[mt] = frag_ld(&lds[QOFF + tokq * 64 + (((ks * 4 + quad) ^ (tokq & 7)) << 3)]);
        }
#pragma unroll
        for (int nv = 0; nv < 2; ++nv) {
            const int d = nv * 16 + l16;
            bf16x8 bv = frag_ld(&lds[VOFF + d * 64 + (((ks * 4 + quad) ^ (d & 7)) << 3)]);
#pragma unroll
            for (int mt = 0; mt < 4; ++mt)
                ov[mt][nv] = MFMA16(ap[mt], bv, ov[mt][nv]);
        }
    }
    __syncthreads();  // all P/V reads done before O overlays region0

    // ---- O -> LDS [tok][e] s136 @0 ----
#pragma unroll
    for (int mt = 0; mt < 4; ++mt)
#pragma unroll
        for (int nv = 0; nv < 2; ++nv)
#pragma unroll
            for (int r = 0; r < 4; ++r)
                lds[(mt * 16 + quad * 4 + r) * 136 + hb + nv * 16 + l16] =
                    fbf(ov[mt][nv][r]);
    __syncthreads();

    // ---- out-proj: D = O . Wo^T (raw; coef+bias applied in fuse) ----
    f32x4 dp[4][2];
#pragma unroll
    for (int mt = 0; mt < 4; ++mt)
#pragma unroll
        for (int nl = 0; nl < 2; ++nl) { f32x4 zz = {0.f, 0.f, 0.f, 0.f}; dp[mt][nl] = zz; }
#pragma unroll
    for (int ks = 0; ks < 4; ++ks) {
        bf16x8 af[4];
#pragma unroll
        for (int mt = 0; mt < 4; ++mt)
            af[mt] = frag_ld(&lds[(mt * 16 + l16) * 136 + ks * 32 + quad * 8]);
#pragma unroll
        for (int nl = 0; nl < 2; ++nl) {
            const int erow = hb + nl * 16 + l16;
            bf16x8 bw = frag_ld(&wo[erow * 128 + ks * 32 + quad * 8]);
#pragma unroll
            for (int mt = 0; mt < 4; ++mt)
                dp[mt][nl] = MFMA16(af[mt], bw, dp[mt][nl]);
        }
    }
    __syncthreads();  // all O reads done before D overlays the same area

    // ---- D -> LDS [tok][e] s136 @0 ----
#pragma unroll
    for (int mt = 0; mt < 4; ++mt)
#pragma unroll
        for (int nl = 0; nl < 2; ++nl)
#pragma unroll
            for (int r = 0; r < 4; ++r)
                lds[(mt * 16 + quad * 4 + r) * 136 + hb + nl * 16 + l16] =
                    fbf(dp[mt][nl][r]);
    __syncthreads();

    // ---- coalesced att store: thread covers (tok = t>>2, 32 e's) ----
    {
        const int tok2 = t >> 2, eo = (t & 3) * 32;
        unsigned short* op = att + (size_t)n * 8192 + tok2 * 128 + eo;
        const unsigned short* lp = lds + tok2 * 136 + eo;
#pragma unroll
        for (int k4 = 0; k4 < 4; ++k4)
            *(uint4v*)(op + k4 * 8) = *(const uint4v*)(lp + k4 * 8);
    }
}

// ---------------------------------------------------------------- K4: fuse
// gathers <=4 covering windows per pixel with closed-form scan coefs.
__global__ __launch_bounds__(256) void fuse_kernel(
    const unsigned short* __restrict__ comb,  // pixel-major [b][y][x][128]
    const unsigned short* __restrict__ att,   // [n][tok][e] raw out-proj
    const void* __restrict__ vf,
    const float* __restrict__ wf,
    const int* __restrict__ flag,
    void* __restrict__ outp)
{
    __shared__ float enhs[128][65];
    __shared__ float fws[64][65];
    const float* fcw = wf + WF_FCW;
    const float* fcb = wf + WF_FCB;
    const bool f32 = (*flag != 0);
    const int t = threadIdx.x;
    const int wl = t & 63;
    const int eg = __builtin_amdgcn_readfirstlane(t >> 6);
    const int h = blockIdx.y, b = blockIdx.z;
    const int w = blockIdx.x * 64 + wl;

    const int mh = h >> 2, mw = w >> 2;
    const bool vh0 = (mh >= 1), vh1 = (mh <= 30);
    const bool vw0 = (mw >= 1), vw1 = (mw <= 30);
    const int k = ((int)vh0 + (int)vh1) * ((int)vw0 + (int)vw1); // 1,2,4
    const float base7 = (k == 1) ? 0.7f : (k == 2) ? 0.49f : 0.2401f;
    const float bias_c = 1.f - base7;  // sum_j coef_j (out-proj bias weight)

    float cw[4]; int coff[4];
    {
        const bool vs[4] = { vh0 && vw0, vh0 && vw1, vh1 && vw0, vh1 && vw1 };
        const int ihc[4] = { mh - 1, mh - 1, mh, mh };
        const int iwc[4] = { mw - 1, mw, mw - 1, mw };
        int j = 0;
#pragma unroll
        for (int s = 0; s < 4; ++s) {
            if (vs[s]) {
                ++j;
                int e2 = k - j;  // 0..3
                float pw = (e2 == 0) ? 1.f : (e2 == 1) ? 0.7f : (e2 == 2) ? 0.49f : 0.343f;
                cw[s] = 0.3f * pw;
                int nn = (ihc[s] * 31 + iwc[s]) * 4 + b;
                int ll = (h - 4 * ihc[s]) * 8 + (w - 4 * iwc[s]);
                coff[s] = nn * 8192 + ll * 128;
            } else { cw[s] = 0.f; coff[s] = 0; }
        }
    }

    const int cbase = (b * 128) * HW + h * 128 + w;                 // vf/out index
    const size_t cpix = (size_t)(b * 16384 + h * 128 + w) * 128;    // comb record
    const int e0 = eg * 32;
#pragma unroll
    for (int i8 = 0; i8 < 4; ++i8) {
        float av[8];
#pragma unroll
        for (int j = 0; j < 8; ++j)
            av[j] = bias_c * wf[WF_OPB + e0 + i8 * 8 + j];
#pragma unroll
        for (int s = 0; s < 4; ++s) {
            uint4v u = *(const uint4v*)(att + coff[s] + e0 + i8 * 8);
            float x[8];
            unp8(u, x);
#pragma unroll
            for (int j = 0; j < 8; ++j)
                av[j] = fmaf(cw[s], x[j], av[j]);
        }
        uint4v cu = *(const uint4v*)(comb + cpix + e0 + i8 * 8);
        float cx[8];
        unp8(cu, cx);
#pragma unroll
        for (int j = 0; j < 8; ++j)
            enhs[e0 + i8 * 8 + j][wl] = fmaf(base7, cx[j], av[j]);
    }
    __syncthreads();

    float a2[16];
    const int co0 = eg * 16;
#pragma unroll
    for (int i = 0; i < 16; ++i) a2[i] = fcb[co0 + i];
    for (int e = 0; e < 128; ++e) {
        float x = enhs[e][wl];
#pragma unroll
        for (int i = 0; i < 16; ++i)
            a2[i] = fmaf(x, fcw[(co0 + i) * 128 + e], a2[i]);
    }
#pragma unroll
    for (int i = 0; i < 16; ++i)
        fws[co0 + i][wl] = 1.f / (1.f + __expf(-a2[i]));
    __syncthreads();

#pragma unroll
    for (int i = 0; i < 32; ++i) {
        const int e = eg * 32 + i;
        const int idx = cbase + e * HW;
        float val = enhs[e][wl] * fws[e & 63][wl] + ldin(vf, idx, f32);
        if (f32) ((float*)outp)[idx] = val;
        else     ((unsigned short*)outp)[idx] = fbf(val);
    }
}

// ---------------------------------------------------------------------------
extern "C" void kernel_launch(void* const* d_in, const int* in_sizes, int n_in,
                              void* d_out, int out_size, void* d_ws, size_t ws_size,
                              hipStream_t stream)
{
    const void* vf  = d_in[0];
    const void* mw1 = d_in[1];
    const void* mb1 = d_in[2];
    const void* mw2 = d_in[3];
    const void* mb2 = d_in[4];
    const void* aw1 = d_in[5];
    const void* ab1 = d_in[6];
    const void* aw2 = d_in[7];
    const void* ab2 = d_in[8];
    const void* ipw = d_in[9];
    const void* ipb = d_in[10];
    const void* opw = d_in[11];
    const void* opb = d_in[12];
    const void* fcw = d_in[13];
    const void* fcb = d_in[14];

    // ws layout (80,351,232 B total)
    int* flag = (int*)d_ws;                                         // @0
    float* wf = (float*)((char*)d_ws + 1024);                       // 592,896 B
    unsigned short* comb = (unsigned short*)((char*)d_ws + 593920); // 16,777,216 B (pixel-major)
    unsigned short* hidden = (unsigned short*)((char*)d_ws + 17371136); // 8.39 MB
    unsigned short* att = (unsigned short*)((char*)d_ws + 17371136);    // 62,980,096 B (overlays hidden)

    detect_kernel<<<1, 256, 0, stream>>>((const unsigned short*)vf, flag);
    cvtw_kernel<<<(WF_TOTAL + 255) / 256, 256, 0, stream>>>(
        ipw, ipb, opw, opb, fcw, fcb, mw1, mb1, aw1, ab1, mw2, mb2, aw2, ab2, flag, wf);
    conv1_kernel<<<dim3(4, 16, 8), 256, 0, stream>>>(vf, wf, flag, hidden);
    conv2_kernel<<<dim3(4, 16, 16), 256, 0, stream>>>(hidden, wf, comb);
    mha_kernel<<<NSEQ, 256, 0, stream>>>(comb, wf, att);
    fuse_kernel<<<dim3(2, 128, 4), 256, 0, stream>>>(comb, att, vf, wf, flag, d_out);
}

// Round 3
// 395.732 us; speedup vs baseline: 1.1321x; 1.0586x over previous
//
#include <hip/hip_runtime.h>
#include <hip/hip_bf16.h>

// ---------------------------------------------------------------------------
// VectorFieldAttention on MI355X — round 11 (HW bf16 cvt + conv occupancy)
//
// r10 post-mortem: spill gone (WRITE 61.5MB), L2 reuse back (FETCH 9.1MB).
// mha 100us: VALUBusy 46% dominated by ~224 software-RNE fbf per thread
// (~1800 cyc/wave vs ~800 cyc MFMA). conv1 101us: 512 blocks -> 2 blocks/CU,
// latency-bound at VALUBusy 44%.
// r11:
//  * v_cvt_pk_bf16_f32 (HW RNE, bit-identical to sw fbf) replaces fbf in all
//    hot paths: mha pack4/V^T/O/D, conv epilogues, fuse store.
//  * conv tiles 32x8 -> 32x4 (2 px/thread, xs[32][6][37] odd stride = 28.4KB)
//    -> conv1 1024 / conv2 2048 blocks, ~5 blocks/CU, same fma order.
// Math order unchanged -> absmax must stay 0.03125.
// ws: flag@0 | wf@1024 | comb@593,920 | hidden@17,371,136 (dead after conv2)
//     overlaid by att@17,371,136 (62,980,096 B) -> total 80,351,232 B.
// ---------------------------------------------------------------------------

#define HW 16384           // 128*128
#define NSEQ 3844          // 961 windows * 4 batch

// f32 weight file offsets (floats)
#define WF_IPW 0
#define WF_IPB 49152
#define WF_OPW 49536
#define WF_OPB 65920
#define WF_FCW 66048
#define WF_FCB 74240
#define WF_MW1 74304
#define WF_MB1 92736
#define WF_AW1 92768
#define WF_AB1 111200
#define WF_MW2 111232
#define WF_MB2 129664
#define WF_AW2 129728
#define WF_AB2 148160
#define WF_TOTAL 148224

typedef __bf16 bf16x8 __attribute__((ext_vector_type(8)));
typedef float f32x4 __attribute__((ext_vector_type(4)));
typedef unsigned int uint2v __attribute__((ext_vector_type(2)));
typedef unsigned int uint4v __attribute__((ext_vector_type(4)));

#define MFMA16(a, b, c) __builtin_amdgcn_mfma_f32_16x16x32_bf16((a), (b), (c), 0, 0, 0)

__device__ __forceinline__ float bfu(unsigned short u) {
    union { unsigned int i; float f; } v; v.i = ((unsigned int)u) << 16; return v.f;
}
// software RNE (cold paths only; bit-identical to v_cvt_pk_bf16_f32)
__device__ __forceinline__ unsigned short fbf(float f) {
    union { float f; unsigned int i; } v; v.f = f;
    unsigned int x = v.i;
    return (unsigned short)((x + 0x7fffu + ((x >> 16) & 1u)) >> 16);
}
// HW RNE pack: lo16 = bf16(a), hi16 = bf16(b). 1 VALU op.
__device__ __forceinline__ unsigned int cvt_pk_bf16(float a, float b) {
    unsigned int r;
    asm("v_cvt_pk_bf16_f32 %0, %1, %2" : "=v"(r) : "v"(a), "v"(b));
    return r;
}
__device__ __forceinline__ unsigned short fbf_hw(float f) {
    return (unsigned short)cvt_pk_bf16(f, f);
}
__device__ __forceinline__ float ldin(const void* p, long long i, bool f32) {
    return f32 ? ((const float*)p)[i] : bfu(((const unsigned short*)p)[i]);
}
__device__ __forceinline__ bf16x8 frag_ld(const unsigned short* p) {
    union { uint4v u; bf16x8 b; } v;
    v.u = *(const uint4v*)p;
    return v.b;
}
__device__ __forceinline__ uint2v pack4(float a, float b, float c, float d) {
    uint2v r;
    r.x = cvt_pk_bf16(a, b);
    r.y = cvt_pk_bf16(c, d);
    return r;
}
__device__ __forceinline__ void unp8(uint4v u, float* x) {
    union { unsigned int i; float f; } a;
    a.i = u.x << 16;         x[0] = a.f;
    a.i = u.x & 0xffff0000u; x[1] = a.f;
    a.i = u.y << 16;         x[2] = a.f;
    a.i = u.y & 0xffff0000u; x[3] = a.f;
    a.i = u.z << 16;         x[4] = a.f;
    a.i = u.z & 0xffff0000u; x[5] = a.f;
    a.i = u.w << 16;         x[6] = a.f;
    a.i = u.w & 0xffff0000u; x[7] = a.f;
}

// ------------------------------------------------------------- K-1: detect
__global__ __launch_bounds__(256) void detect_kernel(const unsigned short* __restrict__ vfu,
                                                     int* __restrict__ flag)
{
    __shared__ int cnt;
    if (threadIdx.x == 0) cnt = 0;
    __syncthreads();
    int bad = 0;
    for (int i = threadIdx.x; i < 8192; i += 256) {
        int e = (vfu[i] >> 7) & 0xff;
        if (e < 0x60 || e > 0xA0) ++bad;
    }
    atomicAdd(&cnt, bad);
    __syncthreads();
    if (threadIdx.x == 0) *flag = (cnt > 400) ? 1 : 0;
}

// ---------------------------------------------------------------- K0: weights
__global__ __launch_bounds__(256) void cvtw_kernel(
    const void* ipw, const void* ipb,
    const void* opw, const void* opb,
    const void* fcw, const void* fcb,
    const void* mw1, const void* mb1,
    const void* aw1, const void* ab1,
    const void* mw2, const void* mb2,
    const void* aw2, const void* ab2,
    const int* __restrict__ flag, float* __restrict__ wf)
{
    int i = blockIdx.x * 256 + threadIdx.x;
    if (i >= WF_TOTAL) return;
    const bool f32 = (*flag != 0);
    const void* src; int off;
    if      (i < WF_IPB) { src = ipw; off = WF_IPW; }
    else if (i < WF_OPW) { src = ipb; off = WF_IPB; }
    else if (i < WF_OPB) { src = opw; off = WF_OPW; }
    else if (i < WF_FCW) { src = opb; off = WF_OPB; }
    else if (i < WF_FCB) { src = fcw; off = WF_FCW; }
    else if (i < WF_MW1) { src = fcb; off = WF_FCB; }
    else if (i < WF_MB1) { src = mw1; off = WF_MW1; }
    else if (i < WF_AW1) { src = mb1; off = WF_MB1; }
    else if (i < WF_AB1) { src = aw1; off = WF_AW1; }
    else if (i < WF_MB2) { src = (i < WF_MW2) ? ab1 : mw2; off = (i < WF_MW2) ? WF_AB1 : WF_MW2; }
    else if (i < WF_AW2) { src = mb2; off = WF_MB2; }
    else if (i < WF_AB2) { src = aw2; off = WF_AW2; }
    else                 { src = ab2; off = WF_AB2; }
    float v = ldin(src, i - off, f32);
    if (i < WF_IPB) {
        ((unsigned short*)(wf + WF_IPW))[i] = fbf(v);           // wqkv_bf [384][128]
    } else if (i >= WF_OPW && i < WF_OPB) {
        ((unsigned short*)(wf + WF_OPW))[i - WF_OPW] = fbf(v);  // wo_bf [128][128]
    } else {
        wf[i] = v;
    }
}

// ------------------------------------------------------------- conv3x3 body
// 32x4 tile, 2 px/thread. PIXMAJ=false: out channel-major [oc][HW] (hidden).
// PIXMAJ=true: pixel-major records [pixel][128], 16B at +wv*8 (comb).
template<int IC, bool RELU, bool PIXMAJ>
__device__ void conv3x3_body(const void* __restrict__ in, long long in_off, bool f32,
                             const float* __restrict__ w,    // [32][IC][9]
                             const float* __restrict__ bias, // [32]
                             unsigned short* __restrict__ out)
{
    __shared__ float xs[32][6][37];   // 6 rows (4+2 halo), 34 cols used, odd stride
    const int t = threadIdx.x;
    const int tx0 = blockIdx.x * 32, ty0 = blockIdx.y * 4;
    const int wv = __builtin_amdgcn_readfirstlane(t >> 6);
    const int lane = t & 63;
    const int pr = lane >> 4, pc2 = lane & 15;   // 4 rows x 16 pairs

    float acc[8][2];
#pragma unroll
    for (int oo = 0; oo < 8; ++oo)
#pragma unroll
        for (int p = 0; p < 2; ++p) acc[oo][p] = 0.f;

    for (int cc = 0; cc < IC; cc += 32) {
        if (cc) __syncthreads();
        for (int i = t; i < 32 * 204; i += 256) {
            int c = i / 204, rem = i - c * 204;
            int rr = rem / 34, cx = rem - rr * 34;
            int gy = ty0 + rr - 1, gx = tx0 + cx - 1;
            float v = 0.f;
            if (gy >= 0 && gy < 128 && gx >= 0 && gx < 128)
                v = ldin(in, in_off + (long long)(cc + c) * HW + gy * 128 + gx, f32);
            xs[c][rr][cx] = v;
        }
        __syncthreads();
        for (int c = 0; c < 32; ++c) {
            float xv[3][4];
#pragma unroll
            for (int dy = 0; dy < 3; ++dy)
#pragma unroll
                for (int dx = 0; dx < 4; ++dx)
                    xv[dy][dx] = xs[c][pr + dy][pc2 * 2 + dx];
            const float* wr0 = w + (wv * 8 * IC + (cc + c)) * 9;
#pragma unroll
            for (int oo = 0; oo < 8; ++oo) {
                const float* wr = wr0 + oo * IC * 9;
#pragma unroll
                for (int dy = 0; dy < 3; ++dy)
#pragma unroll
                    for (int dx = 0; dx < 3; ++dx) {
                        float wvv = wr[dy * 3 + dx];
#pragma unroll
                        for (int p = 0; p < 2; ++p)
                            acc[oo][p] = fmaf(wvv, xv[dy][p + dx], acc[oo][p]);
                    }
            }
        }
    }
    const int px = tx0 + pc2 * 2, py = ty0 + pr;
    if constexpr (PIXMAJ) {
#pragma unroll
        for (int p = 0; p < 2; ++p) {
            union { unsigned int u32[4]; uint4v v; } pk;
#pragma unroll
            for (int j = 0; j < 4; ++j) {
                float v0 = acc[2 * j][p] + bias[wv * 8 + 2 * j];
                float v1 = acc[2 * j + 1][p] + bias[wv * 8 + 2 * j + 1];
                if (RELU) { v0 = fmaxf(v0, 0.f); v1 = fmaxf(v1, 0.f); }
                pk.u32[j] = cvt_pk_bf16(v0, v1);
            }
            *(uint4v*)(out + (size_t)(py * 128 + px + p) * 128 + wv * 8) = pk.v;
        }
    } else {
#pragma unroll
        for (int oo = 0; oo < 8; ++oo) {
            int oc = wv * 8 + oo;
            float bb = bias[oc];
            float v0 = acc[oo][0] + bb, v1 = acc[oo][1] + bb;
            if (RELU) { v0 = fmaxf(v0, 0.f); v1 = fmaxf(v1, 0.f); }
            *(unsigned int*)(out + oc * HW + py * 128 + px) = cvt_pk_bf16(v0, v1);
        }
    }
}

__global__ __launch_bounds__(256) void conv1_kernel(const void* __restrict__ vf,
                                                    const float* __restrict__ wf,
                                                    const int* __restrict__ flag,
                                                    unsigned short* __restrict__ hidden)
{
    int z = blockIdx.z, b = z >> 1, br = z & 1;
    const bool f32 = (*flag != 0);
    conv3x3_body<64, true, false>(vf, (long long)(b * 128 + br * 64) * HW, f32,
                                  wf + (br ? WF_AW1 : WF_MW1), wf + (br ? WF_AB1 : WF_MB1),
                                  hidden + (b * 64 + br * 32) * HW);
}

__global__ __launch_bounds__(256) void conv2_kernel(const unsigned short* __restrict__ hidden,
                                                    const float* __restrict__ wf,
                                                    unsigned short* __restrict__ comb)
{
    int z = blockIdx.z, b = z >> 2, br = (z >> 1) & 1, hf = z & 1;
    // comb pixel-major: image base b*16384*128, channel base br*64+hf*32
    conv3x3_body<32, false, true>(hidden, (long long)(b * 64 + br * 32) * HW, false,
                                  wf + (br ? WF_AW2 : WF_MW2) + hf * 32 * 32 * 9,
                                  wf + (br ? WF_AB2 : WF_MB2) + hf * 32,
                                  comb + (size_t)b * 2097152 + br * 64 + hf * 32);
}

// ---------------------------------------------------------------- K3: MHA (MFMA)
// LDS map (ushort units, 25,088 total = 50,176 B -> 3 blocks/CU):
//   region0 @0 (8,704 ush): X [64][136]  ->  V^T 4x[32][64]swz  ->  O/D [64][136]
//   head hh @8,704+hh*4,096: Q [64][32]swz | K @+2,048 [64][32]swz
//                            P [64][64]swz overlays Q+K after scores
// Two-pass QKV keeps peak regs ~130 (no forced min-waves, no spill).
__global__ __launch_bounds__(256) void mha_kernel(
    const unsigned short* __restrict__ comb,   // [b][y][x][e=128] bf16 pixel-major
    const float* __restrict__ wf,
    unsigned short* __restrict__ att)          // [n][tok][e] bf16, raw out-proj
{
    __shared__ unsigned short lds[25088];

    const unsigned short* wqkv = (const unsigned short*)(wf + WF_IPW); // [384][128] bf16
    const unsigned short* wo   = (const unsigned short*)(wf + WF_OPW); // [128][128] bf16

    // Bijective XCD-chunked batch-major map (HW: block i -> XCD i%8).
    // 3844 = 8*480 + 4: XCD 0..3 own 481 windows, XCD 4..7 own 480.
    const int bid = blockIdx.x;
    const int xcd = bid & 7, idx = bid >> 3;
    const int start = (xcd < 4) ? xcd * 481 : 1924 + (xcd - 4) * 480;
    const int nl = start + idx;            // bb*961 + ih*31 + iw (batch-major raster)
    const int bb = nl / 961;
    const int ihw = nl - bb * 961;
    const int ih = ihw / 31, iw = ihw - ih * 31;
    const int n = ihw * 4 + bb;            // att record index (fuse layout unchanged)

    const int t = threadIdx.x;
    const int lane = t & 63, quad = lane >> 4, l16 = lane & 15;
    const int hh = __builtin_amdgcn_readfirstlane(t >> 6);
    const int hb = hh * 32;
    const int QOFF = 8704 + hh * 4096;
    const int KOFF = QOFF + 2048;
    const int VOFF = hh * 2048;

    // ---- stage X [tok][e] s136: wave hh covers window rows 2hh,2hh+1,
    //      each row = 8 px * 256B = 2KB contiguous -> 1KB coalesced per issue ----
#pragma unroll
    for (int rh = 0; rh < 2; ++rh) {
        const int r = hh * 2 + rh;
        const unsigned short* rp = comb +
            (size_t)(bb * 16384 + (ih * 4 + r) * 128 + iw * 4) * 128;
#pragma unroll
        for (int hv = 0; hv < 2; ++hv) {
            uint4v v = *(const uint4v*)(rp + hv * 512 + lane * 8);
            const int tok = r * 8 + hv * 4 + (lane >> 4);
            *(uint4v*)&lds[tok * 136 + (lane & 15) * 8] = v;
        }
    }
    __syncthreads();

    // ---- pass A: Q,K = Wqkv[0:256] . X^T  (acc[4][4] = 64 regs peak) ----
    {
        f32x4 acc[4][4];
#pragma unroll
        for (int nt = 0; nt < 4; ++nt) {
            const int rb = (nt < 2) ? (hb + nt * 16) : (128 + hb + (nt - 2) * 16);
            f32x4 b4;
            b4[0] = wf[WF_IPB + rb + quad * 4 + 0];
            b4[1] = wf[WF_IPB + rb + quad * 4 + 1];
            b4[2] = wf[WF_IPB + rb + quad * 4 + 2];
            b4[3] = wf[WF_IPB + rb + quad * 4 + 3];
#pragma unroll
            for (int mt = 0; mt < 4; ++mt) acc[nt][mt] = b4;
        }
#pragma unroll
        for (int kc = 0; kc < 4; ++kc) {
            bf16x8 bx[4];
#pragma unroll
            for (int mt = 0; mt < 4; ++mt)
                bx[mt] = frag_ld(&lds[(mt * 16 + l16) * 136 + kc * 32 + quad * 8]);
#pragma unroll
            for (int nt = 0; nt < 4; ++nt) {
                const int rb = (nt < 2) ? (hb + nt * 16) : (128 + hb + (nt - 2) * 16);
                bf16x8 aw = frag_ld(&wqkv[(rb + l16) * 128 + kc * 32 + quad * 8]);
#pragma unroll
                for (int mt = 0; mt < 4; ++mt)
                    acc[nt][mt] = MFMA16(aw, bx[mt], acc[nt][mt]);
            }
        }
        // write Q,K: [tok][d=32], 16B-slot swizzle (slot ^ (tok&3))
#pragma unroll
        for (int nt = 0; nt < 2; ++nt)
#pragma unroll
            for (int mt = 0; mt < 4; ++mt) {
                const int tok = mt * 16 + l16;
                const int aoff = tok * 32 + (((nt * 2 + (quad >> 1)) ^ (tok & 3)) << 3)
                               + (quad & 1) * 4;
                *(uint2v*)&lds[QOFF + aoff] =
                    pack4(acc[nt][mt][0], acc[nt][mt][1], acc[nt][mt][2], acc[nt][mt][3]);
                *(uint2v*)&lds[KOFF + aoff] =
                    pack4(acc[nt + 2][mt][0], acc[nt + 2][mt][1],
                          acc[nt + 2][mt][2], acc[nt + 2][mt][3]);
            }
    }

    // ---- pass B: V = Wqkv[256:384] . X^T  (accv[2][4] = 32 regs) ----
    f32x4 accv[2][4];
#pragma unroll
    for (int nv = 0; nv < 2; ++nv) {
        const int rb = 256 + hb + nv * 16;
        f32x4 b4;
        b4[0] = wf[WF_IPB + rb + quad * 4 + 0];
        b4[1] = wf[WF_IPB + rb + quad * 4 + 1];
        b4[2] = wf[WF_IPB + rb + quad * 4 + 2];
        b4[3] = wf[WF_IPB + rb + quad * 4 + 3];
#pragma unroll
        for (int mt = 0; mt < 4; ++mt) accv[nv][mt] = b4;
    }
#pragma unroll
    for (int kc = 0; kc < 4; ++kc) {
        bf16x8 bx[4];
#pragma unroll
        for (int mt = 0; mt < 4; ++mt)
            bx[mt] = frag_ld(&lds[(mt * 16 + l16) * 136 + kc * 32 + quad * 8]);
#pragma unroll
        for (int nv = 0; nv < 2; ++nv) {
            const int rb = 256 + hb + nv * 16;
            bf16x8 aw = frag_ld(&wqkv[(rb + l16) * 128 + kc * 32 + quad * 8]);
#pragma unroll
            for (int mt = 0; mt < 4; ++mt)
                accv[nv][mt] = MFMA16(aw, bx[mt], accv[nv][mt]);
        }
    }
    __syncthreads();   // all waves done reading X -> region0 reusable; Q/K drained

    // ---- V^T [d=32][tok=64] swz (slot ^ (d&7)), overlays dead X ----
#pragma unroll
    for (int nv = 0; nv < 2; ++nv)
#pragma unroll
        for (int mt = 0; mt < 4; ++mt)
#pragma unroll
            for (int r = 0; r < 4; ++r) {
                const int d = nv * 16 + quad * 4 + r;
                const int tok = mt * 16 + l16;
                lds[VOFF + d * 64 + (((tok >> 3) ^ (d & 7)) << 3) + (tok & 7)] =
                    fbf_hw(accv[nv][mt][r]);
            }

    // ---- scores: S^T = K . Q^T ----
    bf16x8 ak[4], bq[4];
#pragma unroll
    for (int mtk = 0; mtk < 4; ++mtk) {
        const int tok = mtk * 16 + l16;
        ak[mtk] = frag_ld(&lds[KOFF + tok * 32 + ((quad ^ (tok & 3)) << 3)]);
    }
#pragma unroll
    for (int ntq = 0; ntq < 4; ++ntq) {
        const int tok = ntq * 16 + l16;
        bq[ntq] = frag_ld(&lds[QOFF + tok * 32 + ((quad ^ (tok & 3)) << 3)]);
    }
    f32x4 sc[4][4];
    {
        f32x4 zz = {0.f, 0.f, 0.f, 0.f};
#pragma unroll
        for (int mtk = 0; mtk < 4; ++mtk)
#pragma unroll
            for (int ntq = 0; ntq < 4; ++ntq)
                sc[mtk][ntq] = MFMA16(ak[mtk], bq[ntq], zz);
    }

    // ---- softmax; P [tokq][tokk=64] swz (slot ^ (tokq&7)) overlays Q+K ----
    const float scale = 0.17677669529663687f;  // 32^-0.5
#pragma unroll
    for (int ntq = 0; ntq < 4; ++ntq) {
        float m0 = -1e30f;
#pragma unroll
        for (int mtk = 0; mtk < 4; ++mtk)
#pragma unroll
            for (int r = 0; r < 4; ++r) {
                sc[mtk][ntq][r] *= scale;
                m0 = fmaxf(m0, sc[mtk][ntq][r]);
            }
        m0 = fmaxf(m0, __shfl_xor(m0, 16));
        m0 = fmaxf(m0, __shfl_xor(m0, 32));
        float s0 = 0.f;
#pragma unroll
        for (int mtk = 0; mtk < 4; ++mtk)
#pragma unroll
            for (int r = 0; r < 4; ++r) {
                float p = __expf(sc[mtk][ntq][r] - m0);
                sc[mtk][ntq][r] = p;
                s0 += p;
            }
        s0 += __shfl_xor(s0, 16);
        s0 += __shfl_xor(s0, 32);
        float inv = 1.f / s0;
        const int tokq = ntq * 16 + l16;
#pragma unroll
        for (int mtk = 0; mtk < 4; ++mtk)
            *(uint2v*)&lds[QOFF + tokq * 64 +
                           (((mtk * 2 + (quad >> 1)) ^ (tokq & 7)) << 3) + (quad & 1) * 4] =
                pack4(sc[mtk][ntq][0] * inv, sc[mtk][ntq][1] * inv,
                      sc[mtk][ntq][2] * inv, sc[mtk][ntq][3] * inv);
    }
    __asm__ volatile("s_waitcnt lgkmcnt(0)" ::: "memory");  // within-wave P/V handoff

    // ---- O = P . V ----
    f32x4 ov[4][2];
#pragma unroll
    for (int mt = 0; mt < 4; ++mt)
#pragma unroll
        for (int nv = 0; nv < 2; ++nv) { f32x4 zz = {0.f, 0.f, 0.f, 0.f}; ov[mt][nv] = zz; }
#pragma unroll
    for (int ks = 0; ks < 2; ++ks) {
        bf16x8 ap[4];
#pragma unroll
        for (int mt = 0; mt < 4; ++mt) {
            const int tokq = mt * 16 + l16;
            ap[mt] = frag_ld(&lds[QOFF + tokq * 64 + (((ks * 4 + quad) ^ (tokq & 7)) << 3)]);
        }
#pragma unroll
        for (int nv = 0; nv < 2; ++nv) {
            const int d = nv * 16 + l16;
            bf16x8 bv = frag_ld(&lds[VOFF + d * 64 + (((ks * 4 + quad) ^ (d & 7)) << 3)]);
#pragma unroll
            for (int mt = 0; mt < 4; ++mt)
                ov[mt][nv] = MFMA16(ap[mt], bv, ov[mt][nv]);
        }
    }
    __syncthreads();  // all P/V reads done before O overlays region0

    // ---- O -> LDS [tok][e] s136 @0 ----
#pragma unroll
    for (int mt = 0; mt < 4; ++mt)
#pragma unroll
        for (int nv = 0; nv < 2; ++nv)
#pragma unroll
            for (int r = 0; r < 4; ++r)
                lds[(mt * 16 + quad * 4 + r) * 136 + hb + nv * 16 + l16] =
                    fbf_hw(ov[mt][nv][r]);
    __syncthreads();

    // ---- out-proj: D = O . Wo^T (raw; coef+bias applied in fuse) ----
    f32x4 dp[4][2];
#pragma unroll
    for (int mt = 0; mt < 4; ++mt)
#pragma unroll
        for (int nl = 0; nl < 2; ++nl) { f32x4 zz = {0.f, 0.f, 0.f, 0.f}; dp[mt][nl] = zz; }
#pragma unroll
    for (int ks = 0; ks < 4; ++ks) {
        bf16x8 af[4];
#pragma unroll
        for (int mt = 0; mt < 4; ++mt)
            af[mt] = frag_ld(&lds[(mt * 16 + l16) * 136 + ks * 32 + quad * 8]);
#pragma unroll
        for (int nl = 0; nl < 2; ++nl) {
            const int erow = hb + nl * 16 + l16;
            bf16x8 bw = frag_ld(&wo[erow * 128 + ks * 32 + quad * 8]);
#pragma unroll
            for (int mt = 0; mt < 4; ++mt)
                dp[mt][nl] = MFMA16(af[mt], bw, dp[mt][nl]);
        }
    }
    __syncthreads();  // all O reads done before D overlays the same area

    // ---- D -> LDS [tok][e] s136 @0 ----
#pragma unroll
    for (int mt = 0; mt < 4; ++mt)
#pragma unroll
        for (int nl = 0; nl < 2; ++nl)
#pragma unroll
            for (int r = 0; r < 4; ++r)
                lds[(mt * 16 + quad * 4 + r) * 136 + hb + nl * 16 + l16] =
                    fbf_hw(dp[mt][nl][r]);
    __syncthreads();

    // ---- coalesced att store: thread covers (tok = t>>2, 32 e's) ----
    {
        const int tok2 = t >> 2, eo = (t & 3) * 32;
        unsigned short* op = att + (size_t)n * 8192 + tok2 * 128 + eo;
        const unsigned short* lp = lds + tok2 * 136 + eo;
#pragma unroll
        for (int k4 = 0; k4 < 4; ++k4)
            *(uint4v*)(op + k4 * 8) = *(const uint4v*)(lp + k4 * 8);
    }
}

// ---------------------------------------------------------------- K4: fuse
// gathers <=4 covering windows per pixel with closed-form scan coefs.
__global__ __launch_bounds__(256) void fuse_kernel(
    const unsigned short* __restrict__ comb,  // pixel-major [b][y][x][128]
    const unsigned short* __restrict__ att,   // [n][tok][e] raw out-proj
    const void* __restrict__ vf,
    const float* __restrict__ wf,
    const int* __restrict__ flag,
    void* __restrict__ outp)
{
    __shared__ float enhs[128][65];
    __shared__ float fws[64][65];
    const float* fcw = wf + WF_FCW;
    const float* fcb = wf + WF_FCB;
    const bool f32 = (*flag != 0);
    const int t = threadIdx.x;
    const int wl = t & 63;
    const int eg = __builtin_amdgcn_readfirstlane(t >> 6);
    const int h = blockIdx.y, b = blockIdx.z;
    const int w = blockIdx.x * 64 + wl;

    const int mh = h >> 2, mw = w >> 2;
    const bool vh0 = (mh >= 1), vh1 = (mh <= 30);
    const bool vw0 = (mw >= 1), vw1 = (mw <= 30);
    const int k = ((int)vh0 + (int)vh1) * ((int)vw0 + (int)vw1); // 1,2,4
    const float base7 = (k == 1) ? 0.7f : (k == 2) ? 0.49f : 0.2401f;
    const float bias_c = 1.f - base7;  // sum_j coef_j (out-proj bias weight)

    float cw[4]; int coff[4];
    {
        const bool vs[4] = { vh0 && vw0, vh0 && vw1, vh1 && vw0, vh1 && vw1 };
        const int ihc[4] = { mh - 1, mh - 1, mh, mh };
        const int iwc[4] = { mw - 1, mw, mw - 1, mw };
        int j = 0;
#pragma unroll
        for (int s = 0; s < 4; ++s) {
            if (vs[s]) {
                ++j;
                int e2 = k - j;  // 0..3
                float pw = (e2 == 0) ? 1.f : (e2 == 1) ? 0.7f : (e2 == 2) ? 0.49f : 0.343f;
                cw[s] = 0.3f * pw;
                int nn = (ihc[s] * 31 + iwc[s]) * 4 + b;
                int ll = (h - 4 * ihc[s]) * 8 + (w - 4 * iwc[s]);
                coff[s] = nn * 8192 + ll * 128;
            } else { cw[s] = 0.f; coff[s] = 0; }
        }
    }

    const int cbase = (b * 128) * HW + h * 128 + w;                 // vf/out index
    const size_t cpix = (size_t)(b * 16384 + h * 128 + w) * 128;    // comb record
    const int e0 = eg * 32;
#pragma unroll
    for (int i8 = 0; i8 < 4; ++i8) {
        float av[8];
#pragma unroll
        for (int j = 0; j < 8; ++j)
            av[j] = bias_c * wf[WF_OPB + e0 + i8 * 8 + j];
#pragma unroll
        for (int s = 0; s < 4; ++s) {
            uint4v u = *(const uint4v*)(att + coff[s] + e0 + i8 * 8);
            float x[8];
            unp8(u, x);
#pragma unroll
            for (int j = 0; j < 8; ++j)
                av[j] = fmaf(cw[s], x[j], av[j]);
        }
        uint4v cu = *(const uint4v*)(comb + cpix + e0 + i8 * 8);
        float cx[8];
        unp8(cu, cx);
#pragma unroll
        for (int j = 0; j < 8; ++j)
            enhs[e0 + i8 * 8 + j][wl] = fmaf(base7, cx[j], av[j]);
    }
    __syncthreads();

    float a2[16];
    const int co0 = eg * 16;
#pragma unroll
    for (int i = 0; i < 16; ++i) a2[i] = fcb[co0 + i];
    for (int e = 0; e < 128; ++e) {
        float x = enhs[e][wl];
#pragma unroll
        for (int i = 0; i < 16; ++i)
            a2[i] = fmaf(x, fcw[(co0 + i) * 128 + e], a2[i]);
    }
#pragma unroll
    for (int i = 0; i < 16; ++i)
        fws[co0 + i][wl] = 1.f / (1.f + __expf(-a2[i]));
    __syncthreads();

#pragma unroll
    for (int i = 0; i < 32; ++i) {
        const int e = eg * 32 + i;
        const int idx = cbase + e * HW;
        float val = enhs[e][wl] * fws[e & 63][wl] + ldin(vf, idx, f32);
        if (f32) ((float*)outp)[idx] = val;
        else     ((unsigned short*)outp)[idx] = fbf_hw(val);
    }
}

// ---------------------------------------------------------------------------
extern "C" void kernel_launch(void* const* d_in, const int* in_sizes, int n_in,
                              void* d_out, int out_size, void* d_ws, size_t ws_size,
                              hipStream_t stream)
{
    const void* vf  = d_in[0];
    const void* mw1 = d_in[1];
    const void* mb1 = d_in[2];
    const void* mw2 = d_in[3];
    const void* mb2 = d_in[4];
    const void* aw1 = d_in[5];
    const void* ab1 = d_in[6];
    const void* aw2 = d_in[7];
    const void* ab2 = d_in[8];
    const void* ipw = d_in[9];
    const void* ipb = d_in[10];
    const void* opw = d_in[11];
    const void* opb = d_in[12];
    const void* fcw = d_in[13];
    const void* fcb = d_in[14];

    // ws layout (80,351,232 B total)
    int* flag = (int*)d_ws;                                         // @0
    float* wf = (float*)((char*)d_ws + 1024);                       // 592,896 B
    unsigned short* comb = (unsigned short*)((char*)d_ws + 593920); // 16,777,216 B (pixel-major)
    unsigned short* hidden = (unsigned short*)((char*)d_ws + 17371136); // 8.39 MB
    unsigned short* att = (unsigned short*)((char*)d_ws + 17371136);    // 62,980,096 B (overlays hidden)

    detect_kernel<<<1, 256, 0, stream>>>((const unsigned short*)vf, flag);
    cvtw_kernel<<<(WF_TOTAL + 255) / 256, 256, 0, stream>>>(
        ipw, ipb, opw, opb, fcw, fcb, mw1, mb1, aw1, ab1, mw2, mb2, aw2, ab2, flag, wf);
    conv1_kernel<<<dim3(4, 32, 8), 256, 0, stream>>>(vf, wf, flag, hidden);
    conv2_kernel<<<dim3(4, 32, 16), 256, 0, stream>>>(hidden, wf, comb);
    mha_kernel<<<NSEQ, 256, 0, stream>>>(comb, wf, att);
    fuse_kernel<<<dim3(2, 128, 4), 256, 0, stream>>>(comb, att, vf, wf, flag, d_out);
}

// Round 6
// 395.697 us; speedup vs baseline: 1.1322x; 1.0001x over previous
//
#include <hip/hip_runtime.h>
#include <hip/hip_bf16.h>

// ---------------------------------------------------------------------------
// VectorFieldAttention on MI355X — round 14 (revert to r11 mha + setprio)
//
// r12/r13 post-mortem: 8-wave mha NaN'd twice, once with maximal barriers ->
// not a sync bug; no counters/disasm available from failed runs to bisect.
// Shelved. r14 = exact r11 kernel (passed, 396us, absmax 0.03125) plus T5
// s_setprio(1) around each mha MFMA cluster: 3 blocks/CU at independent
// phases -> priority keeps matrix pipe fed (m191 regime). No memory
// semantics -> bit-identical output.
// ws: flag@0 | wf@1024 | comb@593,920 | hidden@17,371,136 (dead after conv2)
//     overlaid by att@17,371,136 (62,980,096 B) -> total 80,351,232 B.
// ---------------------------------------------------------------------------

#define HW 16384           // 128*128
#define NSEQ 3844          // 961 windows * 4 batch

// f32 weight file offsets (floats)
#define WF_IPW 0
#define WF_IPB 49152
#define WF_OPW 49536
#define WF_OPB 65920
#define WF_FCW 66048
#define WF_FCB 74240
#define WF_MW1 74304
#define WF_MB1 92736
#define WF_AW1 92768
#define WF_AB1 111200
#define WF_MW2 111232
#define WF_MB2 129664
#define WF_AW2 129728
#define WF_AB2 148160
#define WF_TOTAL 148224

typedef __bf16 bf16x8 __attribute__((ext_vector_type(8)));
typedef float f32x4 __attribute__((ext_vector_type(4)));
typedef unsigned int uint2v __attribute__((ext_vector_type(2)));
typedef unsigned int uint4v __attribute__((ext_vector_type(4)));

#define MFMA16(a, b, c) __builtin_amdgcn_mfma_f32_16x16x32_bf16((a), (b), (c), 0, 0, 0)

__device__ __forceinline__ float bfu(unsigned short u) {
    union { unsigned int i; float f; } v; v.i = ((unsigned int)u) << 16; return v.f;
}
// software RNE (cold paths only; bit-identical to v_cvt_pk_bf16_f32)
__device__ __forceinline__ unsigned short fbf(float f) {
    union { float f; unsigned int i; } v; v.f = f;
    unsigned int x = v.i;
    return (unsigned short)((x + 0x7fffu + ((x >> 16) & 1u)) >> 16);
}
// HW RNE pack: lo16 = bf16(a), hi16 = bf16(b). 1 VALU op.
__device__ __forceinline__ unsigned int cvt_pk_bf16(float a, float b) {
    unsigned int r;
    asm("v_cvt_pk_bf16_f32 %0, %1, %2" : "=v"(r) : "v"(a), "v"(b));
    return r;
}
__device__ __forceinline__ unsigned short fbf_hw(float f) {
    return (unsigned short)cvt_pk_bf16(f, f);
}
__device__ __forceinline__ float ldin(const void* p, long long i, bool f32) {
    return f32 ? ((const float*)p)[i] : bfu(((const unsigned short*)p)[i]);
}
__device__ __forceinline__ bf16x8 frag_ld(const unsigned short* p) {
    union { uint4v u; bf16x8 b; } v;
    v.u = *(const uint4v*)p;
    return v.b;
}
__device__ __forceinline__ uint2v pack4(float a, float b, float c, float d) {
    uint2v r;
    r.x = cvt_pk_bf16(a, b);
    r.y = cvt_pk_bf16(c, d);
    return r;
}
__device__ __forceinline__ void unp8(uint4v u, float* x) {
    union { unsigned int i; float f; } a;
    a.i = u.x << 16;         x[0] = a.f;
    a.i = u.x & 0xffff0000u; x[1] = a.f;
    a.i = u.y << 16;         x[2] = a.f;
    a.i = u.y & 0xffff0000u; x[3] = a.f;
    a.i = u.z << 16;         x[4] = a.f;
    a.i = u.z & 0xffff0000u; x[5] = a.f;
    a.i = u.w << 16;         x[6] = a.f;
    a.i = u.w & 0xffff0000u; x[7] = a.f;
}

// ------------------------------------------------------------- K-1: detect
__global__ __launch_bounds__(256) void detect_kernel(const unsigned short* __restrict__ vfu,
                                                     int* __restrict__ flag)
{
    __shared__ int cnt;
    if (threadIdx.x == 0) cnt = 0;
    __syncthreads();
    int bad = 0;
    for (int i = threadIdx.x; i < 8192; i += 256) {
        int e = (vfu[i] >> 7) & 0xff;
        if (e < 0x60 || e > 0xA0) ++bad;
    }
    atomicAdd(&cnt, bad);
    __syncthreads();
    if (threadIdx.x == 0) *flag = (cnt > 400) ? 1 : 0;
}

// ---------------------------------------------------------------- K0: weights
__global__ __launch_bounds__(256) void cvtw_kernel(
    const void* ipw, const void* ipb,
    const void* opw, const void* opb,
    const void* fcw, const void* fcb,
    const void* mw1, const void* mb1,
    const void* aw1, const void* ab1,
    const void* mw2, const void* mb2,
    const void* aw2, const void* ab2,
    const int* __restrict__ flag, float* __restrict__ wf)
{
    int i = blockIdx.x * 256 + threadIdx.x;
    if (i >= WF_TOTAL) return;
    const bool f32 = (*flag != 0);
    const void* src; int off;
    if      (i < WF_IPB) { src = ipw; off = WF_IPW; }
    else if (i < WF_OPW) { src = ipb; off = WF_IPB; }
    else if (i < WF_OPB) { src = opw; off = WF_OPW; }
    else if (i < WF_FCW) { src = opb; off = WF_OPB; }
    else if (i < WF_FCB) { src = fcw; off = WF_FCW; }
    else if (i < WF_MW1) { src = fcb; off = WF_FCB; }
    else if (i < WF_MB1) { src = mw1; off = WF_MW1; }
    else if (i < WF_AW1) { src = mb1; off = WF_MB1; }
    else if (i < WF_AB1) { src = aw1; off = WF_AW1; }
    else if (i < WF_MB2) { src = (i < WF_MW2) ? ab1 : mw2; off = (i < WF_MW2) ? WF_AB1 : WF_MW2; }
    else if (i < WF_AW2) { src = mb2; off = WF_MB2; }
    else if (i < WF_AB2) { src = aw2; off = WF_AW2; }
    else                 { src = ab2; off = WF_AB2; }
    float v = ldin(src, i - off, f32);
    if (i < WF_IPB) {
        ((unsigned short*)(wf + WF_IPW))[i] = fbf(v);           // wqkv_bf [384][128]
    } else if (i >= WF_OPW && i < WF_OPB) {
        ((unsigned short*)(wf + WF_OPW))[i - WF_OPW] = fbf(v);  // wo_bf [128][128]
    } else {
        wf[i] = v;
    }
}

// ------------------------------------------------------------- conv3x3 body
// 32x4 tile, 2 px/thread. PIXMAJ=false: out channel-major [oc][HW] (hidden).
// PIXMAJ=true: pixel-major records [pixel][128], 16B at +wv*8 (comb).
template<int IC, bool RELU, bool PIXMAJ>
__device__ void conv3x3_body(const void* __restrict__ in, long long in_off, bool f32,
                             const float* __restrict__ w,    // [32][IC][9]
                             const float* __restrict__ bias, // [32]
                             unsigned short* __restrict__ out)
{
    __shared__ float xs[32][6][37];   // 6 rows (4+2 halo), 34 cols used, odd stride
    const int t = threadIdx.x;
    const int tx0 = blockIdx.x * 32, ty0 = blockIdx.y * 4;
    const int wv = __builtin_amdgcn_readfirstlane(t >> 6);
    const int lane = t & 63;
    const int pr = lane >> 4, pc2 = lane & 15;   // 4 rows x 16 pairs

    float acc[8][2];
#pragma unroll
    for (int oo = 0; oo < 8; ++oo)
#pragma unroll
        for (int p = 0; p < 2; ++p) acc[oo][p] = 0.f;

    for (int cc = 0; cc < IC; cc += 32) {
        if (cc) __syncthreads();
        for (int i = t; i < 32 * 204; i += 256) {
            int c = i / 204, rem = i - c * 204;
            int rr = rem / 34, cx = rem - rr * 34;
            int gy = ty0 + rr - 1, gx = tx0 + cx - 1;
            float v = 0.f;
            if (gy >= 0 && gy < 128 && gx >= 0 && gx < 128)
                v = ldin(in, in_off + (long long)(cc + c) * HW + gy * 128 + gx, f32);
            xs[c][rr][cx] = v;
        }
        __syncthreads();
        for (int c = 0; c < 32; ++c) {
            float xv[3][4];
#pragma unroll
            for (int dy = 0; dy < 3; ++dy)
#pragma unroll
                for (int dx = 0; dx < 4; ++dx)
                    xv[dy][dx] = xs[c][pr + dy][pc2 * 2 + dx];
            const float* wr0 = w + (wv * 8 * IC + (cc + c)) * 9;
#pragma unroll
            for (int oo = 0; oo < 8; ++oo) {
                const float* wr = wr0 + oo * IC * 9;
#pragma unroll
                for (int dy = 0; dy < 3; ++dy)
#pragma unroll
                    for (int dx = 0; dx < 3; ++dx) {
                        float wvv = wr[dy * 3 + dx];
#pragma unroll
                        for (int p = 0; p < 2; ++p)
                            acc[oo][p] = fmaf(wvv, xv[dy][p + dx], acc[oo][p]);
                    }
            }
        }
    }
    const int px = tx0 + pc2 * 2, py = ty0 + pr;
    if constexpr (PIXMAJ) {
#pragma unroll
        for (int p = 0; p < 2; ++p) {
            union { unsigned int u32[4]; uint4v v; } pk;
#pragma unroll
            for (int j = 0; j < 4; ++j) {
                float v0 = acc[2 * j][p] + bias[wv * 8 + 2 * j];
                float v1 = acc[2 * j + 1][p] + bias[wv * 8 + 2 * j + 1];
                if (RELU) { v0 = fmaxf(v0, 0.f); v1 = fmaxf(v1, 0.f); }
                pk.u32[j] = cvt_pk_bf16(v0, v1);
            }
            *(uint4v*)(out + (size_t)(py * 128 + px + p) * 128 + wv * 8) = pk.v;
        }
    } else {
#pragma unroll
        for (int oo = 0; oo < 8; ++oo) {
            int oc = wv * 8 + oo;
            float bb = bias[oc];
            float v0 = acc[oo][0] + bb, v1 = acc[oo][1] + bb;
            if (RELU) { v0 = fmaxf(v0, 0.f); v1 = fmaxf(v1, 0.f); }
            *(unsigned int*)(out + oc * HW + py * 128 + px) = cvt_pk_bf16(v0, v1);
        }
    }
}

__global__ __launch_bounds__(256) void conv1_kernel(const void* __restrict__ vf,
                                                    const float* __restrict__ wf,
                                                    const int* __restrict__ flag,
                                                    unsigned short* __restrict__ hidden)
{
    int z = blockIdx.z, b = z >> 1, br = z & 1;
    const bool f32 = (*flag != 0);
    conv3x3_body<64, true, false>(vf, (long long)(b * 128 + br * 64) * HW, f32,
                                  wf + (br ? WF_AW1 : WF_MW1), wf + (br ? WF_AB1 : WF_MB1),
                                  hidden + (b * 64 + br * 32) * HW);
}

__global__ __launch_bounds__(256) void conv2_kernel(const unsigned short* __restrict__ hidden,
                                                    const float* __restrict__ wf,
                                                    unsigned short* __restrict__ comb)
{
    int z = blockIdx.z, b = z >> 2, br = (z >> 1) & 1, hf = z & 1;
    // comb pixel-major: image base b*16384*128, channel base br*64+hf*32
    conv3x3_body<32, false, true>(hidden, (long long)(b * 64 + br * 32) * HW, false,
                                  wf + (br ? WF_AW2 : WF_MW2) + hf * 32 * 32 * 9,
                                  wf + (br ? WF_AB2 : WF_MB2) + hf * 32,
                                  comb + (size_t)b * 2097152 + br * 64 + hf * 32);
}

// ---------------------------------------------------------------- K3: MHA (MFMA)
// (exact r11 structure: 256 threads, wave hh owns head hh, all LDS flows
//  wave-local or single-barrier; + T5 setprio around MFMA clusters)
// LDS map (ushort units, 25,088 total = 50,176 B -> 3 blocks/CU):
//   region0 @0 (8,704 ush): X [64][136]  ->  V^T 4x[32][64]swz  ->  O/D [64][136]
//   head hh @8,704+hh*4,096: Q [64][32]swz | K @+2,048 [64][32]swz
//                            P [64][64]swz overlays Q+K after scores
__global__ __launch_bounds__(256) void mha_kernel(
    const unsigned short* __restrict__ comb,   // [b][y][x][e=128] bf16 pixel-major
    const float* __restrict__ wf,
    unsigned short* __restrict__ att)          // [n][tok][e] bf16, raw out-proj
{
    __shared__ unsigned short lds[25088];

    const unsigned short* wqkv = (const unsigned short*)(wf + WF_IPW); // [384][128] bf16
    const unsigned short* wo   = (const unsigned short*)(wf + WF_OPW); // [128][128] bf16

    // Bijective XCD-chunked batch-major map (HW: block i -> XCD i%8).
    // 3844 = 8*480 + 4: XCD 0..3 own 481 windows, XCD 4..7 own 480.
    const int bid = blockIdx.x;
    const int xcd = bid & 7, idx = bid >> 3;
    const int start = (xcd < 4) ? xcd * 481 : 1924 + (xcd - 4) * 480;
    const int nl = start + idx;            // bb*961 + ih*31 + iw (batch-major raster)
    const int bb = nl / 961;
    const int ihw = nl - bb * 961;
    const int ih = ihw / 31, iw = ihw - ih * 31;
    const int n = ihw * 4 + bb;            // att record index (fuse layout unchanged)

    const int t = threadIdx.x;
    const int lane = t & 63, quad = lane >> 4, l16 = lane & 15;
    const int hh = __builtin_amdgcn_readfirstlane(t >> 6);
    const int hb = hh * 32;
    const int QOFF = 8704 + hh * 4096;
    const int KOFF = QOFF + 2048;
    const int VOFF = hh * 2048;

    // ---- stage X [tok][e] s136: wave hh covers window rows 2hh,2hh+1,
    //      each row = 8 px * 256B = 2KB contiguous -> 1KB coalesced per issue ----
#pragma unroll
    for (int rh = 0; rh < 2; ++rh) {
        const int r = hh * 2 + rh;
        const unsigned short* rp = comb +
            (size_t)(bb * 16384 + (ih * 4 + r) * 128 + iw * 4) * 128;
#pragma unroll
        for (int hv = 0; hv < 2; ++hv) {
            uint4v v = *(const uint4v*)(rp + hv * 512 + lane * 8);
            const int tok = r * 8 + hv * 4 + (lane >> 4);
            *(uint4v*)&lds[tok * 136 + (lane & 15) * 8] = v;
        }
    }
    __syncthreads();

    // ---- pass A: Q,K = Wqkv[0:256] . X^T  (acc[4][4] = 64 regs peak) ----
    {
        f32x4 acc[4][4];
#pragma unroll
        for (int nt = 0; nt < 4; ++nt) {
            const int rb = (nt < 2) ? (hb + nt * 16) : (128 + hb + (nt - 2) * 16);
            f32x4 b4;
            b4[0] = wf[WF_IPB + rb + quad * 4 + 0];
            b4[1] = wf[WF_IPB + rb + quad * 4 + 1];
            b4[2] = wf[WF_IPB + rb + quad * 4 + 2];
            b4[3] = wf[WF_IPB + rb + quad * 4 + 3];
#pragma unroll
            for (int mt = 0; mt < 4; ++mt) acc[nt][mt] = b4;
        }
        __builtin_amdgcn_s_setprio(1);
#pragma unroll
        for (int kc = 0; kc < 4; ++kc) {
            bf16x8 bx[4];
#pragma unroll
            for (int mt = 0; mt < 4; ++mt)
                bx[mt] = frag_ld(&lds[(mt * 16 + l16) * 136 + kc * 32 + quad * 8]);
#pragma unroll
            for (int nt = 0; nt < 4; ++nt) {
                const int rb = (nt < 2) ? (hb + nt * 16) : (128 + hb + (nt - 2) * 16);
                bf16x8 aw = frag_ld(&wqkv[(rb + l16) * 128 + kc * 32 + quad * 8]);
#pragma unroll
                for (int mt = 0; mt < 4; ++mt)
                    acc[nt][mt] = MFMA16(aw, bx[mt], acc[nt][mt]);
            }
        }
        __builtin_amdgcn_s_setprio(0);
        // write Q,K: [tok][d=32], 16B-slot swizzle (slot ^ (tok&3))
#pragma unroll
        for (int nt = 0; nt < 2; ++nt)
#pragma unroll
            for (int mt = 0; mt < 4; ++mt) {
                const int tok = mt * 16 + l16;
                const int aoff = tok * 32 + (((nt * 2 + (quad >> 1)) ^ (tok & 3)) << 3)
                               + (quad & 1) * 4;
                *(uint2v*)&lds[QOFF + aoff] =
                    pack4(acc[nt][mt][0], acc[nt][mt][1], acc[nt][mt][2], acc[nt][mt][3]);
                *(uint2v*)&lds[KOFF + aoff] =
                    pack4(acc[nt + 2][mt][0], acc[nt + 2][mt][1],
                          acc[nt + 2][mt][2], acc[nt + 2][mt][3]);
            }
    }

    // ---- pass B: V = Wqkv[256:384] . X^T  (accv[2][4] = 32 regs) ----
    f32x4 accv[2][4];
#pragma unroll
    for (int nv = 0; nv < 2; ++nv) {
        const int rb = 256 + hb + nv * 16;
        f32x4 b4;
        b4[0] = wf[WF_IPB + rb + quad * 4 + 0];
        b4[1] = wf[WF_IPB + rb + quad * 4 + 1];
        b4[2] = wf[WF_IPB + rb + quad * 4 + 2];
        b4[3] = wf[WF_IPB + rb + quad * 4 + 3];
#pragma unroll
        for (int mt = 0; mt < 4; ++mt) accv[nv][mt] = b4;
    }
    __builtin_amdgcn_s_setprio(1);
#pragma unroll
    for (int kc = 0; kc < 4; ++kc) {
        bf16x8 bx[4];
#pragma unroll
        for (int mt = 0; mt < 4; ++mt)
            bx[mt] = frag_ld(&lds[(mt * 16 + l16) * 136 + kc * 32 + quad * 8]);
#pragma unroll
        for (int nv = 0; nv < 2; ++nv) {
            const int rb = 256 + hb + nv * 16;
            bf16x8 aw = frag_ld(&wqkv[(rb + l16) * 128 + kc * 32 + quad * 8]);
#pragma unroll
            for (int mt = 0; mt < 4; ++mt)
                accv[nv][mt] = MFMA16(aw, bx[mt], accv[nv][mt]);
        }
    }
    __builtin_amdgcn_s_setprio(0);
    __syncthreads();   // all waves done reading X -> region0 reusable; Q/K drained

    // ---- V^T [d=32][tok=64] swz (slot ^ (d&7)), overlays dead X ----
#pragma unroll
    for (int nv = 0; nv < 2; ++nv)
#pragma unroll
        for (int mt = 0; mt < 4; ++mt)
#pragma unroll
            for (int r = 0; r < 4; ++r) {
                const int d = nv * 16 + quad * 4 + r;
                const int tok = mt * 16 + l16;
                lds[VOFF + d * 64 + (((tok >> 3) ^ (d & 7)) << 3) + (tok & 7)] =
                    fbf_hw(accv[nv][mt][r]);
            }

    // ---- scores: S^T = K . Q^T ----
    bf16x8 ak[4], bq[4];
#pragma unroll
    for (int mtk = 0; mtk < 4; ++mtk) {
        const int tok = mtk * 16 + l16;
        ak[mtk] = frag_ld(&lds[KOFF + tok * 32 + ((quad ^ (tok & 3)) << 3)]);
    }
#pragma unroll
    for (int ntq = 0; ntq < 4; ++ntq) {
        const int tok = ntq * 16 + l16;
        bq[ntq] = frag_ld(&lds[QOFF + tok * 32 + ((quad ^ (tok & 3)) << 3)]);
    }
    f32x4 sc[4][4];
    {
        f32x4 zz = {0.f, 0.f, 0.f, 0.f};
        __builtin_amdgcn_s_setprio(1);
#pragma unroll
        for (int mtk = 0; mtk < 4; ++mtk)
#pragma unroll
            for (int ntq = 0; ntq < 4; ++ntq)
                sc[mtk][ntq] = MFMA16(ak[mtk], bq[ntq], zz);
        __builtin_amdgcn_s_setprio(0);
    }

    // ---- softmax; P [tokq][tokk=64] swz (slot ^ (tokq&7)) overlays Q+K ----
    const float scale = 0.17677669529663687f;  // 32^-0.5
#pragma unroll
    for (int ntq = 0; ntq < 4; ++ntq) {
        float m0 = -1e30f;
#pragma unroll
        for (int mtk = 0; mtk < 4; ++mtk)
#pragma unroll
            for (int r = 0; r < 4; ++r) {
                sc[mtk][ntq][r] *= scale;
                m0 = fmaxf(m0, sc[mtk][ntq][r]);
            }
        m0 = fmaxf(m0, __shfl_xor(m0, 16));
        m0 = fmaxf(m0, __shfl_xor(m0, 32));
        float s0 = 0.f;
#pragma unroll
        for (int mtk = 0; mtk < 4; ++mtk)
#pragma unroll
            for (int r = 0; r < 4; ++r) {
                float p = __expf(sc[mtk][ntq][r] - m0);
                sc[mtk][ntq][r] = p;
                s0 += p;
            }
        s0 += __shfl_xor(s0, 16);
        s0 += __shfl_xor(s0, 32);
        float inv = 1.f / s0;
        const int tokq = ntq * 16 + l16;
#pragma unroll
        for (int mtk = 0; mtk < 4; ++mtk)
            *(uint2v*)&lds[QOFF + tokq * 64 +
                           (((mtk * 2 + (quad >> 1)) ^ (tokq & 7)) << 3) + (quad & 1) * 4] =
                pack4(sc[mtk][ntq][0] * inv, sc[mtk][ntq][1] * inv,
                      sc[mtk][ntq][2] * inv, sc[mtk][ntq][3] * inv);
    }
    __asm__ volatile("s_waitcnt lgkmcnt(0)" ::: "memory");  // within-wave P/V handoff

    // ---- O = P . V ----
    f32x4 ov[4][2];
#pragma unroll
    for (int mt = 0; mt < 4; ++mt)
#pragma unroll
        for (int nv = 0; nv < 2; ++nv) { f32x4 zz = {0.f, 0.f, 0.f, 0.f}; ov[mt][nv] = zz; }
    __builtin_amdgcn_s_setprio(1);
#pragma unroll
    for (int ks = 0; ks < 2; ++ks) {
        bf16x8 ap[4];
#pragma unroll
        for (int mt = 0; mt < 4; ++mt) {
            const int tokq = mt * 16 + l16;
            ap[mt] = frag_ld(&lds[QOFF + tokq * 64 + (((ks * 4 + quad) ^ (tokq & 7)) << 3)]);
        }
#pragma unroll
        for (int nv = 0; nv < 2; ++nv) {
            const int d = nv * 16 + l16;
            bf16x8 bv = frag_ld(&lds[VOFF + d * 64 + (((ks * 4 + quad) ^ (d & 7)) << 3)]);
#pragma unroll
            for (int mt = 0; mt < 4; ++mt)
                ov[mt][nv] = MFMA16(ap[mt], bv, ov[mt][nv]);
        }
    }
    __builtin_amdgcn_s_setprio(0);
    __syncthreads();  // all P/V reads done before O overlays region0

    // ---- O -> LDS [tok][e] s136 @0 ----
#pragma unroll
    for (int mt = 0; mt < 4; ++mt)
#pragma unroll
        for (int nv = 0; nv < 2; ++nv)
#pragma unroll
            for (int r = 0; r < 4; ++r)
                lds[(mt * 16 + quad * 4 + r) * 136 + hb + nv * 16 + l16] =
                    fbf_hw(ov[mt][nv][r]);
    __syncthreads();

    // ---- out-proj: D = O . Wo^T (raw; coef+bias applied in fuse) ----
    f32x4 dp[4][2];
#pragma unroll
    for (int mt = 0; mt < 4; ++mt)
#pragma unroll
        for (int nl = 0; nl < 2; ++nl) { f32x4 zz = {0.f, 0.f, 0.f, 0.f}; dp[mt][nl] = zz; }
    __builtin_amdgcn_s_setprio(1);
#pragma unroll
    for (int ks = 0; ks < 4; ++ks) {
        bf16x8 af[4];
#pragma unroll
        for (int mt = 0; mt < 4; ++mt)
            af[mt] = frag_ld(&lds[(mt * 16 + l16) * 136 + ks * 32 + quad * 8]);
#pragma unroll
        for (int nl = 0; nl < 2; ++nl) {
            const int erow = hb + nl * 16 + l16;
            bf16x8 bw = frag_ld(&wo[erow * 128 + ks * 32 + quad * 8]);
#pragma unroll
            for (int mt = 0; mt < 4; ++mt)
                dp[mt][nl] = MFMA16(af[mt], bw, dp[mt][nl]);
        }
    }
    __builtin_amdgcn_s_setprio(0);
    __syncthreads();  // all O reads done before D overlays the same area

    // ---- D -> LDS [tok][e] s136 @0 ----
#pragma unroll
    for (int mt = 0; mt < 4; ++mt)
#pragma unroll
        for (int nl = 0; nl < 2; ++nl)
#pragma unroll
            for (int r = 0; r < 4; ++r)
                lds[(mt * 16 + quad * 4 + r) * 136 + hb + nl * 16 + l16] =
                    fbf_hw(dp[mt][nl][r]);
    __syncthreads();

    // ---- coalesced att store: thread covers (tok = t>>2, 32 e's) ----
    {
        const int tok2 = t >> 2, eo = (t & 3) * 32;
        unsigned short* op = att + (size_t)n * 8192 + tok2 * 128 + eo;
        const unsigned short* lp = lds + tok2 * 136 + eo;
#pragma unroll
        for (int k4 = 0; k4 < 4; ++k4)
            *(uint4v*)(op + k4 * 8) = *(const uint4v*)(lp + k4 * 8);
    }
}

// ---------------------------------------------------------------- K4: fuse
// gathers <=4 covering windows per pixel with closed-form scan coefs.
__global__ __launch_bounds__(256) void fuse_kernel(
    const unsigned short* __restrict__ comb,  // pixel-major [b][y][x][128]
    const unsigned short* __restrict__ att,   // [n][tok][e] raw out-proj
    const void* __restrict__ vf,
    const float* __restrict__ wf,
    const int* __restrict__ flag,
    void* __restrict__ outp)
{
    __shared__ float enhs[128][65];
    __shared__ float fws[64][65];
    const float* fcw = wf + WF_FCW;
    const float* fcb = wf + WF_FCB;
    const bool f32 = (*flag != 0);
    const int t = threadIdx.x;
    const int wl = t & 63;
    const int eg = __builtin_amdgcn_readfirstlane(t >> 6);
    const int h = blockIdx.y, b = blockIdx.z;
    const int w = blockIdx.x * 64 + wl;

    const int mh = h >> 2, mw = w >> 2;
    const bool vh0 = (mh >= 1), vh1 = (mh <= 30);
    const bool vw0 = (mw >= 1), vw1 = (mw <= 30);
    const int k = ((int)vh0 + (int)vh1) * ((int)vw0 + (int)vw1); // 1,2,4
    const float base7 = (k == 1) ? 0.7f : (k == 2) ? 0.49f : 0.2401f;
    const float bias_c = 1.f - base7;  // sum_j coef_j (out-proj bias weight)

    float cw[4]; int coff[4];
    {
        const bool vs[4] = { vh0 && vw0, vh0 && vw1, vh1 && vw0, vh1 && vw1 };
        const int ihc[4] = { mh - 1, mh - 1, mh, mh };
        const int iwc[4] = { mw - 1, mw, mw - 1, mw };
        int j = 0;
#pragma unroll
        for (int s = 0; s < 4; ++s) {
            if (vs[s]) {
                ++j;
                int e2 = k - j;  // 0..3
                float pw = (e2 == 0) ? 1.f : (e2 == 1) ? 0.7f : (e2 == 2) ? 0.49f : 0.343f;
                cw[s] = 0.3f * pw;
                int nn = (ihc[s] * 31 + iwc[s]) * 4 + b;
                int ll = (h - 4 * ihc[s]) * 8 + (w - 4 * iwc[s]);
                coff[s] = nn * 8192 + ll * 128;
            } else { cw[s] = 0.f; coff[s] = 0; }
        }
    }

    const int cbase = (b * 128) * HW + h * 128 + w;                 // vf/out index
    const size_t cpix = (size_t)(b * 16384 + h * 128 + w) * 128;    // comb record
    const int e0 = eg * 32;
#pragma unroll
    for (int i8 = 0; i8 < 4; ++i8) {
        float av[8];
#pragma unroll
        for (int j = 0; j < 8; ++j)
            av[j] = bias_c * wf[WF_OPB + e0 + i8 * 8 + j];
#pragma unroll
        for (int s = 0; s < 4; ++s) {
            uint4v u = *(const uint4v*)(att + coff[s] + e0 + i8 * 8);
            float x[8];
            unp8(u, x);
#pragma unroll
            for (int j = 0; j < 8; ++j)
                av[j] = fmaf(cw[s], x[j], av[j]);
        }
        uint4v cu = *(const uint4v*)(comb + cpix + e0 + i8 * 8);
        float cx[8];
        unp8(cu, cx);
#pragma unroll
        for (int j = 0; j < 8; ++j)
            enhs[e0 + i8 * 8 + j][wl] = fmaf(base7, cx[j], av[j]);
    }
    __syncthreads();

    float a2[16];
    const int co0 = eg * 16;
#pragma unroll
    for (int i = 0; i < 16; ++i) a2[i] = fcb[co0 + i];
    for (int e = 0; e < 128; ++e) {
        float x = enhs[e][wl];
#pragma unroll
        for (int i = 0; i < 16; ++i)
            a2[i] = fmaf(x, fcw[(co0 + i) * 128 + e], a2[i]);
    }
#pragma unroll
    for (int i = 0; i < 16; ++i)
        fws[co0 + i][wl] = 1.f / (1.f + __expf(-a2[i]));
    __syncthreads();

#pragma unroll
    for (int i = 0; i < 32; ++i) {
        const int e = eg * 32 + i;
        const int idx = cbase + e * HW;
        float val = enhs[e][wl] * fws[e & 63][wl] + ldin(vf, idx, f32);
        if (f32) ((float*)outp)[idx] = val;
        else     ((unsigned short*)outp)[idx] = fbf_hw(val);
    }
}

// ---------------------------------------------------------------------------
extern "C" void kernel_launch(void* const* d_in, const int* in_sizes, int n_in,
                              void* d_out, int out_size, void* d_ws, size_t ws_size,
                              hipStream_t stream)
{
    const void* vf  = d_in[0];
    const void* mw1 = d_in[1];
    const void* mb1 = d_in[2];
    const void* mw2 = d_in[3];
    const void* mb2 = d_in[4];
    const void* aw1 = d_in[5];
    const void* ab1 = d_in[6];
    const void* aw2 = d_in[7];
    const void* ab2 = d_in[8];
    const void* ipw = d_in[9];
    const void* ipb = d_in[10];
    const void* opw = d_in[11];
    const void* opb = d_in[12];
    const void* fcw = d_in[13];
    const void* fcb = d_in[14];

    // ws layout (80,351,232 B total)
    int* flag = (int*)d_ws;                                         // @0
    float* wf = (float*)((char*)d_ws + 1024);                       // 592,896 B
    unsigned short* comb = (unsigned short*)((char*)d_ws + 593920); // 16,777,216 B (pixel-major)
    unsigned short* hidden = (unsigned short*)((char*)d_ws + 17371136); // 8.39 MB
    unsigned short* att = (unsigned short*)((char*)d_ws + 17371136);    // 62,980,096 B (overlays hidden)

    detect_kernel<<<1, 256, 0, stream>>>((const unsigned short*)vf, flag);
    cvtw_kernel<<<(WF_TOTAL + 255) / 256, 256, 0, stream>>>(
        ipw, ipb, opw, opb, fcw, fcb, mw1, mb1, aw1, ab1, mw2, mb2, aw2, ab2, flag, wf);
    conv1_kernel<<<dim3(4, 32, 8), 256, 0, stream>>>(vf, wf, flag, hidden);
    conv2_kernel<<<dim3(4, 32, 16), 256, 0, stream>>>(hidden, wf, comb);
    mha_kernel<<<NSEQ, 256, 0, stream>>>(comb, wf, att);
    fuse_kernel<<<dim3(2, 128, 4), 256, 0, stream>>>(comb, att, vf, wf, flag, d_out);
}

// Round 7
// 388.404 us; speedup vs baseline: 1.1534x; 1.0188x over previous
//
#include <hip/hip_runtime.h>
#include <hip/hip_bf16.h>

// ---------------------------------------------------------------------------
// VectorFieldAttention on MI355X — round 15 (vectorized conv staging + fuse fcw)
//
// r14 post-mortem: setprio null (lockstep waves, m190 regime). Budget math:
// top-5 all-mha at ~99.5 over many iters + total 396 => conv1/conv2/fuse all
// ~90-99us each (VALU floor ~31us each -> 33% efficiency, issue/latency-bound).
// r15 (all bit-identical math):
//  * conv staging rows 34 = 1 + 16 aligned pairs + 1: float2/ushort2 interior
//    loads, no x-bounds check on pairs -> ~2x fewer staging instrs.
//  * fuse gate matvec: fcw via float4 (2048 -> 512 VMEM instrs), e-ascending
//    accumulation order preserved.
// mha = r14 verbatim (green).
// ws: flag@0 | wf@1024 | comb@593,920 | hidden@17,371,136 (dead after conv2)
//     overlaid by att@17,371,136 (62,980,096 B) -> total 80,351,232 B.
// ---------------------------------------------------------------------------

#define HW 16384           // 128*128
#define NSEQ 3844          // 961 windows * 4 batch

// f32 weight file offsets (floats)
#define WF_IPW 0
#define WF_IPB 49152
#define WF_OPW 49536
#define WF_OPB 65920
#define WF_FCW 66048
#define WF_FCB 74240
#define WF_MW1 74304
#define WF_MB1 92736
#define WF_AW1 92768
#define WF_AB1 111200
#define WF_MW2 111232
#define WF_MB2 129664
#define WF_AW2 129728
#define WF_AB2 148160
#define WF_TOTAL 148224

typedef __bf16 bf16x8 __attribute__((ext_vector_type(8)));
typedef float f32x4 __attribute__((ext_vector_type(4)));
typedef unsigned int uint2v __attribute__((ext_vector_type(2)));
typedef unsigned int uint4v __attribute__((ext_vector_type(4)));

#define MFMA16(a, b, c) __builtin_amdgcn_mfma_f32_16x16x32_bf16((a), (b), (c), 0, 0, 0)

__device__ __forceinline__ float bfu(unsigned short u) {
    union { unsigned int i; float f; } v; v.i = ((unsigned int)u) << 16; return v.f;
}
// software RNE (cold paths only; bit-identical to v_cvt_pk_bf16_f32)
__device__ __forceinline__ unsigned short fbf(float f) {
    union { float f; unsigned int i; } v; v.f = f;
    unsigned int x = v.i;
    return (unsigned short)((x + 0x7fffu + ((x >> 16) & 1u)) >> 16);
}
// HW RNE pack: lo16 = bf16(a), hi16 = bf16(b). 1 VALU op.
__device__ __forceinline__ unsigned int cvt_pk_bf16(float a, float b) {
    unsigned int r;
    asm("v_cvt_pk_bf16_f32 %0, %1, %2" : "=v"(r) : "v"(a), "v"(b));
    return r;
}
__device__ __forceinline__ unsigned short fbf_hw(float f) {
    return (unsigned short)cvt_pk_bf16(f, f);
}
__device__ __forceinline__ float ldin(const void* p, long long i, bool f32) {
    return f32 ? ((const float*)p)[i] : bfu(((const unsigned short*)p)[i]);
}
__device__ __forceinline__ bf16x8 frag_ld(const unsigned short* p) {
    union { uint4v u; bf16x8 b; } v;
    v.u = *(const uint4v*)p;
    return v.b;
}
__device__ __forceinline__ uint2v pack4(float a, float b, float c, float d) {
    uint2v r;
    r.x = cvt_pk_bf16(a, b);
    r.y = cvt_pk_bf16(c, d);
    return r;
}
__device__ __forceinline__ void unp8(uint4v u, float* x) {
    union { unsigned int i; float f; } a;
    a.i = u.x << 16;         x[0] = a.f;
    a.i = u.x & 0xffff0000u; x[1] = a.f;
    a.i = u.y << 16;         x[2] = a.f;
    a.i = u.y & 0xffff0000u; x[3] = a.f;
    a.i = u.z << 16;         x[4] = a.f;
    a.i = u.z & 0xffff0000u; x[5] = a.f;
    a.i = u.w << 16;         x[6] = a.f;
    a.i = u.w & 0xffff0000u; x[7] = a.f;
}

// ------------------------------------------------------------- K-1: detect
__global__ __launch_bounds__(256) void detect_kernel(const unsigned short* __restrict__ vfu,
                                                     int* __restrict__ flag)
{
    __shared__ int cnt;
    if (threadIdx.x == 0) cnt = 0;
    __syncthreads();
    int bad = 0;
    for (int i = threadIdx.x; i < 8192; i += 256) {
        int e = (vfu[i] >> 7) & 0xff;
        if (e < 0x60 || e > 0xA0) ++bad;
    }
    atomicAdd(&cnt, bad);
    __syncthreads();
    if (threadIdx.x == 0) *flag = (cnt > 400) ? 1 : 0;
}

// ---------------------------------------------------------------- K0: weights
__global__ __launch_bounds__(256) void cvtw_kernel(
    const void* ipw, const void* ipb,
    const void* opw, const void* opb,
    const void* fcw, const void* fcb,
    const void* mw1, const void* mb1,
    const void* aw1, const void* ab1,
    const void* mw2, const void* mb2,
    const void* aw2, const void* ab2,
    const int* __restrict__ flag, float* __restrict__ wf)
{
    int i = blockIdx.x * 256 + threadIdx.x;
    if (i >= WF_TOTAL) return;
    const bool f32 = (*flag != 0);
    const void* src; int off;
    if      (i < WF_IPB) { src = ipw; off = WF_IPW; }
    else if (i < WF_OPW) { src = ipb; off = WF_IPB; }
    else if (i < WF_OPB) { src = opw; off = WF_OPW; }
    else if (i < WF_FCW) { src = opb; off = WF_OPB; }
    else if (i < WF_FCB) { src = fcw; off = WF_FCW; }
    else if (i < WF_MW1) { src = fcb; off = WF_FCB; }
    else if (i < WF_MB1) { src = mw1; off = WF_MW1; }
    else if (i < WF_AW1) { src = mb1; off = WF_MB1; }
    else if (i < WF_AB1) { src = aw1; off = WF_AW1; }
    else if (i < WF_MB2) { src = (i < WF_MW2) ? ab1 : mw2; off = (i < WF_MW2) ? WF_AB1 : WF_MW2; }
    else if (i < WF_AW2) { src = mb2; off = WF_MB2; }
    else if (i < WF_AB2) { src = aw2; off = WF_AW2; }
    else                 { src = ab2; off = WF_AB2; }
    float v = ldin(src, i - off, f32);
    if (i < WF_IPB) {
        ((unsigned short*)(wf + WF_IPW))[i] = fbf(v);           // wqkv_bf [384][128]
    } else if (i >= WF_OPW && i < WF_OPB) {
        ((unsigned short*)(wf + WF_OPW))[i - WF_OPW] = fbf(v);  // wo_bf [128][128]
    } else {
        wf[i] = v;
    }
}

// ------------------------------------------------------------- conv3x3 body
// 32x4 tile, 2 px/thread. Staging: each 34-col row = 1 edge + 16 aligned
// pairs (no x-bounds check) + 1 edge. PIXMAJ=false: out channel-major
// [oc][HW] (hidden). PIXMAJ=true: pixel-major records [pixel][128] (comb).
template<int IC, bool RELU, bool PIXMAJ>
__device__ void conv3x3_body(const void* __restrict__ in, long long in_off, bool f32,
                             const float* __restrict__ w,    // [32][IC][9]
                             const float* __restrict__ bias, // [32]
                             unsigned short* __restrict__ out)
{
    __shared__ float xs[32][6][37];   // 6 rows (4+2 halo), 34 cols used, odd stride
    const int t = threadIdx.x;
    const int tx0 = blockIdx.x * 32, ty0 = blockIdx.y * 4;
    const int wv = __builtin_amdgcn_readfirstlane(t >> 6);
    const int lane = t & 63;
    const int pr = lane >> 4, pc2 = lane & 15;   // 4 rows x 16 pairs

    float acc[8][2];
#pragma unroll
    for (int oo = 0; oo < 8; ++oo)
#pragma unroll
        for (int p = 0; p < 2; ++p) acc[oo][p] = 0.f;

    for (int cc = 0; cc < IC; cc += 32) {
        if (cc) __syncthreads();
        // 18 slots per (c,row): s=0 edge col0, s in [1,16] pairs, s=17 edge col33
        for (int i = t; i < 32 * 108; i += 256) {
            int c = i / 108, rem = i - c * 108;
            int rr = rem / 18, s = rem - rr * 18;
            int gy = ty0 + rr - 1;
            const bool gyok = (gy >= 0 && gy < 128);
            long long rowoff = in_off + (long long)(cc + c) * HW + gy * 128;
            if (s >= 1 && s <= 16) {
                int cx = 2 * s - 1;              // odd 1..31
                int gx = tx0 + cx - 1;           // even, in [tx0, tx0+30] (always valid)
                float v0 = 0.f, v1 = 0.f;
                if (gyok) {
                    if (f32) {
                        float2 u = *(const float2*)((const float*)in + rowoff + gx);
                        v0 = u.x; v1 = u.y;
                    } else {
                        unsigned int u = *(const unsigned int*)
                            ((const unsigned short*)in + rowoff + gx);
                        v0 = bfu((unsigned short)(u & 0xffffu));
                        v1 = bfu((unsigned short)(u >> 16));
                    }
                }
                xs[c][rr][cx] = v0;
                xs[c][rr][cx + 1] = v1;
            } else {
                int cx = (s == 0) ? 0 : 33;
                int gx = tx0 + cx - 1;
                float v = 0.f;
                if (gyok && gx >= 0 && gx < 128)
                    v = ldin(in, rowoff + gx, f32);
                xs[c][rr][cx] = v;
            }
        }
        __syncthreads();
        for (int c = 0; c < 32; ++c) {
            float xv[3][4];
#pragma unroll
            for (int dy = 0; dy < 3; ++dy)
#pragma unroll
                for (int dx = 0; dx < 4; ++dx)
                    xv[dy][dx] = xs[c][pr + dy][pc2 * 2 + dx];
            const float* wr0 = w + (wv * 8 * IC + (cc + c)) * 9;
#pragma unroll
            for (int oo = 0; oo < 8; ++oo) {
                const float* wr = wr0 + oo * IC * 9;
#pragma unroll
                for (int dy = 0; dy < 3; ++dy)
#pragma unroll
                    for (int dx = 0; dx < 3; ++dx) {
                        float wvv = wr[dy * 3 + dx];
#pragma unroll
                        for (int p = 0; p < 2; ++p)
                            acc[oo][p] = fmaf(wvv, xv[dy][p + dx], acc[oo][p]);
                    }
            }
        }
    }
    const int px = tx0 + pc2 * 2, py = ty0 + pr;
    if constexpr (PIXMAJ) {
#pragma unroll
        for (int p = 0; p < 2; ++p) {
            union { unsigned int u32[4]; uint4v v; } pk;
#pragma unroll
            for (int j = 0; j < 4; ++j) {
                float v0 = acc[2 * j][p] + bias[wv * 8 + 2 * j];
                float v1 = acc[2 * j + 1][p] + bias[wv * 8 + 2 * j + 1];
                if (RELU) { v0 = fmaxf(v0, 0.f); v1 = fmaxf(v1, 0.f); }
                pk.u32[j] = cvt_pk_bf16(v0, v1);
            }
            *(uint4v*)(out + (size_t)(py * 128 + px + p) * 128 + wv * 8) = pk.v;
        }
    } else {
#pragma unroll
        for (int oo = 0; oo < 8; ++oo) {
            int oc = wv * 8 + oo;
            float bb = bias[oc];
            float v0 = acc[oo][0] + bb, v1 = acc[oo][1] + bb;
            if (RELU) { v0 = fmaxf(v0, 0.f); v1 = fmaxf(v1, 0.f); }
            *(unsigned int*)(out + oc * HW + py * 128 + px) = cvt_pk_bf16(v0, v1);
        }
    }
}

__global__ __launch_bounds__(256) void conv1_kernel(const void* __restrict__ vf,
                                                    const float* __restrict__ wf,
                                                    const int* __restrict__ flag,
                                                    unsigned short* __restrict__ hidden)
{
    int z = blockIdx.z, b = z >> 1, br = z & 1;
    const bool f32 = (*flag != 0);
    conv3x3_body<64, true, false>(vf, (long long)(b * 128 + br * 64) * HW, f32,
                                  wf + (br ? WF_AW1 : WF_MW1), wf + (br ? WF_AB1 : WF_MB1),
                                  hidden + (b * 64 + br * 32) * HW);
}

__global__ __launch_bounds__(256) void conv2_kernel(const unsigned short* __restrict__ hidden,
                                                    const float* __restrict__ wf,
                                                    unsigned short* __restrict__ comb)
{
    int z = blockIdx.z, b = z >> 2, br = (z >> 1) & 1, hf = z & 1;
    // comb pixel-major: image base b*16384*128, channel base br*64+hf*32
    conv3x3_body<32, false, true>(hidden, (long long)(b * 64 + br * 32) * HW, false,
                                  wf + (br ? WF_AW2 : WF_MW2) + hf * 32 * 32 * 9,
                                  wf + (br ? WF_AB2 : WF_MB2) + hf * 32,
                                  comb + (size_t)b * 2097152 + br * 64 + hf * 32);
}

// ---------------------------------------------------------------- K3: MHA (MFMA)
// (r14 verbatim: 256 threads, wave hh owns head hh; setprio kept, harmless)
// LDS map (ushort units, 25,088 total = 50,176 B -> 3 blocks/CU):
//   region0 @0 (8,704 ush): X [64][136]  ->  V^T 4x[32][64]swz  ->  O/D [64][136]
//   head hh @8,704+hh*4,096: Q [64][32]swz | K @+2,048 [64][32]swz
//                            P [64][64]swz overlays Q+K after scores
__global__ __launch_bounds__(256) void mha_kernel(
    const unsigned short* __restrict__ comb,   // [b][y][x][e=128] bf16 pixel-major
    const float* __restrict__ wf,
    unsigned short* __restrict__ att)          // [n][tok][e] bf16, raw out-proj
{
    __shared__ unsigned short lds[25088];

    const unsigned short* wqkv = (const unsigned short*)(wf + WF_IPW); // [384][128] bf16
    const unsigned short* wo   = (const unsigned short*)(wf + WF_OPW); // [128][128] bf16

    // Bijective XCD-chunked batch-major map (HW: block i -> XCD i%8).
    // 3844 = 8*480 + 4: XCD 0..3 own 481 windows, XCD 4..7 own 480.
    const int bid = blockIdx.x;
    const int xcd = bid & 7, idx = bid >> 3;
    const int start = (xcd < 4) ? xcd * 481 : 1924 + (xcd - 4) * 480;
    const int nl = start + idx;            // bb*961 + ih*31 + iw (batch-major raster)
    const int bb = nl / 961;
    const int ihw = nl - bb * 961;
    const int ih = ihw / 31, iw = ihw - ih * 31;
    const int n = ihw * 4 + bb;            // att record index (fuse layout unchanged)

    const int t = threadIdx.x;
    const int lane = t & 63, quad = lane >> 4, l16 = lane & 15;
    const int hh = __builtin_amdgcn_readfirstlane(t >> 6);
    const int hb = hh * 32;
    const int QOFF = 8704 + hh * 4096;
    const int KOFF = QOFF + 2048;
    const int VOFF = hh * 2048;

    // ---- stage X [tok][e] s136: wave hh covers window rows 2hh,2hh+1,
    //      each row = 8 px * 256B = 2KB contiguous -> 1KB coalesced per issue ----
#pragma unroll
    for (int rh = 0; rh < 2; ++rh) {
        const int r = hh * 2 + rh;
        const unsigned short* rp = comb +
            (size_t)(bb * 16384 + (ih * 4 + r) * 128 + iw * 4) * 128;
#pragma unroll
        for (int hv = 0; hv < 2; ++hv) {
            uint4v v = *(const uint4v*)(rp + hv * 512 + lane * 8);
            const int tok = r * 8 + hv * 4 + (lane >> 4);
            *(uint4v*)&lds[tok * 136 + (lane & 15) * 8] = v;
        }
    }
    __syncthreads();

    // ---- pass A: Q,K = Wqkv[0:256] . X^T  (acc[4][4] = 64 regs peak) ----
    {
        f32x4 acc[4][4];
#pragma unroll
        for (int nt = 0; nt < 4; ++nt) {
            const int rb = (nt < 2) ? (hb + nt * 16) : (128 + hb + (nt - 2) * 16);
            f32x4 b4;
            b4[0] = wf[WF_IPB + rb + quad * 4 + 0];
            b4[1] = wf[WF_IPB + rb + quad * 4 + 1];
            b4[2] = wf[WF_IPB + rb + quad * 4 + 2];
            b4[3] = wf[WF_IPB + rb + quad * 4 + 3];
#pragma unroll
            for (int mt = 0; mt < 4; ++mt) acc[nt][mt] = b4;
        }
        __builtin_amdgcn_s_setprio(1);
#pragma unroll
        for (int kc = 0; kc < 4; ++kc) {
            bf16x8 bx[4];
#pragma unroll
            for (int mt = 0; mt < 4; ++mt)
                bx[mt] = frag_ld(&lds[(mt * 16 + l16) * 136 + kc * 32 + quad * 8]);
#pragma unroll
            for (int nt = 0; nt < 4; ++nt) {
                const int rb = (nt < 2) ? (hb + nt * 16) : (128 + hb + (nt - 2) * 16);
                bf16x8 aw = frag_ld(&wqkv[(rb + l16) * 128 + kc * 32 + quad * 8]);
#pragma unroll
                for (int mt = 0; mt < 4; ++mt)
                    acc[nt][mt] = MFMA16(aw, bx[mt], acc[nt][mt]);
            }
        }
        __builtin_amdgcn_s_setprio(0);
        // write Q,K: [tok][d=32], 16B-slot swizzle (slot ^ (tok&3))
#pragma unroll
        for (int nt = 0; nt < 2; ++nt)
#pragma unroll
            for (int mt = 0; mt < 4; ++mt) {
                const int tok = mt * 16 + l16;
                const int aoff = tok * 32 + (((nt * 2 + (quad >> 1)) ^ (tok & 3)) << 3)
                               + (quad & 1) * 4;
                *(uint2v*)&lds[QOFF + aoff] =
                    pack4(acc[nt][mt][0], acc[nt][mt][1], acc[nt][mt][2], acc[nt][mt][3]);
                *(uint2v*)&lds[KOFF + aoff] =
                    pack4(acc[nt + 2][mt][0], acc[nt + 2][mt][1],
                          acc[nt + 2][mt][2], acc[nt + 2][mt][3]);
            }
    }

    // ---- pass B: V = Wqkv[256:384] . X^T  (accv[2][4] = 32 regs) ----
    f32x4 accv[2][4];
#pragma unroll
    for (int nv = 0; nv < 2; ++nv) {
        const int rb = 256 + hb + nv * 16;
        f32x4 b4;
        b4[0] = wf[WF_IPB + rb + quad * 4 + 0];
        b4[1] = wf[WF_IPB + rb + quad * 4 + 1];
        b4[2] = wf[WF_IPB + rb + quad * 4 + 2];
        b4[3] = wf[WF_IPB + rb + quad * 4 + 3];
#pragma unroll
        for (int mt = 0; mt < 4; ++mt) accv[nv][mt] = b4;
    }
    __builtin_amdgcn_s_setprio(1);
#pragma unroll
    for (int kc = 0; kc < 4; ++kc) {
        bf16x8 bx[4];
#pragma unroll
        for (int mt = 0; mt < 4; ++mt)
            bx[mt] = frag_ld(&lds[(mt * 16 + l16) * 136 + kc * 32 + quad * 8]);
#pragma unroll
        for (int nv = 0; nv < 2; ++nv) {
            const int rb = 256 + hb + nv * 16;
            bf16x8 aw = frag_ld(&wqkv[(rb + l16) * 128 + kc * 32 + quad * 8]);
#pragma unroll
            for (int mt = 0; mt < 4; ++mt)
                accv[nv][mt] = MFMA16(aw, bx[mt], accv[nv][mt]);
        }
    }
    __builtin_amdgcn_s_setprio(0);
    __syncthreads();   // all waves done reading X -> region0 reusable; Q/K drained

    // ---- V^T [d=32][tok=64] swz (slot ^ (d&7)), overlays dead X ----
#pragma unroll
    for (int nv = 0; nv < 2; ++nv)
#pragma unroll
        for (int mt = 0; mt < 4; ++mt)
#pragma unroll
            for (int r = 0; r < 4; ++r) {
                const int d = nv * 16 + quad * 4 + r;
                const int tok = mt * 16 + l16;
                lds[VOFF + d * 64 + (((tok >> 3) ^ (d & 7)) << 3) + (tok & 7)] =
                    fbf_hw(accv[nv][mt][r]);
            }

    // ---- scores: S^T = K . Q^T ----
    bf16x8 ak[4], bq[4];
#pragma unroll
    for (int mtk = 0; mtk < 4; ++mtk) {
        const int tok = mtk * 16 + l16;
        ak[mtk] = frag_ld(&lds[KOFF + tok * 32 + ((quad ^ (tok & 3)) << 3)]);
    }
#pragma unroll
    for (int ntq = 0; ntq < 4; ++ntq) {
        const int tok = ntq * 16 + l16;
        bq[ntq] = frag_ld(&lds[QOFF + tok * 32 + ((quad ^ (tok & 3)) << 3)]);
    }
    f32x4 sc[4][4];
    {
        f32x4 zz = {0.f, 0.f, 0.f, 0.f};
        __builtin_amdgcn_s_setprio(1);
#pragma unroll
        for (int mtk = 0; mtk < 4; ++mtk)
#pragma unroll
            for (int ntq = 0; ntq < 4; ++ntq)
                sc[mtk][ntq] = MFMA16(ak[mtk], bq[ntq], zz);
        __builtin_amdgcn_s_setprio(0);
    }

    // ---- softmax; P [tokq][tokk=64] swz (slot ^ (tokq&7)) overlays Q+K ----
    const float scale = 0.17677669529663687f;  // 32^-0.5
#pragma unroll
    for (int ntq = 0; ntq < 4; ++ntq) {
        float m0 = -1e30f;
#pragma unroll
        for (int mtk = 0; mtk < 4; ++mtk)
#pragma unroll
            for (int r = 0; r < 4; ++r) {
                sc[mtk][ntq][r] *= scale;
                m0 = fmaxf(m0, sc[mtk][ntq][r]);
            }
        m0 = fmaxf(m0, __shfl_xor(m0, 16));
        m0 = fmaxf(m0, __shfl_xor(m0, 32));
        float s0 = 0.f;
#pragma unroll
        for (int mtk = 0; mtk < 4; ++mtk)
#pragma unroll
            for (int r = 0; r < 4; ++r) {
                float p = __expf(sc[mtk][ntq][r] - m0);
                sc[mtk][ntq][r] = p;
                s0 += p;
            }
        s0 += __shfl_xor(s0, 16);
        s0 += __shfl_xor(s0, 32);
        float inv = 1.f / s0;
        const int tokq = ntq * 16 + l16;
#pragma unroll
        for (int mtk = 0; mtk < 4; ++mtk)
            *(uint2v*)&lds[QOFF + tokq * 64 +
                           (((mtk * 2 + (quad >> 1)) ^ (tokq & 7)) << 3) + (quad & 1) * 4] =
                pack4(sc[mtk][ntq][0] * inv, sc[mtk][ntq][1] * inv,
                      sc[mtk][ntq][2] * inv, sc[mtk][ntq][3] * inv);
    }
    __asm__ volatile("s_waitcnt lgkmcnt(0)" ::: "memory");  // within-wave P/V handoff

    // ---- O = P . V ----
    f32x4 ov[4][2];
#pragma unroll
    for (int mt = 0; mt < 4; ++mt)
#pragma unroll
        for (int nv = 0; nv < 2; ++nv) { f32x4 zz = {0.f, 0.f, 0.f, 0.f}; ov[mt][nv] = zz; }
    __builtin_amdgcn_s_setprio(1);
#pragma unroll
    for (int ks = 0; ks < 2; ++ks) {
        bf16x8 ap[4];
#pragma unroll
        for (int mt = 0; mt < 4; ++mt) {
            const int tokq = mt * 16 + l16;
            ap[mt] = frag_ld(&lds[QOFF + tokq * 64 + (((ks * 4 + quad) ^ (tokq & 7)) << 3)]);
        }
#pragma unroll
        for (int nv = 0; nv < 2; ++nv) {
            const int d = nv * 16 + l16;
            bf16x8 bv = frag_ld(&lds[VOFF + d * 64 + (((ks * 4 + quad) ^ (d & 7)) << 3)]);
#pragma unroll
            for (int mt = 0; mt < 4; ++mt)
                ov[mt][nv] = MFMA16(ap[mt], bv, ov[mt][nv]);
        }
    }
    __builtin_amdgcn_s_setprio(0);
    __syncthreads();  // all P/V reads done before O overlays region0

    // ---- O -> LDS [tok][e] s136 @0 ----
#pragma unroll
    for (int mt = 0; mt < 4; ++mt)
#pragma unroll
        for (int nv = 0; nv < 2; ++nv)
#pragma unroll
            for (int r = 0; r < 4; ++r)
                lds[(mt * 16 + quad * 4 + r) * 136 + hb + nv * 16 + l16] =
                    fbf_hw(ov[mt][nv][r]);
    __syncthreads();

    // ---- out-proj: D = O . Wo^T (raw; coef+bias applied in fuse) ----
    f32x4 dp[4][2];
#pragma unroll
    for (int mt = 0; mt < 4; ++mt)
#pragma unroll
        for (int nl = 0; nl < 2; ++nl) { f32x4 zz = {0.f, 0.f, 0.f, 0.f}; dp[mt][nl] = zz; }
    __builtin_amdgcn_s_setprio(1);
#pragma unroll
    for (int ks = 0; ks < 4; ++ks) {
        bf16x8 af[4];
#pragma unroll
        for (int mt = 0; mt < 4; ++mt)
            af[mt] = frag_ld(&lds[(mt * 16 + l16) * 136 + ks * 32 + quad * 8]);
#pragma unroll
        for (int nl = 0; nl < 2; ++nl) {
            const int erow = hb + nl * 16 + l16;
            bf16x8 bw = frag_ld(&wo[erow * 128 + ks * 32 + quad * 8]);
#pragma unroll
            for (int mt = 0; mt < 4; ++mt)
                dp[mt][nl] = MFMA16(af[mt], bw, dp[mt][nl]);
        }
    }
    __builtin_amdgcn_s_setprio(0);
    __syncthreads();  // all O reads done before D overlays the same area

    // ---- D -> LDS [tok][e] s136 @0 ----
#pragma unroll
    for (int mt = 0; mt < 4; ++mt)
#pragma unroll
        for (int nl = 0; nl < 2; ++nl)
#pragma unroll
            for (int r = 0; r < 4; ++r)
                lds[(mt * 16 + quad * 4 + r) * 136 + hb + nl * 16 + l16] =
                    fbf_hw(dp[mt][nl][r]);
    __syncthreads();

    // ---- coalesced att store: thread covers (tok = t>>2, 32 e's) ----
    {
        const int tok2 = t >> 2, eo = (t & 3) * 32;
        unsigned short* op = att + (size_t)n * 8192 + tok2 * 128 + eo;
        const unsigned short* lp = lds + tok2 * 136 + eo;
#pragma unroll
        for (int k4 = 0; k4 < 4; ++k4)
            *(uint4v*)(op + k4 * 8) = *(const uint4v*)(lp + k4 * 8);
    }
}

// ---------------------------------------------------------------- K4: fuse
// gathers <=4 covering windows per pixel with closed-form scan coefs.
__global__ __launch_bounds__(256) void fuse_kernel(
    const unsigned short* __restrict__ comb,  // pixel-major [b][y][x][128]
    const unsigned short* __restrict__ att,   // [n][tok][e] raw out-proj
    const void* __restrict__ vf,
    const float* __restrict__ wf,
    const int* __restrict__ flag,
    void* __restrict__ outp)
{
    __shared__ float enhs[128][65];
    __shared__ float fws[64][65];
    const float* fcw = wf + WF_FCW;
    const float* fcb = wf + WF_FCB;
    const bool f32 = (*flag != 0);
    const int t = threadIdx.x;
    const int wl = t & 63;
    const int eg = __builtin_amdgcn_readfirstlane(t >> 6);
    const int h = blockIdx.y, b = blockIdx.z;
    const int w = blockIdx.x * 64 + wl;

    const int mh = h >> 2, mw = w >> 2;
    const bool vh0 = (mh >= 1), vh1 = (mh <= 30);
    const bool vw0 = (mw >= 1), vw1 = (mw <= 30);
    const int k = ((int)vh0 + (int)vh1) * ((int)vw0 + (int)vw1); // 1,2,4
    const float base7 = (k == 1) ? 0.7f : (k == 2) ? 0.49f : 0.2401f;
    const float bias_c = 1.f - base7;  // sum_j coef_j (out-proj bias weight)

    float cw[4]; int coff[4];
    {
        const bool vs[4] = { vh0 && vw0, vh0 && vw1, vh1 && vw0, vh1 && vw1 };
        const int ihc[4] = { mh - 1, mh - 1, mh, mh };
        const int iwc[4] = { mw - 1, mw, mw - 1, mw };
        int j = 0;
#pragma unroll
        for (int s = 0; s < 4; ++s) {
            if (vs[s]) {
                ++j;
                int e2 = k - j;  // 0..3
                float pw = (e2 == 0) ? 1.f : (e2 == 1) ? 0.7f : (e2 == 2) ? 0.49f : 0.343f;
                cw[s] = 0.3f * pw;
                int nn = (ihc[s] * 31 + iwc[s]) * 4 + b;
                int ll = (h - 4 * ihc[s]) * 8 + (w - 4 * iwc[s]);
                coff[s] = nn * 8192 + ll * 128;
            } else { cw[s] = 0.f; coff[s] = 0; }
        }
    }

    const int cbase = (b * 128) * HW + h * 128 + w;                 // vf/out index
    const size_t cpix = (size_t)(b * 16384 + h * 128 + w) * 128;    // comb record
    const int e0 = eg * 32;
#pragma unroll
    for (int i8 = 0; i8 < 4; ++i8) {
        float av[8];
#pragma unroll
        for (int j = 0; j < 8; ++j)
            av[j] = bias_c * wf[WF_OPB + e0 + i8 * 8 + j];
#pragma unroll
        for (int s = 0; s < 4; ++s) {
            uint4v u = *(const uint4v*)(att + coff[s] + e0 + i8 * 8);
            float x[8];
            unp8(u, x);
#pragma unroll
            for (int j = 0; j < 8; ++j)
                av[j] = fmaf(cw[s], x[j], av[j]);
        }
        uint4v cu = *(const uint4v*)(comb + cpix + e0 + i8 * 8);
        float cx[8];
        unp8(cu, cx);
#pragma unroll
        for (int j = 0; j < 8; ++j)
            enhs[e0 + i8 * 8 + j][wl] = fmaf(base7, cx[j], av[j]);
    }
    __syncthreads();

    // gate matvec: fcw via float4 (4x fewer VMEM instrs); per-a2[i] order
    // stays e-ascending -> bit-identical.
    float a2[16];
    const int co0 = eg * 16;
#pragma unroll
    for (int i = 0; i < 16; ++i) a2[i] = fcb[co0 + i];
    const float4* fcw4 = (const float4*)fcw;   // row stride 32 float4
    for (int eb = 0; eb < 32; ++eb) {
        float x0 = enhs[eb * 4 + 0][wl];
        float x1 = enhs[eb * 4 + 1][wl];
        float x2 = enhs[eb * 4 + 2][wl];
        float x3 = enhs[eb * 4 + 3][wl];
#pragma unroll
        for (int i = 0; i < 16; ++i) {
            float4 wv4 = fcw4[(co0 + i) * 32 + eb];
            float a = a2[i];
            a = fmaf(x0, wv4.x, a);
            a = fmaf(x1, wv4.y, a);
            a = fmaf(x2, wv4.z, a);
            a = fmaf(x3, wv4.w, a);
            a2[i] = a;
        }
    }
#pragma unroll
    for (int i = 0; i < 16; ++i)
        fws[co0 + i][wl] = 1.f / (1.f + __expf(-a2[i]));
    __syncthreads();

#pragma unroll
    for (int i = 0; i < 32; ++i) {
        const int e = eg * 32 + i;
        const int idx = cbase + e * HW;
        float val = enhs[e][wl] * fws[e & 63][wl] + ldin(vf, idx, f32);
        if (f32) ((float*)outp)[idx] = val;
        else     ((unsigned short*)outp)[idx] = fbf_hw(val);
    }
}

// ---------------------------------------------------------------------------
extern "C" void kernel_launch(void* const* d_in, const int* in_sizes, int n_in,
                              void* d_out, int out_size, void* d_ws, size_t ws_size,
                              hipStream_t stream)
{
    const void* vf  = d_in[0];
    const void* mw1 = d_in[1];
    const void* mb1 = d_in[2];
    const void* mw2 = d_in[3];
    const void* mb2 = d_in[4];
    const void* aw1 = d_in[5];
    const void* ab1 = d_in[6];
    const void* aw2 = d_in[7];
    const void* ab2 = d_in[8];
    const void* ipw = d_in[9];
    const void* ipb = d_in[10];
    const void* opw = d_in[11];
    const void* opb = d_in[12];
    const void* fcw = d_in[13];
    const void* fcb = d_in[14];

    // ws layout (80,351,232 B total)
    int* flag = (int*)d_ws;                                         // @0
    float* wf = (float*)((char*)d_ws + 1024);                       // 592,896 B
    unsigned short* comb = (unsigned short*)((char*)d_ws + 593920); // 16,777,216 B (pixel-major)
    unsigned short* hidden = (unsigned short*)((char*)d_ws + 17371136); // 8.39 MB
    unsigned short* att = (unsigned short*)((char*)d_ws + 17371136);    // 62,980,096 B (overlays hidden)

    detect_kernel<<<1, 256, 0, stream>>>((const unsigned short*)vf, flag);
    cvtw_kernel<<<(WF_TOTAL + 255) / 256, 256, 0, stream>>>(
        ipw, ipb, opw, opb, fcw, fcb, mw1, mb1, aw1, ab1, mw2, mb2, aw2, ab2, flag, wf);
    conv1_kernel<<<dim3(4, 32, 8), 256, 0, stream>>>(vf, wf, flag, hidden);
    conv2_kernel<<<dim3(4, 32, 16), 256, 0, stream>>>(hidden, wf, comb);
    mha_kernel<<<NSEQ, 256, 0, stream>>>(comb, wf, att);
    fuse_kernel<<<dim3(2, 128, 4), 256, 0, stream>>>(comb, att, vf, wf, flag, d_out);
}

// Round 8
// 344.496 us; speedup vs baseline: 1.3004x; 1.1275x over previous
//
#include <hip/hip_runtime.h>
#include <hip/hip_bf16.h>

// ---------------------------------------------------------------------------
// VectorFieldAttention on MI355X — round 16 (conv2 -> MFMA implicit GEMM)
//
// r15 post-mortem: conv/fuse vectorization only -8us -> convs are VALU-issue-
// bound in the f32 fma loop itself (9216 fma/thread, 33% eff), not staging.
// r16: conv2 moves to the matrix pipe. conv1 writes hidden PIXEL-MAJOR
// [b*2+br][px][32ch] bf16; cvtw emits bf16 conv2 weights [br][64oc][9][32ic]
// into the dead upper half of the WF_IPW region; new conv2 = per-tap MFMA
// (9 taps x 8 mfma/wave, bias-seeded, record-80B LDS staging = 2-way alias).
// Numerics: conv2 weights bf16-rounded + MFMA accum order -> absmax moves off
// 0.03125; predicted 0.03-0.07 vs threshold 0.109. mha/fuse unchanged.
// ws: flag@0 | wf@1024 | comb@593,920 | hidden@17,371,136 (dead after conv2)
//     overlaid by att@17,371,136 (62,980,096 B) -> total 80,351,232 B.
// ---------------------------------------------------------------------------

#define HW 16384           // 128*128
#define NSEQ 3844          // 961 windows * 4 batch

// f32 weight file offsets (floats)
#define WF_IPW 0
#define WF_IPB 49152
#define WF_OPW 49536
#define WF_OPB 65920
#define WF_FCW 66048
#define WF_FCB 74240
#define WF_MW1 74304
#define WF_MB1 92736
#define WF_AW1 92768
#define WF_AB1 111200
#define WF_MW2 111232
#define WF_MB2 129664
#define WF_AW2 129728
#define WF_AB2 148160
#define WF_TOTAL 148224
#define WF_W2BF 24576      // bf16 conv2 weights (ushort idx base inside wf floats)

typedef __bf16 bf16x8 __attribute__((ext_vector_type(8)));
typedef float f32x4 __attribute__((ext_vector_type(4)));
typedef unsigned int uint2v __attribute__((ext_vector_type(2)));
typedef unsigned int uint4v __attribute__((ext_vector_type(4)));

#define MFMA16(a, b, c) __builtin_amdgcn_mfma_f32_16x16x32_bf16((a), (b), (c), 0, 0, 0)

__device__ __forceinline__ float bfu(unsigned short u) {
    union { unsigned int i; float f; } v; v.i = ((unsigned int)u) << 16; return v.f;
}
// software RNE (cold paths only; bit-identical to v_cvt_pk_bf16_f32)
__device__ __forceinline__ unsigned short fbf(float f) {
    union { float f; unsigned int i; } v; v.f = f;
    unsigned int x = v.i;
    return (unsigned short)((x + 0x7fffu + ((x >> 16) & 1u)) >> 16);
}
// HW RNE pack: lo16 = bf16(a), hi16 = bf16(b). 1 VALU op.
__device__ __forceinline__ unsigned int cvt_pk_bf16(float a, float b) {
    unsigned int r;
    asm("v_cvt_pk_bf16_f32 %0, %1, %2" : "=v"(r) : "v"(a), "v"(b));
    return r;
}
__device__ __forceinline__ unsigned short fbf_hw(float f) {
    return (unsigned short)cvt_pk_bf16(f, f);
}
__device__ __forceinline__ float ldin(const void* p, long long i, bool f32) {
    return f32 ? ((const float*)p)[i] : bfu(((const unsigned short*)p)[i]);
}
__device__ __forceinline__ bf16x8 frag_ld(const unsigned short* p) {
    union { uint4v u; bf16x8 b; } v;
    v.u = *(const uint4v*)p;
    return v.b;
}
__device__ __forceinline__ uint2v pack4(float a, float b, float c, float d) {
    uint2v r;
    r.x = cvt_pk_bf16(a, b);
    r.y = cvt_pk_bf16(c, d);
    return r;
}
__device__ __forceinline__ void unp8(uint4v u, float* x) {
    union { unsigned int i; float f; } a;
    a.i = u.x << 16;         x[0] = a.f;
    a.i = u.x & 0xffff0000u; x[1] = a.f;
    a.i = u.y << 16;         x[2] = a.f;
    a.i = u.y & 0xffff0000u; x[3] = a.f;
    a.i = u.z << 16;         x[4] = a.f;
    a.i = u.z & 0xffff0000u; x[5] = a.f;
    a.i = u.w << 16;         x[6] = a.f;
    a.i = u.w & 0xffff0000u; x[7] = a.f;
}

// ------------------------------------------------------------- K-1: detect
__global__ __launch_bounds__(256) void detect_kernel(const unsigned short* __restrict__ vfu,
                                                     int* __restrict__ flag)
{
    __shared__ int cnt;
    if (threadIdx.x == 0) cnt = 0;
    __syncthreads();
    int bad = 0;
    for (int i = threadIdx.x; i < 8192; i += 256) {
        int e = (vfu[i] >> 7) & 0xff;
        if (e < 0x60 || e > 0xA0) ++bad;
    }
    atomicAdd(&cnt, bad);
    __syncthreads();
    if (threadIdx.x == 0) *flag = (cnt > 400) ? 1 : 0;
}

// ---------------------------------------------------------------- K0: weights
__global__ __launch_bounds__(256) void cvtw_kernel(
    const void* ipw, const void* ipb,
    const void* opw, const void* opb,
    const void* fcw, const void* fcb,
    const void* mw1, const void* mb1,
    const void* aw1, const void* ab1,
    const void* mw2, const void* mb2,
    const void* aw2, const void* ab2,
    const int* __restrict__ flag, float* __restrict__ wf)
{
    int i = blockIdx.x * 256 + threadIdx.x;
    if (i >= WF_TOTAL) return;
    const bool f32 = (*flag != 0);
    const void* src; int off;
    if      (i < WF_IPB) { src = ipw; off = WF_IPW; }
    else if (i < WF_OPW) { src = ipb; off = WF_IPB; }
    else if (i < WF_OPB) { src = opw; off = WF_OPW; }
    else if (i < WF_FCW) { src = opb; off = WF_OPB; }
    else if (i < WF_FCB) { src = fcw; off = WF_FCW; }
    else if (i < WF_MW1) { src = fcb; off = WF_FCB; }
    else if (i < WF_MB1) { src = mw1; off = WF_MW1; }
    else if (i < WF_AW1) { src = mb1; off = WF_MB1; }
    else if (i < WF_AB1) { src = aw1; off = WF_AW1; }
    else if (i < WF_MB2) { src = (i < WF_MW2) ? ab1 : mw2; off = (i < WF_MW2) ? WF_AB1 : WF_MW2; }
    else if (i < WF_AW2) { src = mb2; off = WF_MB2; }
    else if (i < WF_AB2) { src = aw2; off = WF_AW2; }
    else                 { src = ab2; off = WF_AB2; }
    float v = ldin(src, i - off, f32);
    if (i < WF_IPB) {
        ((unsigned short*)(wf + WF_IPW))[i] = fbf(v);           // wqkv_bf [384][128]
    } else if (i >= WF_OPW && i < WF_OPB) {
        ((unsigned short*)(wf + WF_OPW))[i - WF_OPW] = fbf(v);  // wo_bf [128][128]
    } else {
        wf[i] = v;
    }
    // bf16 conv2 weights, tap-major: w2bf[br][oc 64][tap 9][ic 32]
    if (i >= WF_MW2 && i < WF_MB2) {
        int rel = i - WF_MW2;                  // [oc][ic][tap]
        int oc = rel / 288, rem = rel - oc * 288;
        int ic = rem / 9, tap = rem - ic * 9;
        ((unsigned short*)(wf + WF_W2BF))[oc * 288 + tap * 32 + ic] = fbf(v);
    } else if (i >= WF_AW2 && i < WF_AB2) {
        int rel = i - WF_AW2;
        int oc = rel / 288, rem = rel - oc * 288;
        int ic = rem / 9, tap = rem - ic * 9;
        ((unsigned short*)(wf + WF_W2BF))[18432 + oc * 288 + tap * 32 + ic] = fbf(v);
    }
}

// ------------------------------------------------------------- conv1 (VALU)
// 32x4 tile, 2 px/thread; output PIXEL-MAJOR records [px][32ch] bf16.
template<int IC, bool RELU>
__device__ void conv3x3_body(const void* __restrict__ in, long long in_off, bool f32,
                             const float* __restrict__ w,    // [32][IC][9]
                             const float* __restrict__ bias, // [32]
                             unsigned short* __restrict__ out)   // + record base
{
    __shared__ float xs[32][6][37];
    const int t = threadIdx.x;
    const int tx0 = blockIdx.x * 32, ty0 = blockIdx.y * 4;
    const int wv = __builtin_amdgcn_readfirstlane(t >> 6);
    const int lane = t & 63;
    const int pr = lane >> 4, pc2 = lane & 15;   // 4 rows x 16 pairs

    float acc[8][2];
#pragma unroll
    for (int oo = 0; oo < 8; ++oo)
#pragma unroll
        for (int p = 0; p < 2; ++p) acc[oo][p] = 0.f;

    for (int cc = 0; cc < IC; cc += 32) {
        if (cc) __syncthreads();
        for (int i = t; i < 32 * 108; i += 256) {
            int c = i / 108, rem = i - c * 108;
            int rr = rem / 18, s = rem - rr * 18;
            int gy = ty0 + rr - 1;
            const bool gyok = (gy >= 0 && gy < 128);
            long long rowoff = in_off + (long long)(cc + c) * HW + gy * 128;
            if (s >= 1 && s <= 16) {
                int cx = 2 * s - 1;
                int gx = tx0 + cx - 1;
                float v0 = 0.f, v1 = 0.f;
                if (gyok) {
                    if (f32) {
                        float2 u = *(const float2*)((const float*)in + rowoff + gx);
                        v0 = u.x; v1 = u.y;
                    } else {
                        unsigned int u = *(const unsigned int*)
                            ((const unsigned short*)in + rowoff + gx);
                        v0 = bfu((unsigned short)(u & 0xffffu));
                        v1 = bfu((unsigned short)(u >> 16));
                    }
                }
                xs[c][rr][cx] = v0;
                xs[c][rr][cx + 1] = v1;
            } else {
                int cx = (s == 0) ? 0 : 33;
                int gx = tx0 + cx - 1;
                float v = 0.f;
                if (gyok && gx >= 0 && gx < 128)
                    v = ldin(in, rowoff + gx, f32);
                xs[c][rr][cx] = v;
            }
        }
        __syncthreads();
        for (int c = 0; c < 32; ++c) {
            float xv[3][4];
#pragma unroll
            for (int dy = 0; dy < 3; ++dy)
#pragma unroll
                for (int dx = 0; dx < 4; ++dx)
                    xv[dy][dx] = xs[c][pr + dy][pc2 * 2 + dx];
            const float* wr0 = w + (wv * 8 * IC + (cc + c)) * 9;
#pragma unroll
            for (int oo = 0; oo < 8; ++oo) {
                const float* wr = wr0 + oo * IC * 9;
#pragma unroll
                for (int dy = 0; dy < 3; ++dy)
#pragma unroll
                    for (int dx = 0; dx < 3; ++dx) {
                        float wvv = wr[dy * 3 + dx];
#pragma unroll
                        for (int p = 0; p < 2; ++p)
                            acc[oo][p] = fmaf(wvv, xv[dy][p + dx], acc[oo][p]);
                    }
            }
        }
    }
    const int px = tx0 + pc2 * 2, py = ty0 + pr;
#pragma unroll
    for (int p = 0; p < 2; ++p) {
        union { unsigned int u32[4]; uint4v v; } pk;
#pragma unroll
        for (int j = 0; j < 4; ++j) {
            float v0 = acc[2 * j][p] + bias[wv * 8 + 2 * j];
            float v1 = acc[2 * j + 1][p] + bias[wv * 8 + 2 * j + 1];
            if (RELU) { v0 = fmaxf(v0, 0.f); v1 = fmaxf(v1, 0.f); }
            pk.u32[j] = cvt_pk_bf16(v0, v1);
        }
        *(uint4v*)(out + (size_t)(py * 128 + px + p) * 32 + wv * 8) = pk.v;
    }
}

__global__ __launch_bounds__(256) void conv1_kernel(const void* __restrict__ vf,
                                                    const float* __restrict__ wf,
                                                    const int* __restrict__ flag,
                                                    unsigned short* __restrict__ hidden)
{
    int z = blockIdx.z, b = z >> 1, br = z & 1;
    const bool f32 = (*flag != 0);
    conv3x3_body<64, true>(vf, (long long)(b * 128 + br * 64) * HW, f32,
                           wf + (br ? WF_AW1 : WF_MW1), wf + (br ? WF_AB1 : WF_MB1),
                           hidden + (size_t)z * 16384 * 32);
}

// ------------------------------------------------------------- conv2 (MFMA)
// Per block: 32x4 px tile, 64 oc (one branch). Stage [6 rows][34 cols] px
// records (32ch bf16, padded to 40 ush = 80B -> 2-way bank alias = free).
// 9 taps x (4 oc-tiles x 2 px-tiles) mfma per wave; bias-seeded acc.
__global__ __launch_bounds__(256) void conv2_kernel(const unsigned short* __restrict__ hidden,
                                                    const float* __restrict__ wf,
                                                    unsigned short* __restrict__ comb)
{
    __shared__ unsigned short xs[8160];   // 204 records * 40 ush
    const int t = threadIdx.x;
    const int tx0 = blockIdx.x * 32, ty0 = blockIdx.y * 4;
    const int z = blockIdx.z, b = z >> 1, br = z & 1;
    const size_t ibase = (size_t)z * 16384;

    // stage 6x34 records (16B quarters), zero OOB
    for (int i = t; i < 816; i += 256) {
        const int rec = i >> 2, part = i & 3;
        const int rr = rec / 34, cx = rec - rr * 34;
        const int gy = ty0 + rr - 1, gx = tx0 + cx - 1;
        uint4v v = {0u, 0u, 0u, 0u};
        if (gy >= 0 && gy < 128 && gx >= 0 && gx < 128)
            v = *(const uint4v*)(hidden + (ibase + gy * 128 + gx) * 32 + part * 8);
        *(uint4v*)&xs[rec * 40 + part * 8] = v;
    }
    __syncthreads();

    const int lane = t & 63, quad = lane >> 4, l16 = lane & 15;
    const int wv = __builtin_amdgcn_readfirstlane(t >> 6);   // output row ty0+wv
    const unsigned short* w2 = (const unsigned short*)(wf + WF_W2BF) + br * 18432;
    const float* bias = wf + (br ? WF_AB2 : WF_MB2);         // [64]

    f32x4 acc[4][2];   // [oc-tile][px-half]
#pragma unroll
    for (int oct = 0; oct < 4; ++oct) {
        f32x4 b4;
#pragma unroll
        for (int r = 0; r < 4; ++r) b4[r] = bias[oct * 16 + quad * 4 + r];
        acc[oct][0] = b4;
        acc[oct][1] = b4;
    }

    __builtin_amdgcn_s_setprio(1);
#pragma unroll
    for (int tap = 0; tap < 9; ++tap) {
        const int dy = tap / 3, dx = tap - dy * 3;
        bf16x8 bxf[2];
#pragma unroll
        for (int pt2 = 0; pt2 < 2; ++pt2)
            bxf[pt2] = frag_ld(&xs[((wv + dy) * 34 + (pt2 * 16 + l16 + dx)) * 40 + quad * 8]);
#pragma unroll
        for (int oct = 0; oct < 4; ++oct) {
            bf16x8 af = frag_ld(&w2[(oct * 16 + l16) * 288 + tap * 32 + quad * 8]);
            acc[oct][0] = MFMA16(af, bxf[0], acc[oct][0]);
            acc[oct][1] = MFMA16(af, bxf[1], acc[oct][1]);
        }
    }
    __builtin_amdgcn_s_setprio(0);

    // epilogue: D row = oc = oct*16 + quad*4 + r, col = px = l16
#pragma unroll
    for (int pt2 = 0; pt2 < 2; ++pt2) {
        const int px_ = tx0 + pt2 * 16 + l16;
        unsigned short* op = comb + ((size_t)b * 16384 + (ty0 + wv) * 128 + px_) * 128
                           + br * 64 + quad * 4;
#pragma unroll
        for (int oct = 0; oct < 4; ++oct)
            *(uint2v*)(op + oct * 16) =
                pack4(acc[oct][pt2][0], acc[oct][pt2][1],
                      acc[oct][pt2][2], acc[oct][pt2][3]);
    }
}

// ---------------------------------------------------------------- K3: MHA (MFMA)
// (r14 verbatim: 256 threads, wave hh owns head hh; setprio kept)
// LDS map (ushort units, 25,088 total = 50,176 B -> 3 blocks/CU):
//   region0 @0 (8,704 ush): X [64][136]  ->  V^T 4x[32][64]swz  ->  O/D [64][136]
//   head hh @8,704+hh*4,096: Q [64][32]swz | K @+2,048 [64][32]swz
//                            P [64][64]swz overlays Q+K after scores
__global__ __launch_bounds__(256) void mha_kernel(
    const unsigned short* __restrict__ comb,   // [b][y][x][e=128] bf16 pixel-major
    const float* __restrict__ wf,
    unsigned short* __restrict__ att)          // [n][tok][e] bf16, raw out-proj
{
    __shared__ unsigned short lds[25088];

    const unsigned short* wqkv = (const unsigned short*)(wf + WF_IPW); // [384][128] bf16
    const unsigned short* wo   = (const unsigned short*)(wf + WF_OPW); // [128][128] bf16

    // Bijective XCD-chunked batch-major map (HW: block i -> XCD i%8).
    const int bid = blockIdx.x;
    const int xcd = bid & 7, idx = bid >> 3;
    const int start = (xcd < 4) ? xcd * 481 : 1924 + (xcd - 4) * 480;
    const int nl = start + idx;
    const int bb = nl / 961;
    const int ihw = nl - bb * 961;
    const int ih = ihw / 31, iw = ihw - ih * 31;
    const int n = ihw * 4 + bb;

    const int t = threadIdx.x;
    const int lane = t & 63, quad = lane >> 4, l16 = lane & 15;
    const int hh = __builtin_amdgcn_readfirstlane(t >> 6);
    const int hb = hh * 32;
    const int QOFF = 8704 + hh * 4096;
    const int KOFF = QOFF + 2048;
    const int VOFF = hh * 2048;

#pragma unroll
    for (int rh = 0; rh < 2; ++rh) {
        const int r = hh * 2 + rh;
        const unsigned short* rp = comb +
            (size_t)(bb * 16384 + (ih * 4 + r) * 128 + iw * 4) * 128;
#pragma unroll
        for (int hv = 0; hv < 2; ++hv) {
            uint4v v = *(const uint4v*)(rp + hv * 512 + lane * 8);
            const int tok = r * 8 + hv * 4 + (lane >> 4);
            *(uint4v*)&lds[tok * 136 + (lane & 15) * 8] = v;
        }
    }
    __syncthreads();

    // ---- pass A: Q,K = Wqkv[0:256] . X^T ----
    {
        f32x4 acc[4][4];
#pragma unroll
        for (int nt = 0; nt < 4; ++nt) {
            const int rb = (nt < 2) ? (hb + nt * 16) : (128 + hb + (nt - 2) * 16);
            f32x4 b4;
            b4[0] = wf[WF_IPB + rb + quad * 4 + 0];
            b4[1] = wf[WF_IPB + rb + quad * 4 + 1];
            b4[2] = wf[WF_IPB + rb + quad * 4 + 2];
            b4[3] = wf[WF_IPB + rb + quad * 4 + 3];
#pragma unroll
            for (int mt = 0; mt < 4; ++mt) acc[nt][mt] = b4;
        }
        __builtin_amdgcn_s_setprio(1);
#pragma unroll
        for (int kc = 0; kc < 4; ++kc) {
            bf16x8 bx[4];
#pragma unroll
            for (int mt = 0; mt < 4; ++mt)
                bx[mt] = frag_ld(&lds[(mt * 16 + l16) * 136 + kc * 32 + quad * 8]);
#pragma unroll
            for (int nt = 0; nt < 4; ++nt) {
                const int rb = (nt < 2) ? (hb + nt * 16) : (128 + hb + (nt - 2) * 16);
                bf16x8 aw = frag_ld(&wqkv[(rb + l16) * 128 + kc * 32 + quad * 8]);
#pragma unroll
                for (int mt = 0; mt < 4; ++mt)
                    acc[nt][mt] = MFMA16(aw, bx[mt], acc[nt][mt]);
            }
        }
        __builtin_amdgcn_s_setprio(0);
#pragma unroll
        for (int nt = 0; nt < 2; ++nt)
#pragma unroll
            for (int mt = 0; mt < 4; ++mt) {
                const int tok = mt * 16 + l16;
                const int aoff = tok * 32 + (((nt * 2 + (quad >> 1)) ^ (tok & 3)) << 3)
                               + (quad & 1) * 4;
                *(uint2v*)&lds[QOFF + aoff] =
                    pack4(acc[nt][mt][0], acc[nt][mt][1], acc[nt][mt][2], acc[nt][mt][3]);
                *(uint2v*)&lds[KOFF + aoff] =
                    pack4(acc[nt + 2][mt][0], acc[nt + 2][mt][1],
                          acc[nt + 2][mt][2], acc[nt + 2][mt][3]);
            }
    }

    // ---- pass B: V = Wqkv[256:384] . X^T ----
    f32x4 accv[2][4];
#pragma unroll
    for (int nv = 0; nv < 2; ++nv) {
        const int rb = 256 + hb + nv * 16;
        f32x4 b4;
        b4[0] = wf[WF_IPB + rb + quad * 4 + 0];
        b4[1] = wf[WF_IPB + rb + quad * 4 + 1];
        b4[2] = wf[WF_IPB + rb + quad * 4 + 2];
        b4[3] = wf[WF_IPB + rb + quad * 4 + 3];
#pragma unroll
        for (int mt = 0; mt < 4; ++mt) accv[nv][mt] = b4;
    }
    __builtin_amdgcn_s_setprio(1);
#pragma unroll
    for (int kc = 0; kc < 4; ++kc) {
        bf16x8 bx[4];
#pragma unroll
        for (int mt = 0; mt < 4; ++mt)
            bx[mt] = frag_ld(&lds[(mt * 16 + l16) * 136 + kc * 32 + quad * 8]);
#pragma unroll
        for (int nv = 0; nv < 2; ++nv) {
            const int rb = 256 + hb + nv * 16;
            bf16x8 aw = frag_ld(&wqkv[(rb + l16) * 128 + kc * 32 + quad * 8]);
#pragma unroll
            for (int mt = 0; mt < 4; ++mt)
                accv[nv][mt] = MFMA16(aw, bx[mt], accv[nv][mt]);
        }
    }
    __builtin_amdgcn_s_setprio(0);
    __syncthreads();

    // ---- V^T [d=32][tok=64] swz (slot ^ (d&7)), overlays dead X ----
#pragma unroll
    for (int nv = 0; nv < 2; ++nv)
#pragma unroll
        for (int mt = 0; mt < 4; ++mt)
#pragma unroll
            for (int r = 0; r < 4; ++r) {
                const int d = nv * 16 + quad * 4 + r;
                const int tok = mt * 16 + l16;
                lds[VOFF + d * 64 + (((tok >> 3) ^ (d & 7)) << 3) + (tok & 7)] =
                    fbf_hw(accv[nv][mt][r]);
            }

    // ---- scores: S^T = K . Q^T ----
    bf16x8 ak[4], bq[4];
#pragma unroll
    for (int mtk = 0; mtk < 4; ++mtk) {
        const int tok = mtk * 16 + l16;
        ak[mtk] = frag_ld(&lds[KOFF + tok * 32 + ((quad ^ (tok & 3)) << 3)]);
    }
#pragma unroll
    for (int ntq = 0; ntq < 4; ++ntq) {
        const int tok = ntq * 16 + l16;
        bq[ntq] = frag_ld(&lds[QOFF + tok * 32 + ((quad ^ (tok & 3)) << 3)]);
    }
    f32x4 sc[4][4];
    {
        f32x4 zz = {0.f, 0.f, 0.f, 0.f};
        __builtin_amdgcn_s_setprio(1);
#pragma unroll
        for (int mtk = 0; mtk < 4; ++mtk)
#pragma unroll
            for (int ntq = 0; ntq < 4; ++ntq)
                sc[mtk][ntq] = MFMA16(ak[mtk], bq[ntq], zz);
        __builtin_amdgcn_s_setprio(0);
    }

    // ---- softmax; P [tokq][tokk=64] swz (slot ^ (tokq&7)) overlays Q+K ----
    const float scale = 0.17677669529663687f;  // 32^-0.5
#pragma unroll
    for (int ntq = 0; ntq < 4; ++ntq) {
        float m0 = -1e30f;
#pragma unroll
        for (int mtk = 0; mtk < 4; ++mtk)
#pragma unroll
            for (int r = 0; r < 4; ++r) {
                sc[mtk][ntq][r] *= scale;
                m0 = fmaxf(m0, sc[mtk][ntq][r]);
            }
        m0 = fmaxf(m0, __shfl_xor(m0, 16));
        m0 = fmaxf(m0, __shfl_xor(m0, 32));
        float s0 = 0.f;
#pragma unroll
        for (int mtk = 0; mtk < 4; ++mtk)
#pragma unroll
            for (int r = 0; r < 4; ++r) {
                float p = __expf(sc[mtk][ntq][r] - m0);
                sc[mtk][ntq][r] = p;
                s0 += p;
            }
        s0 += __shfl_xor(s0, 16);
        s0 += __shfl_xor(s0, 32);
        float inv = 1.f / s0;
        const int tokq = ntq * 16 + l16;
#pragma unroll
        for (int mtk = 0; mtk < 4; ++mtk)
            *(uint2v*)&lds[QOFF + tokq * 64 +
                           (((mtk * 2 + (quad >> 1)) ^ (tokq & 7)) << 3) + (quad & 1) * 4] =
                pack4(sc[mtk][ntq][0] * inv, sc[mtk][ntq][1] * inv,
                      sc[mtk][ntq][2] * inv, sc[mtk][ntq][3] * inv);
    }
    __asm__ volatile("s_waitcnt lgkmcnt(0)" ::: "memory");  // within-wave P/V handoff

    // ---- O = P . V ----
    f32x4 ov[4][2];
#pragma unroll
    for (int mt = 0; mt < 4; ++mt)
#pragma unroll
        for (int nv = 0; nv < 2; ++nv) { f32x4 zz = {0.f, 0.f, 0.f, 0.f}; ov[mt][nv] = zz; }
    __builtin_amdgcn_s_setprio(1);
#pragma unroll
    for (int ks = 0; ks < 2; ++ks) {
        bf16x8 ap[4];
#pragma unroll
        for (int mt = 0; mt < 4; ++mt) {
            const int tokq = mt * 16 + l16;
            ap[mt] = frag_ld(&lds[QOFF + tokq * 64 + (((ks * 4 + quad) ^ (tokq & 7)) << 3)]);
        }
#pragma unroll
        for (int nv = 0; nv < 2; ++nv) {
            const int d = nv * 16 + l16;
            bf16x8 bv = frag_ld(&lds[VOFF + d * 64 + (((ks * 4 + quad) ^ (d & 7)) << 3)]);
#pragma unroll
            for (int mt = 0; mt < 4; ++mt)
                ov[mt][nv] = MFMA16(ap[mt], bv, ov[mt][nv]);
        }
    }
    __builtin_amdgcn_s_setprio(0);
    __syncthreads();

    // ---- O -> LDS [tok][e] s136 @0 ----
#pragma unroll
    for (int mt = 0; mt < 4; ++mt)
#pragma unroll
        for (int nv = 0; nv < 2; ++nv)
#pragma unroll
            for (int r = 0; r < 4; ++r)
                lds[(mt * 16 + quad * 4 + r) * 136 + hb + nv * 16 + l16] =
                    fbf_hw(ov[mt][nv][r]);
    __syncthreads();

    // ---- out-proj: D = O . Wo^T ----
    f32x4 dp[4][2];
#pragma unroll
    for (int mt = 0; mt < 4; ++mt)
#pragma unroll
        for (int nl = 0; nl < 2; ++nl) { f32x4 zz = {0.f, 0.f, 0.f, 0.f}; dp[mt][nl] = zz; }
    __builtin_amdgcn_s_setprio(1);
#pragma unroll
    for (int ks = 0; ks < 4; ++ks) {
        bf16x8 af[4];
#pragma unroll
        for (int mt = 0; mt < 4; ++mt)
            af[mt] = frag_ld(&lds[(mt * 16 + l16) * 136 + ks * 32 + quad * 8]);
#pragma unroll
        for (int nl = 0; nl < 2; ++nl) {
            const int erow = hb + nl * 16 + l16;
            bf16x8 bw = frag_ld(&wo[erow * 128 + ks * 32 + quad * 8]);
#pragma unroll
            for (int mt = 0; mt < 4; ++mt)
                dp[mt][nl] = MFMA16(af[mt], bw, dp[mt][nl]);
        }
    }
    __builtin_amdgcn_s_setprio(0);
    __syncthreads();

    // ---- D -> LDS [tok][e] s136 @0 ----
#pragma unroll
    for (int mt = 0; mt < 4; ++mt)
#pragma unroll
        for (int nl = 0; nl < 2; ++nl)
#pragma unroll
            for (int r = 0; r < 4; ++r)
                lds[(mt * 16 + quad * 4 + r) * 136 + hb + nl * 16 + l16] =
                    fbf_hw(dp[mt][nl][r]);
    __syncthreads();

    // ---- coalesced att store ----
    {
        const int tok2 = t >> 2, eo = (t & 3) * 32;
        unsigned short* op = att + (size_t)n * 8192 + tok2 * 128 + eo;
        const unsigned short* lp = lds + tok2 * 136 + eo;
#pragma unroll
        for (int k4 = 0; k4 < 4; ++k4)
            *(uint4v*)(op + k4 * 8) = *(const uint4v*)(lp + k4 * 8);
    }
}

// ---------------------------------------------------------------- K4: fuse
__global__ __launch_bounds__(256) void fuse_kernel(
    const unsigned short* __restrict__ comb,  // pixel-major [b][y][x][128]
    const unsigned short* __restrict__ att,   // [n][tok][e] raw out-proj
    const void* __restrict__ vf,
    const float* __restrict__ wf,
    const int* __restrict__ flag,
    void* __restrict__ outp)
{
    __shared__ float enhs[128][65];
    __shared__ float fws[64][65];
    const float* fcw = wf + WF_FCW;
    const float* fcb = wf + WF_FCB;
    const bool f32 = (*flag != 0);
    const int t = threadIdx.x;
    const int wl = t & 63;
    const int eg = __builtin_amdgcn_readfirstlane(t >> 6);
    const int h = blockIdx.y, b = blockIdx.z;
    const int w = blockIdx.x * 64 + wl;

    const int mh = h >> 2, mw = w >> 2;
    const bool vh0 = (mh >= 1), vh1 = (mh <= 30);
    const bool vw0 = (mw >= 1), vw1 = (mw <= 30);
    const int k = ((int)vh0 + (int)vh1) * ((int)vw0 + (int)vw1); // 1,2,4
    const float base7 = (k == 1) ? 0.7f : (k == 2) ? 0.49f : 0.2401f;
    const float bias_c = 1.f - base7;  // sum_j coef_j (out-proj bias weight)

    float cw[4]; int coff[4];
    {
        const bool vs[4] = { vh0 && vw0, vh0 && vw1, vh1 && vw0, vh1 && vw1 };
        const int ihc[4] = { mh - 1, mh - 1, mh, mh };
        const int iwc[4] = { mw - 1, mw, mw - 1, mw };
        int j = 0;
#pragma unroll
        for (int s = 0; s < 4; ++s) {
            if (vs[s]) {
                ++j;
                int e2 = k - j;  // 0..3
                float pw = (e2 == 0) ? 1.f : (e2 == 1) ? 0.7f : (e2 == 2) ? 0.49f : 0.343f;
                cw[s] = 0.3f * pw;
                int nn = (ihc[s] * 31 + iwc[s]) * 4 + b;
                int ll = (h - 4 * ihc[s]) * 8 + (w - 4 * iwc[s]);
                coff[s] = nn * 8192 + ll * 128;
            } else { cw[s] = 0.f; coff[s] = 0; }
        }
    }

    const int cbase = (b * 128) * HW + h * 128 + w;                 // vf/out index
    const size_t cpix = (size_t)(b * 16384 + h * 128 + w) * 128;    // comb record
    const int e0 = eg * 32;
#pragma unroll
    for (int i8 = 0; i8 < 4; ++i8) {
        float av[8];
#pragma unroll
        for (int j = 0; j < 8; ++j)
            av[j] = bias_c * wf[WF_OPB + e0 + i8 * 8 + j];
#pragma unroll
        for (int s = 0; s < 4; ++s) {
            uint4v u = *(const uint4v*)(att + coff[s] + e0 + i8 * 8);
            float x[8];
            unp8(u, x);
#pragma unroll
            for (int j = 0; j < 8; ++j)
                av[j] = fmaf(cw[s], x[j], av[j]);
        }
        uint4v cu = *(const uint4v*)(comb + cpix + e0 + i8 * 8);
        float cx[8];
        unp8(cu, cx);
#pragma unroll
        for (int j = 0; j < 8; ++j)
            enhs[e0 + i8 * 8 + j][wl] = fmaf(base7, cx[j], av[j]);
    }
    __syncthreads();

    float a2[16];
    const int co0 = eg * 16;
#pragma unroll
    for (int i = 0; i < 16; ++i) a2[i] = fcb[co0 + i];
    const float4* fcw4 = (const float4*)fcw;   // row stride 32 float4
    for (int eb = 0; eb < 32; ++eb) {
        float x0 = enhs[eb * 4 + 0][wl];
        float x1 = enhs[eb * 4 + 1][wl];
        float x2 = enhs[eb * 4 + 2][wl];
        float x3 = enhs[eb * 4 + 3][wl];
#pragma unroll
        for (int i = 0; i < 16; ++i) {
            float4 wv4 = fcw4[(co0 + i) * 32 + eb];
            float a = a2[i];
            a = fmaf(x0, wv4.x, a);
            a = fmaf(x1, wv4.y, a);
            a = fmaf(x2, wv4.z, a);
            a = fmaf(x3, wv4.w, a);
            a2[i] = a;
        }
    }
#pragma unroll
    for (int i = 0; i < 16; ++i)
        fws[co0 + i][wl] = 1.f / (1.f + __expf(-a2[i]));
    __syncthreads();

#pragma unroll
    for (int i = 0; i < 32; ++i) {
        const int e = eg * 32 + i;
        const int idx = cbase + e * HW;
        float val = enhs[e][wl] * fws[e & 63][wl] + ldin(vf, idx, f32);
        if (f32) ((float*)outp)[idx] = val;
        else     ((unsigned short*)outp)[idx] = fbf_hw(val);
    }
}

// ---------------------------------------------------------------------------
extern "C" void kernel_launch(void* const* d_in, const int* in_sizes, int n_in,
                              void* d_out, int out_size, void* d_ws, size_t ws_size,
                              hipStream_t stream)
{
    const void* vf  = d_in[0];
    const void* mw1 = d_in[1];
    const void* mb1 = d_in[2];
    const void* mw2 = d_in[3];
    const void* mb2 = d_in[4];
    const void* aw1 = d_in[5];
    const void* ab1 = d_in[6];
    const void* aw2 = d_in[7];
    const void* ab2 = d_in[8];
    const void* ipw = d_in[9];
    const void* ipb = d_in[10];
    const void* opw = d_in[11];
    const void* opb = d_in[12];
    const void* fcw = d_in[13];
    const void* fcb = d_in[14];

    // ws layout (80,351,232 B total)
    int* flag = (int*)d_ws;                                         // @0
    float* wf = (float*)((char*)d_ws + 1024);                       // 592,896 B
    unsigned short* comb = (unsigned short*)((char*)d_ws + 593920); // 16,777,216 B (pixel-major)
    unsigned short* hidden = (unsigned short*)((char*)d_ws + 17371136); // 8.39 MB (pixel-major)
    unsigned short* att = (unsigned short*)((char*)d_ws + 17371136);    // 62,980,096 B (overlays hidden)

    detect_kernel<<<1, 256, 0, stream>>>((const unsigned short*)vf, flag);
    cvtw_kernel<<<(WF_TOTAL + 255) / 256, 256, 0, stream>>>(
        ipw, ipb, opw, opb, fcw, fcb, mw1, mb1, aw1, ab1, mw2, mb2, aw2, ab2, flag, wf);
    conv1_kernel<<<dim3(4, 32, 8), 256, 0, stream>>>(vf, wf, flag, hidden);
    conv2_kernel<<<dim3(4, 32, 8), 256, 0, stream>>>(hidden, wf, comb);
    mha_kernel<<<NSEQ, 256, 0, stream>>>(comb, wf, att);
    fuse_kernel<<<dim3(2, 128, 4), 256, 0, stream>>>(comb, att, vf, wf, flag, d_out);
}

// Round 9
// 303.719 us; speedup vs baseline: 1.4750x; 1.1343x over previous
//
#include <hip/hip_runtime.h>
#include <hip/hip_bf16.h>

// ---------------------------------------------------------------------------
// VectorFieldAttention on MI355X — round 17 (conv1 -> MFMA via vf2p transpose)
//
// r16 post-mortem: conv2 MFMA -44us, absmax held 0.03125 -> template proven.
// r17: conv1 gets the same treatment. New one-shot vf2p kernel transposes vf
// to pixel-major bf16 records [z][px][64ch] (~10us HBM-bound); conv1 becomes
// a clone of the green conv2 kernel (2 IC-chunks of 32, 2 oc-tiles, ReLU
// epilogue, hidden records unchanged). cvtw emits bf16 conv1 weights
// [oc][9tap][64ic] into the now-dead f32 mw1/aw1 regions. mha/conv2/fuse
// untouched.
// ws: flag@0 | wf@1024 | comb@593,920 | vfp@17,371,136 (16.78MB, dead after
//     conv1) | hidden@34,148,352 (8.39MB, dead after conv2) | att@17,371,136
//     (62,980,096 B, overlays vfp+hidden) -> total 80,351,232 B.
// ---------------------------------------------------------------------------

#define HW 16384           // 128*128
#define NSEQ 3844          // 961 windows * 4 batch

// f32 weight file offsets (floats)
#define WF_IPW 0
#define WF_IPB 49152
#define WF_OPW 49536
#define WF_OPB 65920
#define WF_FCW 66048
#define WF_FCB 74240
#define WF_MW1 74304
#define WF_MB1 92736
#define WF_AW1 92768
#define WF_AB1 111200
#define WF_MW2 111232
#define WF_MB2 129664
#define WF_AW2 129728
#define WF_AB2 148160
#define WF_TOTAL 148224
#define WF_W2BF 24576      // bf16 conv2 weights (float-offset base; cast to ushort*)

typedef __bf16 bf16x8 __attribute__((ext_vector_type(8)));
typedef float f32x4 __attribute__((ext_vector_type(4)));
typedef unsigned int uint2v __attribute__((ext_vector_type(2)));
typedef unsigned int uint4v __attribute__((ext_vector_type(4)));

#define MFMA16(a, b, c) __builtin_amdgcn_mfma_f32_16x16x32_bf16((a), (b), (c), 0, 0, 0)

__device__ __forceinline__ float bfu(unsigned short u) {
    union { unsigned int i; float f; } v; v.i = ((unsigned int)u) << 16; return v.f;
}
// software RNE (cold paths only; bit-identical to v_cvt_pk_bf16_f32)
__device__ __forceinline__ unsigned short fbf(float f) {
    union { float f; unsigned int i; } v; v.f = f;
    unsigned int x = v.i;
    return (unsigned short)((x + 0x7fffu + ((x >> 16) & 1u)) >> 16);
}
// HW RNE pack: lo16 = bf16(a), hi16 = bf16(b). 1 VALU op.
__device__ __forceinline__ unsigned int cvt_pk_bf16(float a, float b) {
    unsigned int r;
    asm("v_cvt_pk_bf16_f32 %0, %1, %2" : "=v"(r) : "v"(a), "v"(b));
    return r;
}
__device__ __forceinline__ unsigned short fbf_hw(float f) {
    return (unsigned short)cvt_pk_bf16(f, f);
}
__device__ __forceinline__ float ldin(const void* p, long long i, bool f32) {
    return f32 ? ((const float*)p)[i] : bfu(((const unsigned short*)p)[i]);
}
__device__ __forceinline__ bf16x8 frag_ld(const unsigned short* p) {
    union { uint4v u; bf16x8 b; } v;
    v.u = *(const uint4v*)p;
    return v.b;
}
__device__ __forceinline__ uint2v pack4(float a, float b, float c, float d) {
    uint2v r;
    r.x = cvt_pk_bf16(a, b);
    r.y = cvt_pk_bf16(c, d);
    return r;
}
__device__ __forceinline__ void unp8(uint4v u, float* x) {
    union { unsigned int i; float f; } a;
    a.i = u.x << 16;         x[0] = a.f;
    a.i = u.x & 0xffff0000u; x[1] = a.f;
    a.i = u.y << 16;         x[2] = a.f;
    a.i = u.y & 0xffff0000u; x[3] = a.f;
    a.i = u.z << 16;         x[4] = a.f;
    a.i = u.z & 0xffff0000u; x[5] = a.f;
    a.i = u.w << 16;         x[6] = a.f;
    a.i = u.w & 0xffff0000u; x[7] = a.f;
}

// ------------------------------------------------------------- K-1: detect
__global__ __launch_bounds__(256) void detect_kernel(const unsigned short* __restrict__ vfu,
                                                     int* __restrict__ flag)
{
    __shared__ int cnt;
    if (threadIdx.x == 0) cnt = 0;
    __syncthreads();
    int bad = 0;
    for (int i = threadIdx.x; i < 8192; i += 256) {
        int e = (vfu[i] >> 7) & 0xff;
        if (e < 0x60 || e > 0xA0) ++bad;
    }
    atomicAdd(&cnt, bad);
    __syncthreads();
    if (threadIdx.x == 0) *flag = (cnt > 400) ? 1 : 0;
}

// ---------------------------------------------------------------- K0: weights
__global__ __launch_bounds__(256) void cvtw_kernel(
    const void* ipw, const void* ipb,
    const void* opw, const void* opb,
    const void* fcw, const void* fcb,
    const void* mw1, const void* mb1,
    const void* aw1, const void* ab1,
    const void* mw2, const void* mb2,
    const void* aw2, const void* ab2,
    const int* __restrict__ flag, float* __restrict__ wf)
{
    int i = blockIdx.x * 256 + threadIdx.x;
    if (i >= WF_TOTAL) return;
    const bool f32 = (*flag != 0);
    const void* src; int off;
    if      (i < WF_IPB) { src = ipw; off = WF_IPW; }
    else if (i < WF_OPW) { src = ipb; off = WF_IPB; }
    else if (i < WF_OPB) { src = opw; off = WF_OPW; }
    else if (i < WF_FCW) { src = opb; off = WF_OPB; }
    else if (i < WF_FCB) { src = fcw; off = WF_FCW; }
    else if (i < WF_MW1) { src = fcb; off = WF_FCB; }
    else if (i < WF_MB1) { src = mw1; off = WF_MW1; }
    else if (i < WF_AW1) { src = mb1; off = WF_MB1; }
    else if (i < WF_AB1) { src = aw1; off = WF_AW1; }
    else if (i < WF_MB2) { src = (i < WF_MW2) ? ab1 : mw2; off = (i < WF_MW2) ? WF_AB1 : WF_MW2; }
    else if (i < WF_AW2) { src = mb2; off = WF_MB2; }
    else if (i < WF_AB2) { src = aw2; off = WF_AW2; }
    else                 { src = ab2; off = WF_AB2; }
    float v = ldin(src, i - off, f32);
    if (i < WF_IPB) {
        ((unsigned short*)(wf + WF_IPW))[i] = fbf(v);           // wqkv_bf [384][128]
    } else if (i >= WF_OPW && i < WF_OPB) {
        ((unsigned short*)(wf + WF_OPW))[i - WF_OPW] = fbf(v);  // wo_bf [128][128]
    } else if (i >= WF_MW1 && i < WF_MB1) {
        // bf16 conv1 weights [32oc][9tap][64ic] overlaying dead f32 mw1 region
        int rel = i - WF_MW1;                  // src [oc][ic][tap]
        int oc = rel / 576, rem = rel - oc * 576;
        int ic = rem / 9, tap = rem - ic * 9;
        ((unsigned short*)(wf + WF_MW1))[oc * 576 + tap * 64 + ic] = fbf(v);
    } else if (i >= WF_AW1 && i < WF_AB1) {
        int rel = i - WF_AW1;
        int oc = rel / 576, rem = rel - oc * 576;
        int ic = rem / 9, tap = rem - ic * 9;
        ((unsigned short*)(wf + WF_AW1))[oc * 576 + tap * 64 + ic] = fbf(v);
    } else {
        wf[i] = v;
    }
    // bf16 conv2 weights, tap-major: w2bf[br][oc 64][tap 9][ic 32]
    if (i >= WF_MW2 && i < WF_MB2) {
        int rel = i - WF_MW2;                  // [oc][ic][tap]
        int oc = rel / 288, rem = rel - oc * 288;
        int ic = rem / 9, tap = rem - ic * 9;
        ((unsigned short*)(wf + WF_W2BF))[oc * 288 + tap * 32 + ic] = fbf(v);
    } else if (i >= WF_AW2 && i < WF_AB2) {
        int rel = i - WF_AW2;
        int oc = rel / 288, rem = rel - oc * 288;
        int ic = rem / 9, tap = rem - ic * 9;
        ((unsigned short*)(wf + WF_W2BF))[18432 + oc * 288 + tap * 32 + ic] = fbf(v);
    }
}

// ------------------------------------------------------------- K0.5: vf2p
// one-shot transpose: vf (channel-major, f32 or bf16) -> vfp pixel-major
// bf16 records [z=b*2+br][px 16384][64ch].
__global__ __launch_bounds__(256) void vf2p_kernel(const void* __restrict__ vf,
                                                   const int* __restrict__ flag,
                                                   unsigned short* __restrict__ vfp)
{
    __shared__ unsigned short ts[64 * 72];   // 64 px records, 72-ush pad
    const int t = threadIdx.x;
    const int z = blockIdx.y;
    const int px0 = blockIdx.x * 64;
    const bool f32 = (*flag != 0);
    const long long in_off = (long long)((z >> 1) * 128 + (z & 1) * 64) * HW;

    // read 64ch x 64px as pairs along x (coalesced), scatter to records
    for (int i = t; i < 2048; i += 256) {
        const int c = i >> 5, jp = i & 31;
        const long long a = in_off + (long long)c * HW + px0 + 2 * jp;
        if (f32) {
            float2 u = *(const float2*)((const float*)vf + a);
            ts[(2 * jp) * 72 + c] = fbf_hw(u.x);
            ts[(2 * jp + 1) * 72 + c] = fbf_hw(u.y);
        } else {
            unsigned int u = *(const unsigned int*)((const unsigned short*)vf + a);
            ts[(2 * jp) * 72 + c] = (unsigned short)(u & 0xffffu);
            ts[(2 * jp + 1) * 72 + c] = (unsigned short)(u >> 16);
        }
    }
    __syncthreads();
    // write records coalesced (16B per thread-slot)
    for (int i = t; i < 512; i += 256) {
        const int px = i >> 3, part = i & 7;
        *(uint4v*)(vfp + ((size_t)z * 16384 + px0 + px) * 64 + part * 8) =
            *(const uint4v*)&ts[px * 72 + part * 8];
    }
}

// ------------------------------------------------------------- conv1 (MFMA)
// 32x4 px tile, 32 oc, IC=64 in 2 chunks of 32. Clone of conv2 structure.
__global__ __launch_bounds__(256) void conv1_kernel(const unsigned short* __restrict__ vfp,
                                                    const float* __restrict__ wf,
                                                    unsigned short* __restrict__ hidden)
{
    __shared__ unsigned short xs[8160];   // 204 records * 40 ush (32ch chunk)
    const int t = threadIdx.x;
    const int tx0 = blockIdx.x * 32, ty0 = blockIdx.y * 4;
    const int z = blockIdx.z, br = z & 1;
    const size_t ibase = (size_t)z * 16384;

    const int lane = t & 63, quad = lane >> 4, l16 = lane & 15;
    const int wv = __builtin_amdgcn_readfirstlane(t >> 6);   // output row ty0+wv
    const unsigned short* w1 = (const unsigned short*)(wf + (br ? WF_AW1 : WF_MW1));
    const float* bias = wf + (br ? WF_AB1 : WF_MB1);         // [32]

    f32x4 acc[2][2];   // [oc-tile][px-half]
#pragma unroll
    for (int oct = 0; oct < 2; ++oct) {
        f32x4 b4;
#pragma unroll
        for (int r = 0; r < 4; ++r) b4[r] = bias[oct * 16 + quad * 4 + r];
        acc[oct][0] = b4;
        acc[oct][1] = b4;
    }

    for (int ck = 0; ck < 2; ++ck) {
        if (ck) __syncthreads();   // all chunk-0 reads done before restage
        for (int i = t; i < 816; i += 256) {
            const int rec = i >> 2, part = i & 3;
            const int rr = rec / 34, cx = rec - rr * 34;
            const int gy = ty0 + rr - 1, gx = tx0 + cx - 1;
            uint4v v = {0u, 0u, 0u, 0u};
            if (gy >= 0 && gy < 128 && gx >= 0 && gx < 128)
                v = *(const uint4v*)(vfp + (ibase + gy * 128 + gx) * 64 + ck * 32 + part * 8);
            *(uint4v*)&xs[rec * 40 + part * 8] = v;
        }
        __syncthreads();
        __builtin_amdgcn_s_setprio(1);
#pragma unroll
        for (int tap = 0; tap < 9; ++tap) {
            const int dy = tap / 3, dx = tap - dy * 3;
            bf16x8 bxf[2];
#pragma unroll
            for (int pt2 = 0; pt2 < 2; ++pt2)
                bxf[pt2] = frag_ld(&xs[((wv + dy) * 34 + (pt2 * 16 + l16 + dx)) * 40 + quad * 8]);
#pragma unroll
            for (int oct = 0; oct < 2; ++oct) {
                bf16x8 af = frag_ld(&w1[(oct * 16 + l16) * 576 + tap * 64 + ck * 32 + quad * 8]);
                acc[oct][0] = MFMA16(af, bxf[0], acc[oct][0]);
                acc[oct][1] = MFMA16(af, bxf[1], acc[oct][1]);
            }
        }
        __builtin_amdgcn_s_setprio(0);
    }

    // epilogue with ReLU: record stride 32, oc = oct*16 + quad*4 + r
#pragma unroll
    for (int pt2 = 0; pt2 < 2; ++pt2) {
        const int px_ = tx0 + pt2 * 16 + l16;
        unsigned short* op = hidden + (ibase + (ty0 + wv) * 128 + px_) * 32 + quad * 4;
#pragma unroll
        for (int oct = 0; oct < 2; ++oct) {
            f32x4 a = acc[oct][pt2];
            *(uint2v*)(op + oct * 16) =
                pack4(fmaxf(a[0], 0.f), fmaxf(a[1], 0.f),
                      fmaxf(a[2], 0.f), fmaxf(a[3], 0.f));
        }
    }
}

// ------------------------------------------------------------- conv2 (MFMA)
// Per block: 32x4 px tile, 64 oc (one branch). Stage [6 rows][34 cols] px
// records (32ch bf16, padded to 40 ush = 80B -> 2-way bank alias = free).
__global__ __launch_bounds__(256) void conv2_kernel(const unsigned short* __restrict__ hidden,
                                                    const float* __restrict__ wf,
                                                    unsigned short* __restrict__ comb)
{
    __shared__ unsigned short xs[8160];   // 204 records * 40 ush
    const int t = threadIdx.x;
    const int tx0 = blockIdx.x * 32, ty0 = blockIdx.y * 4;
    const int z = blockIdx.z, b = z >> 1, br = z & 1;
    const size_t ibase = (size_t)z * 16384;

    // stage 6x34 records (16B quarters), zero OOB
    for (int i = t; i < 816; i += 256) {
        const int rec = i >> 2, part = i & 3;
        const int rr = rec / 34, cx = rec - rr * 34;
        const int gy = ty0 + rr - 1, gx = tx0 + cx - 1;
        uint4v v = {0u, 0u, 0u, 0u};
        if (gy >= 0 && gy < 128 && gx >= 0 && gx < 128)
            v = *(const uint4v*)(hidden + (ibase + gy * 128 + gx) * 32 + part * 8);
        *(uint4v*)&xs[rec * 40 + part * 8] = v;
    }
    __syncthreads();

    const int lane = t & 63, quad = lane >> 4, l16 = lane & 15;
    const int wv = __builtin_amdgcn_readfirstlane(t >> 6);   // output row ty0+wv
    const unsigned short* w2 = (const unsigned short*)(wf + WF_W2BF) + br * 18432;
    const float* bias = wf + (br ? WF_AB2 : WF_MB2);         // [64]

    f32x4 acc[4][2];   // [oc-tile][px-half]
#pragma unroll
    for (int oct = 0; oct < 4; ++oct) {
        f32x4 b4;
#pragma unroll
        for (int r = 0; r < 4; ++r) b4[r] = bias[oct * 16 + quad * 4 + r];
        acc[oct][0] = b4;
        acc[oct][1] = b4;
    }

    __builtin_amdgcn_s_setprio(1);
#pragma unroll
    for (int tap = 0; tap < 9; ++tap) {
        const int dy = tap / 3, dx = tap - dy * 3;
        bf16x8 bxf[2];
#pragma unroll
        for (int pt2 = 0; pt2 < 2; ++pt2)
            bxf[pt2] = frag_ld(&xs[((wv + dy) * 34 + (pt2 * 16 + l16 + dx)) * 40 + quad * 8]);
#pragma unroll
        for (int oct = 0; oct < 4; ++oct) {
            bf16x8 af = frag_ld(&w2[(oct * 16 + l16) * 288 + tap * 32 + quad * 8]);
            acc[oct][0] = MFMA16(af, bxf[0], acc[oct][0]);
            acc[oct][1] = MFMA16(af, bxf[1], acc[oct][1]);
        }
    }
    __builtin_amdgcn_s_setprio(0);

    // epilogue: D row = oc = oct*16 + quad*4 + r, col = px = l16
#pragma unroll
    for (int pt2 = 0; pt2 < 2; ++pt2) {
        const int px_ = tx0 + pt2 * 16 + l16;
        unsigned short* op = comb + ((size_t)b * 16384 + (ty0 + wv) * 128 + px_) * 128
                           + br * 64 + quad * 4;
#pragma unroll
        for (int oct = 0; oct < 4; ++oct)
            *(uint2v*)(op + oct * 16) =
                pack4(acc[oct][pt2][0], acc[oct][pt2][1],
                      acc[oct][pt2][2], acc[oct][pt2][3]);
    }
}

// ---------------------------------------------------------------- K3: MHA (MFMA)
// (r14 verbatim: 256 threads, wave hh owns head hh; setprio kept)
// LDS map (ushort units, 25,088 total = 50,176 B -> 3 blocks/CU):
//   region0 @0 (8,704 ush): X [64][136]  ->  V^T 4x[32][64]swz  ->  O/D [64][136]
//   head hh @8,704+hh*4,096: Q [64][32]swz | K @+2,048 [64][32]swz
//                            P [64][64]swz overlays Q+K after scores
__global__ __launch_bounds__(256) void mha_kernel(
    const unsigned short* __restrict__ comb,   // [b][y][x][e=128] bf16 pixel-major
    const float* __restrict__ wf,
    unsigned short* __restrict__ att)          // [n][tok][e] bf16, raw out-proj
{
    __shared__ unsigned short lds[25088];

    const unsigned short* wqkv = (const unsigned short*)(wf + WF_IPW); // [384][128] bf16
    const unsigned short* wo   = (const unsigned short*)(wf + WF_OPW); // [128][128] bf16

    // Bijective XCD-chunked batch-major map (HW: block i -> XCD i%8).
    const int bid = blockIdx.x;
    const int xcd = bid & 7, idx = bid >> 3;
    const int start = (xcd < 4) ? xcd * 481 : 1924 + (xcd - 4) * 480;
    const int nl = start + idx;
    const int bb = nl / 961;
    const int ihw = nl - bb * 961;
    const int ih = ihw / 31, iw = ihw - ih * 31;
    const int n = ihw * 4 + bb;

    const int t = threadIdx.x;
    const int lane = t & 63, quad = lane >> 4, l16 = lane & 15;
    const int hh = __builtin_amdgcn_readfirstlane(t >> 6);
    const int hb = hh * 32;
    const int QOFF = 8704 + hh * 4096;
    const int KOFF = QOFF + 2048;
    const int VOFF = hh * 2048;

#pragma unroll
    for (int rh = 0; rh < 2; ++rh) {
        const int r = hh * 2 + rh;
        const unsigned short* rp = comb +
            (size_t)(bb * 16384 + (ih * 4 + r) * 128 + iw * 4) * 128;
#pragma unroll
        for (int hv = 0; hv < 2; ++hv) {
            uint4v v = *(const uint4v*)(rp + hv * 512 + lane * 8);
            const int tok = r * 8 + hv * 4 + (lane >> 4);
            *(uint4v*)&lds[tok * 136 + (lane & 15) * 8] = v;
        }
    }
    __syncthreads();

    // ---- pass A: Q,K = Wqkv[0:256] . X^T ----
    {
        f32x4 acc[4][4];
#pragma unroll
        for (int nt = 0; nt < 4; ++nt) {
            const int rb = (nt < 2) ? (hb + nt * 16) : (128 + hb + (nt - 2) * 16);
            f32x4 b4;
            b4[0] = wf[WF_IPB + rb + quad * 4 + 0];
            b4[1] = wf[WF_IPB + rb + quad * 4 + 1];
            b4[2] = wf[WF_IPB + rb + quad * 4 + 2];
            b4[3] = wf[WF_IPB + rb + quad * 4 + 3];
#pragma unroll
            for (int mt = 0; mt < 4; ++mt) acc[nt][mt] = b4;
        }
        __builtin_amdgcn_s_setprio(1);
#pragma unroll
        for (int kc = 0; kc < 4; ++kc) {
            bf16x8 bx[4];
#pragma unroll
            for (int mt = 0; mt < 4; ++mt)
                bx[mt] = frag_ld(&lds[(mt * 16 + l16) * 136 + kc * 32 + quad * 8]);
#pragma unroll
            for (int nt = 0; nt < 4; ++nt) {
                const int rb = (nt < 2) ? (hb + nt * 16) : (128 + hb + (nt - 2) * 16);
                bf16x8 aw = frag_ld(&wqkv[(rb + l16) * 128 + kc * 32 + quad * 8]);
#pragma unroll
                for (int mt = 0; mt < 4; ++mt)
                    acc[nt][mt] = MFMA16(aw, bx[mt], acc[nt][mt]);
            }
        }
        __builtin_amdgcn_s_setprio(0);
#pragma unroll
        for (int nt = 0; nt < 2; ++nt)
#pragma unroll
            for (int mt = 0; mt < 4; ++mt) {
                const int tok = mt * 16 + l16;
                const int aoff = tok * 32 + (((nt * 2 + (quad >> 1)) ^ (tok & 3)) << 3)
                               + (quad & 1) * 4;
                *(uint2v*)&lds[QOFF + aoff] =
                    pack4(acc[nt][mt][0], acc[nt][mt][1], acc[nt][mt][2], acc[nt][mt][3]);
                *(uint2v*)&lds[KOFF + aoff] =
                    pack4(acc[nt + 2][mt][0], acc[nt + 2][mt][1],
                          acc[nt + 2][mt][2], acc[nt + 2][mt][3]);
            }
    }

    // ---- pass B: V = Wqkv[256:384] . X^T ----
    f32x4 accv[2][4];
#pragma unroll
    for (int nv = 0; nv < 2; ++nv) {
        const int rb = 256 + hb + nv * 16;
        f32x4 b4;
        b4[0] = wf[WF_IPB + rb + quad * 4 + 0];
        b4[1] = wf[WF_IPB + rb + quad * 4 + 1];
        b4[2] = wf[WF_IPB + rb + quad * 4 + 2];
        b4[3] = wf[WF_IPB + rb + quad * 4 + 3];
#pragma unroll
        for (int mt = 0; mt < 4; ++mt) accv[nv][mt] = b4;
    }
    __builtin_amdgcn_s_setprio(1);
#pragma unroll
    for (int kc = 0; kc < 4; ++kc) {
        bf16x8 bx[4];
#pragma unroll
        for (int mt = 0; mt < 4; ++mt)
            bx[mt] = frag_ld(&lds[(mt * 16 + l16) * 136 + kc * 32 + quad * 8]);
#pragma unroll
        for (int nv = 0; nv < 2; ++nv) {
            const int rb = 256 + hb + nv * 16;
            bf16x8 aw = frag_ld(&wqkv[(rb + l16) * 128 + kc * 32 + quad * 8]);
#pragma unroll
            for (int mt = 0; mt < 4; ++mt)
                accv[nv][mt] = MFMA16(aw, bx[mt], accv[nv][mt]);
        }
    }
    __builtin_amdgcn_s_setprio(0);
    __syncthreads();

    // ---- V^T [d=32][tok=64] swz (slot ^ (d&7)), overlays dead X ----
#pragma unroll
    for (int nv = 0; nv < 2; ++nv)
#pragma unroll
        for (int mt = 0; mt < 4; ++mt)
#pragma unroll
            for (int r = 0; r < 4; ++r) {
                const int d = nv * 16 + quad * 4 + r;
                const int tok = mt * 16 + l16;
                lds[VOFF + d * 64 + (((tok >> 3) ^ (d & 7)) << 3) + (tok & 7)] =
                    fbf_hw(accv[nv][mt][r]);
            }

    // ---- scores: S^T = K . Q^T ----
    bf16x8 ak[4], bq[4];
#pragma unroll
    for (int mtk = 0; mtk < 4; ++mtk) {
        const int tok = mtk * 16 + l16;
        ak[mtk] = frag_ld(&lds[KOFF + tok * 32 + ((quad ^ (tok & 3)) << 3)]);
    }
#pragma unroll
    for (int ntq = 0; ntq < 4; ++ntq) {
        const int tok = ntq * 16 + l16;
        bq[ntq] = frag_ld(&lds[QOFF + tok * 32 + ((quad ^ (tok & 3)) << 3)]);
    }
    f32x4 sc[4][4];
    {
        f32x4 zz = {0.f, 0.f, 0.f, 0.f};
        __builtin_amdgcn_s_setprio(1);
#pragma unroll
        for (int mtk = 0; mtk < 4; ++mtk)
#pragma unroll
            for (int ntq = 0; ntq < 4; ++ntq)
                sc[mtk][ntq] = MFMA16(ak[mtk], bq[ntq], zz);
        __builtin_amdgcn_s_setprio(0);
    }

    // ---- softmax; P [tokq][tokk=64] swz (slot ^ (tokq&7)) overlays Q+K ----
    const float scale = 0.17677669529663687f;  // 32^-0.5
#pragma unroll
    for (int ntq = 0; ntq < 4; ++ntq) {
        float m0 = -1e30f;
#pragma unroll
        for (int mtk = 0; mtk < 4; ++mtk)
#pragma unroll
            for (int r = 0; r < 4; ++r) {
                sc[mtk][ntq][r] *= scale;
                m0 = fmaxf(m0, sc[mtk][ntq][r]);
            }
        m0 = fmaxf(m0, __shfl_xor(m0, 16));
        m0 = fmaxf(m0, __shfl_xor(m0, 32));
        float s0 = 0.f;
#pragma unroll
        for (int mtk = 0; mtk < 4; ++mtk)
#pragma unroll
            for (int r = 0; r < 4; ++r) {
                float p = __expf(sc[mtk][ntq][r] - m0);
                sc[mtk][ntq][r] = p;
                s0 += p;
            }
        s0 += __shfl_xor(s0, 16);
        s0 += __shfl_xor(s0, 32);
        float inv = 1.f / s0;
        const int tokq = ntq * 16 + l16;
#pragma unroll
        for (int mtk = 0; mtk < 4; ++mtk)
            *(uint2v*)&lds[QOFF + tokq * 64 +
                           (((mtk * 2 + (quad >> 1)) ^ (tokq & 7)) << 3) + (quad & 1) * 4] =
                pack4(sc[mtk][ntq][0] * inv, sc[mtk][ntq][1] * inv,
                      sc[mtk][ntq][2] * inv, sc[mtk][ntq][3] * inv);
    }
    __asm__ volatile("s_waitcnt lgkmcnt(0)" ::: "memory");  // within-wave P/V handoff

    // ---- O = P . V ----
    f32x4 ov[4][2];
#pragma unroll
    for (int mt = 0; mt < 4; ++mt)
#pragma unroll
        for (int nv = 0; nv < 2; ++nv) { f32x4 zz = {0.f, 0.f, 0.f, 0.f}; ov[mt][nv] = zz; }
    __builtin_amdgcn_s_setprio(1);
#pragma unroll
    for (int ks = 0; ks < 2; ++ks) {
        bf16x8 ap[4];
#pragma unroll
        for (int mt = 0; mt < 4; ++mt) {
            const int tokq = mt * 16 + l16;
            ap[mt] = frag_ld(&lds[QOFF + tokq * 64 + (((ks * 4 + quad) ^ (tokq & 7)) << 3)]);
        }
#pragma unroll
        for (int nv = 0; nv < 2; ++nv) {
            const int d = nv * 16 + l16;
            bf16x8 bv = frag_ld(&lds[VOFF + d * 64 + (((ks * 4 + quad) ^ (d & 7)) << 3)]);
#pragma unroll
            for (int mt = 0; mt < 4; ++mt)
                ov[mt][nv] = MFMA16(ap[mt], bv, ov[mt][nv]);
        }
    }
    __builtin_amdgcn_s_setprio(0);
    __syncthreads();

    // ---- O -> LDS [tok][e] s136 @0 ----
#pragma unroll
    for (int mt = 0; mt < 4; ++mt)
#pragma unroll
        for (int nv = 0; nv < 2; ++nv)
#pragma unroll
            for (int r = 0; r < 4; ++r)
                lds[(mt * 16 + quad * 4 + r) * 136 + hb + nv * 16 + l16] =
                    fbf_hw(ov[mt][nv][r]);
    __syncthreads();

    // ---- out-proj: D = O . Wo^T ----
    f32x4 dp[4][2];
#pragma unroll
    for (int mt = 0; mt < 4; ++mt)
#pragma unroll
        for (int nl = 0; nl < 2; ++nl) { f32x4 zz = {0.f, 0.f, 0.f, 0.f}; dp[mt][nl] = zz; }
    __builtin_amdgcn_s_setprio(1);
#pragma unroll
    for (int ks = 0; ks < 4; ++ks) {
        bf16x8 af[4];
#pragma unroll
        for (int mt = 0; mt < 4; ++mt)
            af[mt] = frag_ld(&lds[(mt * 16 + l16) * 136 + ks * 32 + quad * 8]);
#pragma unroll
        for (int nl = 0; nl < 2; ++nl) {
            const int erow = hb + nl * 16 + l16;
            bf16x8 bw = frag_ld(&wo[erow * 128 + ks * 32 + quad * 8]);
#pragma unroll
            for (int mt = 0; mt < 4; ++mt)
                dp[mt][nl] = MFMA16(af[mt], bw, dp[mt][nl]);
        }
    }
    __builtin_amdgcn_s_setprio(0);
    __syncthreads();

    // ---- D -> LDS [tok][e] s136 @0 ----
#pragma unroll
    for (int mt = 0; mt < 4; ++mt)
#pragma unroll
        for (int nl = 0; nl < 2; ++nl)
#pragma unroll
            for (int r = 0; r < 4; ++r)
                lds[(mt * 16 + quad * 4 + r) * 136 + hb + nl * 16 + l16] =
                    fbf_hw(dp[mt][nl][r]);
    __syncthreads();

    // ---- coalesced att store ----
    {
        const int tok2 = t >> 2, eo = (t & 3) * 32;
        unsigned short* op = att + (size_t)n * 8192 + tok2 * 128 + eo;
        const unsigned short* lp = lds + tok2 * 136 + eo;
#pragma unroll
        for (int k4 = 0; k4 < 4; ++k4)
            *(uint4v*)(op + k4 * 8) = *(const uint4v*)(lp + k4 * 8);
    }
}

// ---------------------------------------------------------------- K4: fuse
__global__ __launch_bounds__(256) void fuse_kernel(
    const unsigned short* __restrict__ comb,  // pixel-major [b][y][x][128]
    const unsigned short* __restrict__ att,   // [n][tok][e] raw out-proj
    const void* __restrict__ vf,
    const float* __restrict__ wf,
    const int* __restrict__ flag,
    void* __restrict__ outp)
{
    __shared__ float enhs[128][65];
    __shared__ float fws[64][65];
    const float* fcw = wf + WF_FCW;
    const float* fcb = wf + WF_FCB;
    const bool f32 = (*flag != 0);
    const int t = threadIdx.x;
    const int wl = t & 63;
    const int eg = __builtin_amdgcn_readfirstlane(t >> 6);
    const int h = blockIdx.y, b = blockIdx.z;
    const int w = blockIdx.x * 64 + wl;

    const int mh = h >> 2, mw = w >> 2;
    const bool vh0 = (mh >= 1), vh1 = (mh <= 30);
    const bool vw0 = (mw >= 1), vw1 = (mw <= 30);
    const int k = ((int)vh0 + (int)vh1) * ((int)vw0 + (int)vw1); // 1,2,4
    const float base7 = (k == 1) ? 0.7f : (k == 2) ? 0.49f : 0.2401f;
    const float bias_c = 1.f - base7;  // sum_j coef_j (out-proj bias weight)

    float cw[4]; int coff[4];
    {
        const bool vs[4] = { vh0 && vw0, vh0 && vw1, vh1 && vw0, vh1 && vw1 };
        const int ihc[4] = { mh - 1, mh - 1, mh, mh };
        const int iwc[4] = { mw - 1, mw, mw - 1, mw };
        int j = 0;
#pragma unroll
        for (int s = 0; s < 4; ++s) {
            if (vs[s]) {
                ++j;
                int e2 = k - j;  // 0..3
                float pw = (e2 == 0) ? 1.f : (e2 == 1) ? 0.7f : (e2 == 2) ? 0.49f : 0.343f;
                cw[s] = 0.3f * pw;
                int nn = (ihc[s] * 31 + iwc[s]) * 4 + b;
                int ll = (h - 4 * ihc[s]) * 8 + (w - 4 * iwc[s]);
                coff[s] = nn * 8192 + ll * 128;
            } else { cw[s] = 0.f; coff[s] = 0; }
        }
    }

    const int cbase = (b * 128) * HW + h * 128 + w;                 // vf/out index
    const size_t cpix = (size_t)(b * 16384 + h * 128 + w) * 128;    // comb record
    const int e0 = eg * 32;
#pragma unroll
    for (int i8 = 0; i8 < 4; ++i8) {
        float av[8];
#pragma unroll
        for (int j = 0; j < 8; ++j)
            av[j] = bias_c * wf[WF_OPB + e0 + i8 * 8 + j];
#pragma unroll
        for (int s = 0; s < 4; ++s) {
            uint4v u = *(const uint4v*)(att + coff[s] + e0 + i8 * 8);
            float x[8];
            unp8(u, x);
#pragma unroll
            for (int j = 0; j < 8; ++j)
                av[j] = fmaf(cw[s], x[j], av[j]);
        }
        uint4v cu = *(const uint4v*)(comb + cpix + e0 + i8 * 8);
        float cx[8];
        unp8(cu, cx);
#pragma unroll
        for (int j = 0; j < 8; ++j)
            enhs[e0 + i8 * 8 + j][wl] = fmaf(base7, cx[j], av[j]);
    }
    __syncthreads();

    float a2[16];
    const int co0 = eg * 16;
#pragma unroll
    for (int i = 0; i < 16; ++i) a2[i] = fcb[co0 + i];
    const float4* fcw4 = (const float4*)fcw;   // row stride 32 float4
    for (int eb = 0; eb < 32; ++eb) {
        float x0 = enhs[eb * 4 + 0][wl];
        float x1 = enhs[eb * 4 + 1][wl];
        float x2 = enhs[eb * 4 + 2][wl];
        float x3 = enhs[eb * 4 + 3][wl];
#pragma unroll
        for (int i = 0; i < 16; ++i) {
            float4 wv4 = fcw4[(co0 + i) * 32 + eb];
            float a = a2[i];
            a = fmaf(x0, wv4.x, a);
            a = fmaf(x1, wv4.y, a);
            a = fmaf(x2, wv4.z, a);
            a = fmaf(x3, wv4.w, a);
            a2[i] = a;
        }
    }
#pragma unroll
    for (int i = 0; i < 16; ++i)
        fws[co0 + i][wl] = 1.f / (1.f + __expf(-a2[i]));
    __syncthreads();

#pragma unroll
    for (int i = 0; i < 32; ++i) {
        const int e = eg * 32 + i;
        const int idx = cbase + e * HW;
        float val = enhs[e][wl] * fws[e & 63][wl] + ldin(vf, idx, f32);
        if (f32) ((float*)outp)[idx] = val;
        else     ((unsigned short*)outp)[idx] = fbf_hw(val);
    }
}

// ---------------------------------------------------------------------------
extern "C" void kernel_launch(void* const* d_in, const int* in_sizes, int n_in,
                              void* d_out, int out_size, void* d_ws, size_t ws_size,
                              hipStream_t stream)
{
    const void* vf  = d_in[0];
    const void* mw1 = d_in[1];
    const void* mb1 = d_in[2];
    const void* mw2 = d_in[3];
    const void* mb2 = d_in[4];
    const void* aw1 = d_in[5];
    const void* ab1 = d_in[6];
    const void* aw2 = d_in[7];
    const void* ab2 = d_in[8];
    const void* ipw = d_in[9];
    const void* ipb = d_in[10];
    const void* opw = d_in[11];
    const void* opb = d_in[12];
    const void* fcw = d_in[13];
    const void* fcb = d_in[14];

    // ws layout (80,351,232 B total)
    int* flag = (int*)d_ws;                                         // @0
    float* wf = (float*)((char*)d_ws + 1024);                       // 592,896 B
    unsigned short* comb = (unsigned short*)((char*)d_ws + 593920); // 16,777,216 B (pixel-major)
    unsigned short* vfp = (unsigned short*)((char*)d_ws + 17371136);    // 16,777,216 B (dead after conv1)
    unsigned short* hidden = (unsigned short*)((char*)d_ws + 34148352); // 8,388,608 B (dead after conv2)
    unsigned short* att = (unsigned short*)((char*)d_ws + 17371136);    // 62,980,096 B (overlays vfp+hidden)

    detect_kernel<<<1, 256, 0, stream>>>((const unsigned short*)vf, flag);
    cvtw_kernel<<<(WF_TOTAL + 255) / 256, 256, 0, stream>>>(
        ipw, ipb, opw, opb, fcw, fcb, mw1, mb1, aw1, ab1, mw2, mb2, aw2, ab2, flag, wf);
    vf2p_kernel<<<dim3(256, 8), 256, 0, stream>>>(vf, flag, vfp);
    conv1_kernel<<<dim3(4, 32, 8), 256, 0, stream>>>(vfp, wf, hidden);
    conv2_kernel<<<dim3(4, 32, 8), 256, 0, stream>>>(hidden, wf, comb);
    mha_kernel<<<NSEQ, 256, 0, stream>>>(comb, wf, att);
    fuse_kernel<<<dim3(2, 128, 4), 256, 0, stream>>>(comb, att, vf, wf, flag, d_out);
}